// Round 1
// baseline (990.104 us; speedup 1.0000x reference)
//
#include <hip/hip_runtime.h>
#include <math.h>

// Problem constants (fixed by harness: B=1, T=2048, C=768, H=12, D=64, R=32, K0=128)
#define T_DIM 2048
#define C_DIM 768
#define H_DIM 12
#define D_DIM 64
#define R_DIM 32

static constexpr float B_SCALAR    = -7.6246189861593985f;   // -log(2048)
static constexpr float INV_TAU     = 2.8571428571428571f;    // 1/0.35
static constexpr float INV_SQRT_R  = 0.17677669529663687f;   // 1/sqrt(32)

// ---------------------------------------------------------------------------
// Generic 128x128x16 fp32 tiled GEMM, 256 threads, 8x8 per thread.
// MODE 0: QKV  (A=x, B piecewise Wq|Wk|Wv, bias piecewise, out ld=2304)
// MODE 1: Wz   (A = concat[x,H0,Htl,H0*Htl] fetched on the fly, K=3072,
//               epilogue z=sigmoid(.+bz); out = (1-z)*H0 + z*Htl)
// MODE 2: Wo   (A=hout, plain bias, out=d_out)
// ---------------------------------------------------------------------------
template<int MODE>
__global__ __launch_bounds__(256) void gemm128(
    const float* __restrict__ A,
    const float* __restrict__ W0, const float* __restrict__ W1, const float* __restrict__ W2,
    const float* __restrict__ b0, const float* __restrict__ b1, const float* __restrict__ b2,
    const float* __restrict__ h0, const float* __restrict__ htl,
    float* __restrict__ out, int K, int ldo)
{
    __shared__ float As[16][132];   // [k][m] transposed
    __shared__ float Bs[16][132];   // [k][n]
    const int tid = threadIdx.x;
    const int tx = tid & 15, ty = tid >> 4;
    const int n0 = blockIdx.x * 128, m0 = blockIdx.y * 128;

    float acc[8][8];
#pragma unroll
    for (int i = 0; i < 8; ++i)
#pragma unroll
        for (int j = 0; j < 8; ++j) acc[i][j] = 0.f;

    for (int k0 = 0; k0 < K; k0 += 16) {
        // ---- stage A tile (128 rows x 16 cols), transposed
#pragma unroll
        for (int s = 0; s < 2; ++s) {
            int idx = tid + s * 256;
            int mm = idx >> 2, c4 = (idx & 3) * 4;
            int t = m0 + mm;
            int c = k0 + c4;
            float4 av;
            if (MODE == 1) {
                if (c < 768)        av = *(const float4*)&A  [t*768 + c];
                else if (c < 1536)  av = *(const float4*)&h0 [t*768 + (c - 768)];
                else if (c < 2304)  av = *(const float4*)&htl[t*768 + (c - 1536)];
                else {
                    float4 p = *(const float4*)&h0 [t*768 + (c - 2304)];
                    float4 q = *(const float4*)&htl[t*768 + (c - 2304)];
                    av = make_float4(p.x*q.x, p.y*q.y, p.z*q.z, p.w*q.w);
                }
            } else {
                av = *(const float4*)&A[t*768 + c];
            }
            As[c4+0][mm] = av.x; As[c4+1][mm] = av.y;
            As[c4+2][mm] = av.z; As[c4+3][mm] = av.w;
        }
        // ---- stage B tile (16 rows x 128 cols)
#pragma unroll
        for (int s = 0; s < 2; ++s) {
            int idx = tid + s * 256;
            int kk = idx >> 5, n4 = (idx & 31) * 4;
            int n = n0 + n4;
            const float* w; int nn;
            if (MODE == 0) {
                if (n < 768)       { w = W0; nn = n; }
                else if (n < 1536) { w = W1; nn = n - 768; }
                else               { w = W2; nn = n - 1536; }
            } else { w = W0; nn = n; }
            float4 bv = *(const float4*)&w[(k0 + kk)*768 + nn];
            *(float4*)&Bs[kk][n4] = bv;
        }
        __syncthreads();
#pragma unroll
        for (int kk = 0; kk < 16; ++kk) {
            float a[8], b[8];
            *(float4*)&a[0] = *(const float4*)&As[kk][ty*8];
            *(float4*)&a[4] = *(const float4*)&As[kk][ty*8 + 4];
            *(float4*)&b[0] = *(const float4*)&Bs[kk][tx*8];
            *(float4*)&b[4] = *(const float4*)&Bs[kk][tx*8 + 4];
#pragma unroll
            for (int i = 0; i < 8; ++i)
#pragma unroll
                for (int j = 0; j < 8; ++j) acc[i][j] = fmaf(a[i], b[j], acc[i][j]);
        }
        __syncthreads();
    }
    // ---- epilogue
#pragma unroll
    for (int i = 0; i < 8; ++i) {
        int m = m0 + ty*8 + i;
#pragma unroll
        for (int j = 0; j < 8; ++j) {
            int n = n0 + tx*8 + j;
            float v = acc[i][j];
            if (MODE == 0) {
                float bb = (n < 768) ? b0[n] : (n < 1536) ? b1[n-768] : b2[n-1536];
                out[m*ldo + n] = v + bb;
            } else if (MODE == 1) {
                float z = 1.f / (1.f + expf(-(v + b0[n])));
                int idx = m*768 + n;
                out[idx] = (1.f - z)*h0[idx] + z*htl[idx];
            } else {
                out[m*ldo + n] = v + b0[n];
            }
        }
    }
}

// ---------------------------------------------------------------------------
// Low-rank projections: Qr (scaled by 1/sqrt(R)), Kr, Vr, expVr
// grid (T/8, 3), block 256 = 8 t x 32 r
// ---------------------------------------------------------------------------
__global__ __launch_bounds__(256) void lowrank_proj(
    const float* __restrict__ qkv,
    const float* __restrict__ pq, const float* __restrict__ pk, const float* __restrict__ pv,
    float* __restrict__ qr, float* __restrict__ kr, float* __restrict__ vr,
    float* __restrict__ evr)
{
    int tid = threadIdx.x;
    int r = tid & 31, tl = tid >> 5;
    int t = blockIdx.x * 8 + tl;
    int sel = blockIdx.y;
    const float* src = qkv + t*2304 + sel*768;
    const float* P = (sel == 0) ? pq : (sel == 1) ? pk : pv;
    float acc = 0.f;
    for (int k = 0; k < 768; k += 4) {
        float4 s4 = *(const float4*)&src[k];
        acc = fmaf(s4.x, P[(k+0)*32 + r], acc);
        acc = fmaf(s4.y, P[(k+1)*32 + r], acc);
        acc = fmaf(s4.z, P[(k+2)*32 + r], acc);
        acc = fmaf(s4.w, P[(k+3)*32 + r], acc);
    }
    if (sel == 0)      qr[t*32 + r] = acc * INV_SQRT_R;
    else if (sel == 1) kr[t*32 + r] = acc;
    else { vr[t*32 + r] = acc; evr[t*32 + r] = expf(acc); }
}

// ---------------------------------------------------------------------------
// Inclusive cumulative max over time per feature r. grid R, block 256 (8 el/thr)
// ---------------------------------------------------------------------------
__global__ __launch_bounds__(256) void cummax_vr(const float* __restrict__ vr,
                                                 float* __restrict__ ms)
{
    __shared__ float part[256];
    int r = blockIdx.x, tid = threadIdx.x;
    int t0 = tid * 8;
    float v[8];
    float run = -INFINITY;
#pragma unroll
    for (int e = 0; e < 8; ++e) { run = fmaxf(run, vr[(t0+e)*32 + r]); v[e] = run; }
    part[tid] = run;
    __syncthreads();
    for (int off = 1; off < 256; off <<= 1) {
        float other = (tid >= off) ? part[tid - off] : -INFINITY;
        __syncthreads();
        part[tid] = fmaxf(part[tid], other);
        __syncthreads();
    }
    float excl = (tid > 0) ? part[tid - 1] : -INFINITY;
#pragma unroll
    for (int e = 0; e < 8; ++e) ms[(t0+e)*32 + r] = fmaxf(v[e], excl);
}

// ---------------------------------------------------------------------------
// Seed attention: Lr[i][r] = log(max( (sum_{j<=i} sig(S_ij^2+b) expVr[j][r]) * e^-m, eps)) + m
// grid T, block 256 (thread per j stride 256, 32 accumulators)
// ---------------------------------------------------------------------------
__global__ __launch_bounds__(256) void seed_attn(
    const float* __restrict__ qr, const float* __restrict__ kr,
    const float* __restrict__ evr, const float* __restrict__ ms,
    float* __restrict__ lr)
{
    __shared__ float qs[32];
    __shared__ float red[256][33];
    int i = blockIdx.x, tid = threadIdx.x;
    if (tid < 32) qs[tid] = qr[i*32 + tid];
    __syncthreads();
    float acc[32];
#pragma unroll
    for (int r = 0; r < 32; ++r) acc[r] = 0.f;
    for (int j = tid; j <= i; j += 256) {
        const float* krow = &kr[j*32];
        float s = 0.f;
#pragma unroll
        for (int r4 = 0; r4 < 32; r4 += 4) {
            float4 kv = *(const float4*)&krow[r4];
            s = fmaf(qs[r4+0], kv.x, s); s = fmaf(qs[r4+1], kv.y, s);
            s = fmaf(qs[r4+2], kv.z, s); s = fmaf(qs[r4+3], kv.w, s);
        }
        float a = 1.f / (1.f + expf(-(s*s + B_SCALAR)));
        const float* ev = &evr[j*32];
#pragma unroll
        for (int r4 = 0; r4 < 32; r4 += 4) {
            float4 e4 = *(const float4*)&ev[r4];
            acc[r4+0] = fmaf(a, e4.x, acc[r4+0]); acc[r4+1] = fmaf(a, e4.y, acc[r4+1]);
            acc[r4+2] = fmaf(a, e4.z, acc[r4+2]); acc[r4+3] = fmaf(a, e4.w, acc[r4+3]);
        }
    }
#pragma unroll
    for (int r = 0; r < 32; ++r) red[tid][r] = acc[r];
    __syncthreads();
    if (tid < 32) {
        int r = tid;
        float y = 0.f;
        for (int u = 0; u < 256; ++u) y += red[u][r];
        float m = ms[i*32 + r];
        lr[i*32 + r] = logf(fmaxf(y * expf(-m), 1e-30f)) + m;
    }
}

// ---------------------------------------------------------------------------
// H0 = Lr @ up_w.  grid T, block 256 (3 cols each), K=32
// ---------------------------------------------------------------------------
__global__ __launch_bounds__(256) void up_proj(const float* __restrict__ lr,
                                               const float* __restrict__ up,
                                               float* __restrict__ h0)
{
    __shared__ float ls[32];
    int t = blockIdx.x, tid = threadIdx.x;
    if (tid < 32) ls[tid] = lr[t*32 + tid];
    __syncthreads();
    for (int c = tid; c < 768; c += 256) {
        float acc = 0.f;
#pragma unroll
        for (int rr = 0; rr < 32; ++rr) acc = fmaf(ls[rr], up[rr*768 + c], acc);
        h0[t*768 + c] = acc;
    }
}

// ---------------------------------------------------------------------------
// Per-(t,h) inverse L2 norms of Qh and Kh. grid T, block 768 (wave per head)
// ---------------------------------------------------------------------------
__global__ void head_norms(const float* __restrict__ qkv,
                           float* __restrict__ invq, float* __restrict__ invk)
{
    int t = blockIdx.x, tid = threadIdx.x;
    int h = tid >> 6, d = tid & 63;
    float q = qkv[t*2304 + h*64 + d];
    float k = qkv[t*2304 + 768 + h*64 + d];
    float sq = q*q, sk = k*k;
#pragma unroll
    for (int off = 32; off; off >>= 1) { sq += __shfl_xor(sq, off); sk += __shfl_xor(sk, off); }
    if (d == 0) {
        invq[t*12 + h] = 1.f / fmaxf(sqrtf(sq), 1e-12f);
        invk[t*12 + h] = 1.f / fmaxf(sqrtf(sk), 1e-12f);
    }
}

// ---------------------------------------------------------------------------
// Sliding past-window (129) max of V per feature + Vexp = exp(V - m_near)
// grid (C/64, T/64), block 256. LDS tile 192 x 64.
// ---------------------------------------------------------------------------
__global__ __launch_bounds__(256) void slide_max(const float* __restrict__ qkv,
                                                 float* __restrict__ mnear,
                                                 float* __restrict__ vexp)
{
    __shared__ float vs[192][64];
    int c0 = blockIdx.x * 64, t0 = blockIdx.y * 64;
    int tid = threadIdx.x;
#pragma unroll
    for (int s = 0; s < 12; ++s) {
        int idx = tid + s * 256;
        int rr = idx >> 4, c4 = (idx & 15) * 4;
        int t = t0 - 128 + rr;
        float4 v4;
        if (t < 0) v4 = make_float4(-INFINITY, -INFINITY, -INFINITY, -INFINITY);
        else       v4 = *(const float4*)&qkv[t*2304 + 1536 + c0 + c4];
        *(float4*)&vs[rr][c4] = v4;
    }
    __syncthreads();
    int c = tid & 63, tg = tid >> 6;
    for (int u = 0; u < 16; ++u) {
        int tl = tg * 16 + u;
        float m = -INFINITY;
        for (int s = 0; s < 129; ++s) m = fmaxf(m, vs[tl + s][c]);
        float v = vs[tl + 128][c];
        int t = t0 + tl;
        mnear[t*768 + c0 + c] = m;
        vexp [t*768 + c0 + c] = expf(v - m);
    }
}

// ---------------------------------------------------------------------------
// Banded cos^2 attention weights. grid (H, T/16), block 256.
// A[h][i][jj] = sigmoid(cos^2/tau + b), j = i-128+jj, jj in [0,129)
// ---------------------------------------------------------------------------
__global__ __launch_bounds__(256) void near_cos(const float* __restrict__ qkv,
                                                const float* __restrict__ invq,
                                                const float* __restrict__ invk,
                                                float* __restrict__ aband)
{
    __shared__ float Qs[16][65];
    __shared__ float Ks[144][65];
    int hh = blockIdx.x, i0 = blockIdx.y * 16, tid = threadIdx.x;
    {   // stage Q (16 x 64), normalized
        int ii = tid >> 4, d4 = (tid & 15) * 4;
        float4 q4 = *(const float4*)&qkv[(i0+ii)*2304 + hh*64 + d4];
        float s = invq[(i0+ii)*12 + hh];
        Qs[ii][d4+0] = q4.x*s; Qs[ii][d4+1] = q4.y*s;
        Qs[ii][d4+2] = q4.z*s; Qs[ii][d4+3] = q4.w*s;
    }
#pragma unroll
    for (int v = 0; v < 9; ++v) {   // stage K rows j in [i0-128, i0+15]
        int idx = tid + v * 256;
        int rr = idx >> 4, d4 = (idx & 15) * 4;
        int j = i0 - 128 + rr;
        float4 k4 = make_float4(0.f, 0.f, 0.f, 0.f);
        float s = 0.f;
        if (j >= 0) { k4 = *(const float4*)&qkv[j*2304 + 768 + hh*64 + d4]; s = invk[j*12 + hh]; }
        Ks[rr][d4+0] = k4.x*s; Ks[rr][d4+1] = k4.y*s;
        Ks[rr][d4+2] = k4.z*s; Ks[rr][d4+3] = k4.w*s;
    }
    __syncthreads();
    int ii = tid & 15, jg = tid >> 4;
#pragma unroll
    for (int v = 0; v < 9; ++v) {
        int jj = jg + (v << 4);
        if (jj <= 128) {
            int rr = ii + jj;
            float s = 0.f;
            for (int d = 0; d < 64; ++d) s = fmaf(Qs[ii][d], Ks[rr][d], s);
            int j = i0 + ii - 128 + jj;
            float a = 0.f;
            if (j >= 0) a = 1.f / (1.f + expf(-(s*s*INV_TAU + B_SCALAR)));
            aband[(hh*2048 + i0 + ii)*132 + jj] = a;
        }
    }
}

// ---------------------------------------------------------------------------
// Banded PV + LASER epilogue: Hn = log(max(A @ Vexp, eps)) + m_near
// grid (H, T/16), block 256 (thread = (d, 4 rows))
// ---------------------------------------------------------------------------
__global__ __launch_bounds__(256) void near_pv(const float* __restrict__ aband,
                                               const float* __restrict__ vexp,
                                               const float* __restrict__ mnear,
                                               float* __restrict__ hn)
{
    __shared__ float Vs[144][64];
    __shared__ float As[16][132];
    int hh = blockIdx.x, i0 = blockIdx.y * 16, tid = threadIdx.x;
#pragma unroll
    for (int v = 0; v < 9; ++v) {
        int idx = tid + v * 256;
        int rr = idx >> 4, d4 = (idx & 15) * 4;
        int j = i0 - 128 + rr;
        float4 v4 = make_float4(0.f, 0.f, 0.f, 0.f);
        if (j >= 0) v4 = *(const float4*)&vexp[j*768 + hh*64 + d4];
        *(float4*)&Vs[rr][d4] = v4;
    }
    for (int idx = tid; idx < 16*129; idx += 256) {
        int ii = idx / 129, jj = idx - ii*129;
        As[ii][jj] = aband[(hh*2048 + i0 + ii)*132 + jj];
    }
    __syncthreads();
    int d = tid & 63, ig = tid >> 6;
    float acc[4] = {0.f, 0.f, 0.f, 0.f};
    for (int jj = 0; jj <= 128; ++jj) {
#pragma unroll
        for (int q = 0; q < 4; ++q) {
            int ii = ig*4 + q;
            acc[q] = fmaf(As[ii][jj], Vs[ii + jj][d], acc[q]);
        }
    }
#pragma unroll
    for (int q = 0; q < 4; ++q) {
        int ii = ig*4 + q;
        int idx = (i0 + ii)*768 + hh*64 + d;
        hn[idx] = logf(fmaxf(acc[q], 1e-30f)) + mnear[idx];
    }
}

// ---------------------------------------------------------------------------
// Head-wise sigmoid gate, in place: Htl = Hn * sigmoid(<Hn, gate_u[h]> + gate_b[h])
// grid T*H/4, block 256 (wave per (t,h))
// ---------------------------------------------------------------------------
__global__ __launch_bounds__(256) void gate_kernel(const float* __restrict__ gu,
                                                   const float* __restrict__ gb,
                                                   float* __restrict__ hn)
{
    int w = blockIdx.x * 4 + (threadIdx.x >> 6);
    int lane = threadIdx.x & 63;
    int t = w / 12, h = w - t*12;
    int idx = t*768 + h*64 + lane;
    float v = hn[idx];
    float s = v * gu[h*64 + lane];
#pragma unroll
    for (int off = 32; off; off >>= 1) s += __shfl_xor(s, off);
    float g = 1.f / (1.f + expf(-(s + gb[h])));
    hn[idx] = v * g;
}

// ---------------------------------------------------------------------------
extern "C" void kernel_launch(void* const* d_in, const int* in_sizes, int n_in,
                              void* d_out, int out_size, void* d_ws, size_t ws_size,
                              hipStream_t stream)
{
    const float* x  = (const float*)d_in[0];
    const float* wq = (const float*)d_in[1];  const float* bq = (const float*)d_in[2];
    const float* wk = (const float*)d_in[3];  const float* bk = (const float*)d_in[4];
    const float* wv = (const float*)d_in[5];  const float* bv = (const float*)d_in[6];
    const float* wo = (const float*)d_in[7];  const float* bo = (const float*)d_in[8];
    const float* pq = (const float*)d_in[9];  const float* pk = (const float*)d_in[10];
    const float* pv = (const float*)d_in[11];
    const float* up = (const float*)d_in[12];
    const float* gu = (const float*)d_in[13]; const float* gb = (const float*)d_in[14];
    const float* wz = (const float*)d_in[15]; const float* bz = (const float*)d_in[16];
    float* out = (float*)d_out;

    float* w = (float*)d_ws;
    float* qkv  = w; w += 2048*2304;
    float* qr   = w; w += 2048*32;
    float* kr   = w; w += 2048*32;
    float* vr   = w; w += 2048*32;
    float* evr  = w; w += 2048*32;
    float* ms   = w; w += 2048*32;
    float* lr   = w; w += 2048*32;
    float* h0   = w; w += 2048*768;
    float* invq = w; w += 2048*12;
    float* invk = w; w += 2048*12;
    float* mnear= w; w += 2048*768;
    float* vexp = w; w += 2048*768;
    float* aband= w; w += 12*2048*132;
    float* hn   = w; w += 2048*768;   // becomes Htilde in place after gate
    float* hout = w; w += 2048*768;

    // 0) QKV projections
    gemm128<0><<<dim3(18,16), 256, 0, stream>>>(x, wq, wk, wv, bq, bk, bv,
                                                nullptr, nullptr, qkv, 768, 2304);
    // 1) low-rank path
    lowrank_proj<<<dim3(256,3), 256, 0, stream>>>(qkv, pq, pk, pv, qr, kr, vr, evr);
    cummax_vr<<<32, 256, 0, stream>>>(vr, ms);
    seed_attn<<<2048, 256, 0, stream>>>(qr, kr, evr, ms, lr);
    up_proj<<<2048, 256, 0, stream>>>(lr, up, h0);
    // 2) near-field path
    head_norms<<<2048, 768, 0, stream>>>(qkv, invq, invk);
    slide_max<<<dim3(12,32), 256, 0, stream>>>(qkv, mnear, vexp);
    near_cos<<<dim3(12,128), 256, 0, stream>>>(qkv, invq, invk, aband);
    near_pv<<<dim3(12,128), 256, 0, stream>>>(aband, vexp, mnear, hn);
    // 3) gate
    gate_kernel<<<2048*12/4, 256, 0, stream>>>(gu, gb, hn);
    // 4) GRU blend + output projection
    gemm128<1><<<dim3(6,16), 256, 0, stream>>>(x, wz, nullptr, nullptr, bz, nullptr, nullptr,
                                               h0, hn, hout, 3072, 768);
    gemm128<2><<<dim3(6,16), 256, 0, stream>>>(hout, wo, nullptr, nullptr, bo, nullptr, nullptr,
                                               nullptr, nullptr, out, 768, 768);
}

// Round 2
// 357.087 us; speedup vs baseline: 2.7727x; 2.7727x over previous
//
#include <hip/hip_runtime.h>
#include <math.h>

// Problem constants (fixed by harness: B=1, T=2048, C=768, H=12, D=64, R=32, K0=128)
static constexpr float B_SCALAR    = -7.6246189861593985f;   // -log(2048)
static constexpr float INV_TAU     = 2.8571428571428571f;    // 1/0.35
static constexpr float INV_SQRT_R  = 0.17677669529663687f;   // 1/sqrt(32)

typedef __attribute__((ext_vector_type(8))) short bf16x8;
typedef __attribute__((ext_vector_type(4))) float f32x4;

__device__ __forceinline__ unsigned short f2b(float f) {
    union { float f; unsigned int u; } v; v.f = f;
    unsigned int r = v.u + 0x7fffu + ((v.u >> 16) & 1u);
    return (unsigned short)(r >> 16);
}

typedef const __attribute__((address_space(1))) unsigned int* gp1_t;
typedef __attribute__((address_space(3))) unsigned int* lp3_t;
__device__ __forceinline__ void gload16(const unsigned short* g, unsigned short* l) {
    __builtin_amdgcn_global_load_lds((gp1_t)g, (lp3_t)l, 16, 0, 0);
}

// ---------------------------------------------------------------------------
// bf16 MFMA GEMM: C[m][n] = sum_k A[m][k] * Bt[n][k]   (Bt = B^T, bf16)
// 128x128 tile, BK=64, 256 threads = 4 waves (2x2), 4x4 16x16 frags per wave.
// MODE 0: QKV  (A=xb, out fp32 qkv ld 2304, bias=bqkv)
// MODE 1: Wz   (A piecewise xb|h0b|htlb|prodb per 768-K-chunk, K=3072;
//               epilogue z=sigmoid(acc+bz); outb = bf16((1-z)*h0 + z*htl))
// MODE 2: Wo   (A=houtb, out fp32 d_out, bias=bo)
// ---------------------------------------------------------------------------
template<int MODE>
__global__ __launch_bounds__(256) void gemm_mfma(
    const unsigned short* __restrict__ A0, const unsigned short* __restrict__ A1,
    const unsigned short* __restrict__ A2, const unsigned short* __restrict__ A3,
    const unsigned short* __restrict__ Bt, const float* __restrict__ bias,
    const float* __restrict__ h0, const float* __restrict__ htl,
    float* __restrict__ outf, unsigned short* __restrict__ outb,
    int K, int ldo)
{
    __shared__ unsigned short As[128*64];
    __shared__ unsigned short Bs[128*64];
    const int tid = threadIdx.x;
    const int lane = tid & 63, wid = tid >> 6;
    const int wr = wid >> 1, wc = wid & 1;
    const int fr = lane & 15, fq = lane >> 4;
    const int n0 = blockIdx.x * 128, m0 = blockIdx.y * 128;

    f32x4 acc[4][4];
#pragma unroll
    for (int mi = 0; mi < 4; ++mi)
#pragma unroll
        for (int ni = 0; ni < 4; ++ni) acc[mi][ni] = (f32x4){0.f, 0.f, 0.f, 0.f};

    for (int k0 = 0; k0 < K; k0 += 64) {
        const unsigned short* Ap;
        int k0l, ldA;
        if (MODE == 1) {
            int p = k0 / 768;
            Ap = (p == 0) ? A0 : (p == 1) ? A1 : (p == 2) ? A2 : A3;
            k0l = k0 - p * 768; ldA = 768;
        } else { Ap = A0; k0l = k0; ldA = K; }
        // ---- stage both tiles: 1024 16B chunks each, 8 rows' worth per wave-iter
#pragma unroll
        for (int i = 0; i < 4; ++i) {
            int cb = i * 256 + wid * 64;           // wave-uniform chunk base
            int c  = cb + lane;
            int r = c >> 3, col = (c & 7) * 8;
            gload16(Ap + (size_t)(m0 + r) * ldA + k0l + col, &As[cb * 8]);
            gload16(Bt + (size_t)(n0 + r) * K   + k0  + col, &Bs[cb * 8]);
        }
        __syncthreads();                            // drains vmcnt
#pragma unroll
        for (int kk = 0; kk < 64; kk += 32) {
            bf16x8 af[4], bfr[4];
#pragma unroll
            for (int mi = 0; mi < 4; ++mi)
                af[mi] = *(const bf16x8*)&As[(wr*64 + mi*16 + fr)*64 + kk + fq*8];
#pragma unroll
            for (int ni = 0; ni < 4; ++ni)
                bfr[ni] = *(const bf16x8*)&Bs[(wc*64 + ni*16 + fr)*64 + kk + fq*8];
#pragma unroll
            for (int mi = 0; mi < 4; ++mi)
#pragma unroll
                for (int ni = 0; ni < 4; ++ni)
                    acc[mi][ni] = __builtin_amdgcn_mfma_f32_16x16x32_bf16(
                        af[mi], bfr[ni], acc[mi][ni], 0, 0, 0);
        }
        __syncthreads();
    }
    // ---- epilogue: C row = fq*4+v, col = fr (m89-verified mapping)
#pragma unroll
    for (int mi = 0; mi < 4; ++mi)
#pragma unroll
        for (int ni = 0; ni < 4; ++ni)
#pragma unroll
            for (int v = 0; v < 4; ++v) {
                int m = m0 + wr*64 + mi*16 + fq*4 + v;
                int n = n0 + wc*64 + ni*16 + fr;
                float val = acc[mi][ni][v];
                if (MODE == 1) {
                    float z = 1.f / (1.f + expf(-(val + bias[n])));
                    size_t idx = (size_t)m * 768 + n;
                    outb[idx] = f2b((1.f - z) * h0[idx] + z * htl[idx]);
                } else {
                    outf[(size_t)m * ldo + n] = val + bias[n];
                }
            }
}

// ---------------------------------------------------------------------------
// Prep kernels: fp32 -> bf16 cast, weight transpose+cast, bias concat
// ---------------------------------------------------------------------------
__global__ __launch_bounds__(256) void cvt_bf16(const float* __restrict__ in,
                                                unsigned short* __restrict__ out, int n4)
{
    int i = blockIdx.x * 256 + threadIdx.x;
    if (i < n4) {
        float4 v = *(const float4*)&in[i * 4];
        out[i*4+0] = f2b(v.x); out[i*4+1] = f2b(v.y);
        out[i*4+2] = f2b(v.z); out[i*4+3] = f2b(v.w);
    }
}

// W [K][N] fp32 -> Wt [N][K] bf16, 32x32 LDS tiles, 256 thr (32x8)
__global__ __launch_bounds__(256) void transpose_w(const float* __restrict__ w,
                                                   unsigned short* __restrict__ wt,
                                                   int K, int N)
{
    __shared__ float tile[32][33];
    int kb = blockIdx.x * 32, nb = blockIdx.y * 32;
    int tx = threadIdx.x & 31, ty = threadIdx.x >> 5;
#pragma unroll
    for (int s = 0; s < 32; s += 8)
        tile[ty + s][tx] = w[(size_t)(kb + ty + s) * N + nb + tx];
    __syncthreads();
#pragma unroll
    for (int s = 0; s < 32; s += 8)
        wt[(size_t)(nb + ty + s) * K + kb + tx] = f2b(tile[tx][ty + s]);
}

__global__ void concat_bias(const float* __restrict__ bq, const float* __restrict__ bk,
                            const float* __restrict__ bv, float* __restrict__ o)
{
    int n = blockIdx.x * 256 + threadIdx.x;
    if (n < 2304) o[n] = (n < 768) ? bq[n] : (n < 1536) ? bk[n - 768] : bv[n - 1536];
}

// h0,hn fp32 -> bf16 copies + product (A-operand pieces for Wz)
__global__ __launch_bounds__(256) void build_gru_inputs(
    const float* __restrict__ h0, const float* __restrict__ hn,
    unsigned short* __restrict__ h0b, unsigned short* __restrict__ htlb,
    unsigned short* __restrict__ prodb, int n4)
{
    int i = blockIdx.x * 256 + threadIdx.x;
    if (i < n4) {
        float4 a = *(const float4*)&h0[i * 4];
        float4 b = *(const float4*)&hn[i * 4];
        h0b[i*4+0] = f2b(a.x); h0b[i*4+1] = f2b(a.y); h0b[i*4+2] = f2b(a.z); h0b[i*4+3] = f2b(a.w);
        htlb[i*4+0] = f2b(b.x); htlb[i*4+1] = f2b(b.y); htlb[i*4+2] = f2b(b.z); htlb[i*4+3] = f2b(b.w);
        prodb[i*4+0] = f2b(a.x*b.x); prodb[i*4+1] = f2b(a.y*b.y);
        prodb[i*4+2] = f2b(a.z*b.z); prodb[i*4+3] = f2b(a.w*b.w);
    }
}

// ---------------------------------------------------------------------------
// Low-rank projections: Qr (scaled), Kr, Vr, expVr.  grid (T/8, 3), block 256
// ---------------------------------------------------------------------------
__global__ __launch_bounds__(256) void lowrank_proj(
    const float* __restrict__ qkv,
    const float* __restrict__ pq, const float* __restrict__ pk, const float* __restrict__ pv,
    float* __restrict__ qr, float* __restrict__ kr, float* __restrict__ vr,
    float* __restrict__ evr)
{
    int tid = threadIdx.x;
    int r = tid & 31, tl = tid >> 5;
    int t = blockIdx.x * 8 + tl;
    int sel = blockIdx.y;
    const float* src = qkv + t*2304 + sel*768;
    const float* P = (sel == 0) ? pq : (sel == 1) ? pk : pv;
    float acc = 0.f;
    for (int k = 0; k < 768; k += 4) {
        float4 s4 = *(const float4*)&src[k];
        acc = fmaf(s4.x, P[(k+0)*32 + r], acc);
        acc = fmaf(s4.y, P[(k+1)*32 + r], acc);
        acc = fmaf(s4.z, P[(k+2)*32 + r], acc);
        acc = fmaf(s4.w, P[(k+3)*32 + r], acc);
    }
    if (sel == 0)      qr[t*32 + r] = acc * INV_SQRT_R;
    else if (sel == 1) kr[t*32 + r] = acc;
    else { vr[t*32 + r] = acc; evr[t*32 + r] = expf(acc); }
}

// ---------------------------------------------------------------------------
// Inclusive cumulative max over time per feature r. grid R, block 256
// ---------------------------------------------------------------------------
__global__ __launch_bounds__(256) void cummax_vr(const float* __restrict__ vr,
                                                 float* __restrict__ ms)
{
    __shared__ float part[256];
    int r = blockIdx.x, tid = threadIdx.x;
    int t0 = tid * 8;
    float v[8];
    float run = -INFINITY;
#pragma unroll
    for (int e = 0; e < 8; ++e) { run = fmaxf(run, vr[(t0+e)*32 + r]); v[e] = run; }
    part[tid] = run;
    __syncthreads();
    for (int off = 1; off < 256; off <<= 1) {
        float other = (tid >= off) ? part[tid - off] : -INFINITY;
        __syncthreads();
        part[tid] = fmaxf(part[tid], other);
        __syncthreads();
    }
    float excl = (tid > 0) ? part[tid - 1] : -INFINITY;
#pragma unroll
    for (int e = 0; e < 8; ++e) ms[(t0+e)*32 + r] = fmaxf(v[e], excl);
}

// ---------------------------------------------------------------------------
// Seed attention. grid T, block 256
// ---------------------------------------------------------------------------
__global__ __launch_bounds__(256) void seed_attn(
    const float* __restrict__ qr, const float* __restrict__ kr,
    const float* __restrict__ evr, const float* __restrict__ ms,
    float* __restrict__ lr)
{
    __shared__ float qs[32];
    __shared__ float red[256][33];
    int i = blockIdx.x, tid = threadIdx.x;
    if (tid < 32) qs[tid] = qr[i*32 + tid];
    __syncthreads();
    float acc[32];
#pragma unroll
    for (int r = 0; r < 32; ++r) acc[r] = 0.f;
    for (int j = tid; j <= i; j += 256) {
        const float* krow = &kr[j*32];
        float s = 0.f;
#pragma unroll
        for (int r4 = 0; r4 < 32; r4 += 4) {
            float4 kv = *(const float4*)&krow[r4];
            s = fmaf(qs[r4+0], kv.x, s); s = fmaf(qs[r4+1], kv.y, s);
            s = fmaf(qs[r4+2], kv.z, s); s = fmaf(qs[r4+3], kv.w, s);
        }
        float a = 1.f / (1.f + expf(-(s*s + B_SCALAR)));
        const float* ev = &evr[j*32];
#pragma unroll
        for (int r4 = 0; r4 < 32; r4 += 4) {
            float4 e4 = *(const float4*)&ev[r4];
            acc[r4+0] = fmaf(a, e4.x, acc[r4+0]); acc[r4+1] = fmaf(a, e4.y, acc[r4+1]);
            acc[r4+2] = fmaf(a, e4.z, acc[r4+2]); acc[r4+3] = fmaf(a, e4.w, acc[r4+3]);
        }
    }
#pragma unroll
    for (int r = 0; r < 32; ++r) red[tid][r] = acc[r];
    __syncthreads();
    if (tid < 32) {
        int r = tid;
        float y = 0.f;
        for (int u = 0; u < 256; ++u) y += red[u][r];
        float m = ms[i*32 + r];
        lr[i*32 + r] = logf(fmaxf(y * expf(-m), 1e-30f)) + m;
    }
}

// ---------------------------------------------------------------------------
// H0 = Lr @ up_w.  grid T, block 256, K=32
// ---------------------------------------------------------------------------
__global__ __launch_bounds__(256) void up_proj(const float* __restrict__ lr,
                                               const float* __restrict__ up,
                                               float* __restrict__ h0)
{
    __shared__ float ls[32];
    int t = blockIdx.x, tid = threadIdx.x;
    if (tid < 32) ls[tid] = lr[t*32 + tid];
    __syncthreads();
    for (int c = tid; c < 768; c += 256) {
        float acc = 0.f;
#pragma unroll
        for (int rr = 0; rr < 32; ++rr) acc = fmaf(ls[rr], up[rr*768 + c], acc);
        h0[t*768 + c] = acc;
    }
}

// ---------------------------------------------------------------------------
// Per-(t,h) inverse L2 norms. grid T, block 768
// ---------------------------------------------------------------------------
__global__ void head_norms(const float* __restrict__ qkv,
                           float* __restrict__ invq, float* __restrict__ invk)
{
    int t = blockIdx.x, tid = threadIdx.x;
    int h = tid >> 6, d = tid & 63;
    float q = qkv[t*2304 + h*64 + d];
    float k = qkv[t*2304 + 768 + h*64 + d];
    float sq = q*q, sk = k*k;
#pragma unroll
    for (int off = 32; off; off >>= 1) { sq += __shfl_xor(sq, off); sk += __shfl_xor(sk, off); }
    if (d == 0) {
        invq[t*12 + h] = 1.f / fmaxf(sqrtf(sq), 1e-12f);
        invk[t*12 + h] = 1.f / fmaxf(sqrtf(sk), 1e-12f);
    }
}

// ---------------------------------------------------------------------------
// Sliding past-window (129) max of V + Vexp = exp(V - m). grid (C/64, T/64)
// ---------------------------------------------------------------------------
__global__ __launch_bounds__(256) void slide_max(const float* __restrict__ qkv,
                                                 float* __restrict__ mnear,
                                                 float* __restrict__ vexp)
{
    __shared__ float vs[192][64];
    int c0 = blockIdx.x * 64, t0 = blockIdx.y * 64;
    int tid = threadIdx.x;
#pragma unroll
    for (int s = 0; s < 12; ++s) {
        int idx = tid + s * 256;
        int rr = idx >> 4, c4 = (idx & 15) * 4;
        int t = t0 - 128 + rr;
        float4 v4;
        if (t < 0) v4 = make_float4(-INFINITY, -INFINITY, -INFINITY, -INFINITY);
        else       v4 = *(const float4*)&qkv[t*2304 + 1536 + c0 + c4];
        *(float4*)&vs[rr][c4] = v4;
    }
    __syncthreads();
    int c = tid & 63, tg = tid >> 6;
    for (int u = 0; u < 16; ++u) {
        int tl = tg * 16 + u;
        float m = -INFINITY;
        for (int s = 0; s < 129; ++s) m = fmaxf(m, vs[tl + s][c]);
        float v = vs[tl + 128][c];
        int t = t0 + tl;
        mnear[t*768 + c0 + c] = m;
        vexp [t*768 + c0 + c] = expf(v - m);
    }
}

// ---------------------------------------------------------------------------
// Banded cos^2 attention weights. grid (H, T/16), block 256
// ---------------------------------------------------------------------------
__global__ __launch_bounds__(256) void near_cos(const float* __restrict__ qkv,
                                                const float* __restrict__ invq,
                                                const float* __restrict__ invk,
                                                float* __restrict__ aband)
{
    __shared__ float Qs[16][65];
    __shared__ float Ks[144][65];
    int hh = blockIdx.x, i0 = blockIdx.y * 16, tid = threadIdx.x;
    {
        int ii = tid >> 4, d4 = (tid & 15) * 4;
        float4 q4 = *(const float4*)&qkv[(i0+ii)*2304 + hh*64 + d4];
        float s = invq[(i0+ii)*12 + hh];
        Qs[ii][d4+0] = q4.x*s; Qs[ii][d4+1] = q4.y*s;
        Qs[ii][d4+2] = q4.z*s; Qs[ii][d4+3] = q4.w*s;
    }
#pragma unroll
    for (int v = 0; v < 9; ++v) {
        int idx = tid + v * 256;
        int rr = idx >> 4, d4 = (idx & 15) * 4;
        int j = i0 - 128 + rr;
        float4 k4 = make_float4(0.f, 0.f, 0.f, 0.f);
        float s = 0.f;
        if (j >= 0) { k4 = *(const float4*)&qkv[j*2304 + 768 + hh*64 + d4]; s = invk[j*12 + hh]; }
        Ks[rr][d4+0] = k4.x*s; Ks[rr][d4+1] = k4.y*s;
        Ks[rr][d4+2] = k4.z*s; Ks[rr][d4+3] = k4.w*s;
    }
    __syncthreads();
    int ii = tid & 15, jg = tid >> 4;
#pragma unroll
    for (int v = 0; v < 9; ++v) {
        int jj = jg + (v << 4);
        if (jj <= 128) {
            int rr = ii + jj;
            float s = 0.f;
            for (int d = 0; d < 64; ++d) s = fmaf(Qs[ii][d], Ks[rr][d], s);
            int j = i0 + ii - 128 + jj;
            float a = 0.f;
            if (j >= 0) a = 1.f / (1.f + expf(-(s*s*INV_TAU + B_SCALAR)));
            aband[(hh*2048 + i0 + ii)*132 + jj] = a;
        }
    }
}

// ---------------------------------------------------------------------------
// Banded PV + LASER epilogue. grid (H, T/16), block 256
// ---------------------------------------------------------------------------
__global__ __launch_bounds__(256) void near_pv(const float* __restrict__ aband,
                                               const float* __restrict__ vexp,
                                               const float* __restrict__ mnear,
                                               float* __restrict__ hn)
{
    __shared__ float Vs[144][64];
    __shared__ float As[16][132];
    int hh = blockIdx.x, i0 = blockIdx.y * 16, tid = threadIdx.x;
#pragma unroll
    for (int v = 0; v < 9; ++v) {
        int idx = tid + v * 256;
        int rr = idx >> 4, d4 = (idx & 15) * 4;
        int j = i0 - 128 + rr;
        float4 v4 = make_float4(0.f, 0.f, 0.f, 0.f);
        if (j >= 0) v4 = *(const float4*)&vexp[j*768 + hh*64 + d4];
        *(float4*)&Vs[rr][d4] = v4;
    }
    for (int idx = tid; idx < 16*129; idx += 256) {
        int ii = idx / 129, jj = idx - ii*129;
        As[ii][jj] = aband[(hh*2048 + i0 + ii)*132 + jj];
    }
    __syncthreads();
    int d = tid & 63, ig = tid >> 6;
    float acc[4] = {0.f, 0.f, 0.f, 0.f};
    for (int jj = 0; jj <= 128; ++jj) {
#pragma unroll
        for (int q = 0; q < 4; ++q) {
            int ii = ig*4 + q;
            acc[q] = fmaf(As[ii][jj], Vs[ii + jj][d], acc[q]);
        }
    }
#pragma unroll
    for (int q = 0; q < 4; ++q) {
        int ii = ig*4 + q;
        int idx = (i0 + ii)*768 + hh*64 + d;
        hn[idx] = logf(fmaxf(acc[q], 1e-30f)) + mnear[idx];
    }
}

// ---------------------------------------------------------------------------
// Head-wise sigmoid gate, in place. grid T*H/4, block 256
// ---------------------------------------------------------------------------
__global__ __launch_bounds__(256) void gate_kernel(const float* __restrict__ gu,
                                                   const float* __restrict__ gb,
                                                   float* __restrict__ hn)
{
    int w = blockIdx.x * 4 + (threadIdx.x >> 6);
    int lane = threadIdx.x & 63;
    int t = w / 12, h = w - t*12;
    int idx = t*768 + h*64 + lane;
    float v = hn[idx];
    float s = v * gu[h*64 + lane];
#pragma unroll
    for (int off = 32; off; off >>= 1) s += __shfl_xor(s, off);
    float g = 1.f / (1.f + expf(-(s + gb[h])));
    hn[idx] = v * g;
}

// ---------------------------------------------------------------------------
extern "C" void kernel_launch(void* const* d_in, const int* in_sizes, int n_in,
                              void* d_out, int out_size, void* d_ws, size_t ws_size,
                              hipStream_t stream)
{
    const float* x  = (const float*)d_in[0];
    const float* wq = (const float*)d_in[1];  const float* bq = (const float*)d_in[2];
    const float* wk = (const float*)d_in[3];  const float* bk = (const float*)d_in[4];
    const float* wv = (const float*)d_in[5];  const float* bv = (const float*)d_in[6];
    const float* wo = (const float*)d_in[7];  const float* bo = (const float*)d_in[8];
    const float* pq = (const float*)d_in[9];  const float* pk = (const float*)d_in[10];
    const float* pv = (const float*)d_in[11];
    const float* up = (const float*)d_in[12];
    const float* gu = (const float*)d_in[13]; const float* gb = (const float*)d_in[14];
    const float* wz = (const float*)d_in[15]; const float* bz = (const float*)d_in[16];
    float* out = (float*)d_out;

    float* w = (float*)d_ws;
    float* qkv  = w; w += 2048*2304;
    float* qr   = w; w += 2048*32;
    float* kr   = w; w += 2048*32;
    float* vr   = w; w += 2048*32;
    float* evr  = w; w += 2048*32;
    float* ms   = w; w += 2048*32;
    float* lr   = w; w += 2048*32;
    float* h0   = w; w += 2048*768;
    float* invq = w; w += 2048*12;
    float* invk = w; w += 2048*12;
    float* mnear= w; w += 2048*768;
    float* vexp = w; w += 2048*768;
    float* aband= w; w += 12*2048*132;
    float* hn   = w; w += 2048*768;      // becomes Htilde after gate
    float* bqkv = w; w += 2304;
    unsigned short* xb     = (unsigned short*)w; w += 2048*768/2;
    unsigned short* wqkvT  = (unsigned short*)w; w += 2304*768/2;
    unsigned short* wzT    = (unsigned short*)w; w += 768*3072/2;
    unsigned short* woT    = (unsigned short*)w; w += 768*768/2;
    unsigned short* h0b    = (unsigned short*)w; w += 2048*768/2;
    unsigned short* htlb   = (unsigned short*)w; w += 2048*768/2;
    unsigned short* prodb  = (unsigned short*)w; w += 2048*768/2;
    unsigned short* houtb  = (unsigned short*)w; w += 2048*768/2;

    // ---- prep: bf16 casts + weight transposes
    cvt_bf16<<<1536, 256, 0, stream>>>(x, xb, 2048*768/4);
    transpose_w<<<dim3(24,24), 256, 0, stream>>>(wq, wqkvT,            768, 768);
    transpose_w<<<dim3(24,24), 256, 0, stream>>>(wk, wqkvT + 768*768,  768, 768);
    transpose_w<<<dim3(24,24), 256, 0, stream>>>(wv, wqkvT + 1536*768, 768, 768);
    transpose_w<<<dim3(96,24), 256, 0, stream>>>(wz, wzT, 3072, 768);
    transpose_w<<<dim3(24,24), 256, 0, stream>>>(wo, woT, 768, 768);
    concat_bias<<<9, 256, 0, stream>>>(bq, bk, bv, bqkv);

    // 0) QKV projections (bf16 MFMA, fp32 out)
    gemm_mfma<0><<<dim3(18,16), 256, 0, stream>>>(xb, nullptr, nullptr, nullptr,
        wqkvT, bqkv, nullptr, nullptr, qkv, nullptr, 768, 2304);

    // 1) low-rank path
    lowrank_proj<<<dim3(256,3), 256, 0, stream>>>(qkv, pq, pk, pv, qr, kr, vr, evr);
    cummax_vr<<<32, 256, 0, stream>>>(vr, ms);
    seed_attn<<<2048, 256, 0, stream>>>(qr, kr, evr, ms, lr);
    up_proj<<<2048, 256, 0, stream>>>(lr, up, h0);

    // 2) near-field path
    head_norms<<<2048, 768, 0, stream>>>(qkv, invq, invk);
    slide_max<<<dim3(12,32), 256, 0, stream>>>(qkv, mnear, vexp);
    near_cos<<<dim3(12,128), 256, 0, stream>>>(qkv, invq, invk, aband);
    near_pv<<<dim3(12,128), 256, 0, stream>>>(aband, vexp, mnear, hn);

    // 3) gate
    gate_kernel<<<2048*12/4, 256, 0, stream>>>(gu, gb, hn);

    // 4) GRU blend (bf16 MFMA, K=3072) + output projection (bf16 MFMA)
    build_gru_inputs<<<1536, 256, 0, stream>>>(h0, hn, h0b, htlb, prodb, 2048*768/4);
    gemm_mfma<1><<<dim3(6,16), 256, 0, stream>>>(xb, h0b, htlb, prodb,
        wzT, bz, h0, hn, nullptr, houtb, 3072, 768);
    gemm_mfma<2><<<dim3(6,16), 256, 0, stream>>>(houtb, nullptr, nullptr, nullptr,
        woT, bo, nullptr, nullptr, out, nullptr, 768, 768);
}

// Round 3
// 303.130 us; speedup vs baseline: 3.2663x; 1.1780x over previous
//
#include <hip/hip_runtime.h>
#include <math.h>

// Problem constants (fixed: B=1, T=2048, C=768, H=12, D=64, R=32, K0=128)
static constexpr float B_SCALAR    = -7.6246189861593985f;   // -log(2048)
static constexpr float INV_TAU     = 2.8571428571428571f;    // 1/0.35
static constexpr float INV_SQRT_R  = 0.17677669529663687f;   // 1/sqrt(32)

typedef __attribute__((ext_vector_type(8))) short bf16x8;
typedef __attribute__((ext_vector_type(4))) float f32x4;

__device__ __forceinline__ unsigned short f2b(float f) {
    union { float f; unsigned int u; } v; v.f = f;
    unsigned int r = v.u + 0x7fffu + ((v.u >> 16) & 1u);
    return (unsigned short)(r >> 16);
}

typedef const __attribute__((address_space(1))) unsigned int* gp1_t;
typedef __attribute__((address_space(3))) unsigned int* lp3_t;
__device__ __forceinline__ void gload16(const unsigned short* g, unsigned short* l) {
    __builtin_amdgcn_global_load_lds((gp1_t)g, (lp3_t)l, 16, 0, 0);
}

// ---------------------------------------------------------------------------
// bf16 MFMA GEMM, 128x128 tile, BK=64, double-buffered LDS + 2-phase prefetch.
// MODE 0: QKV   MODE 1: Wz (piecewise A, GRU epilogue)   MODE 2: Wo
// ---------------------------------------------------------------------------
template<int MODE>
__global__ __launch_bounds__(256) void gemm_mfma(
    const unsigned short* __restrict__ A0, const unsigned short* __restrict__ A1,
    const unsigned short* __restrict__ A2, const unsigned short* __restrict__ A3,
    const unsigned short* __restrict__ Bt, const float* __restrict__ bias,
    const float* __restrict__ h0, const float* __restrict__ htl,
    float* __restrict__ outf, unsigned short* __restrict__ outb,
    int K, int ldo)
{
    __shared__ unsigned short As[2][128*64];
    __shared__ unsigned short Bs[2][128*64];
    const int tid = threadIdx.x;
    const int lane = tid & 63, wid = tid >> 6;
    const int wr = wid >> 1, wc = wid & 1;
    const int fr = lane & 15, fq = lane >> 4;
    const int n0 = blockIdx.x * 128, m0 = blockIdx.y * 128;
    const int nt = K / 64;

    f32x4 acc[4][4];
#pragma unroll
    for (int mi = 0; mi < 4; ++mi)
#pragma unroll
        for (int ni = 0; ni < 4; ++ni) acc[mi][ni] = (f32x4){0.f, 0.f, 0.f, 0.f};

    auto stage = [&](int buf, int k0) {
        const unsigned short* Ap;
        int k0l, ldA;
        if (MODE == 1) {
            int p = k0 / 768;
            Ap = (p == 0) ? A0 : (p == 1) ? A1 : (p == 2) ? A2 : A3;
            k0l = k0 - p * 768; ldA = 768;
        } else { Ap = A0; k0l = k0; ldA = K; }
#pragma unroll
        for (int i = 0; i < 4; ++i) {
            int cb = i * 256 + wid * 64;          // wave-uniform chunk base
            int c  = cb + lane;
            int r = c >> 3, col = (c & 7) * 8;
            gload16(Ap + (size_t)(m0 + r) * ldA + k0l + col, &As[buf][cb * 8]);
            gload16(Bt + (size_t)(n0 + r) * K   + k0  + col, &Bs[buf][cb * 8]);
        }
    };

    stage(0, 0);
    asm volatile("s_waitcnt vmcnt(0)" ::: "memory");
    __builtin_amdgcn_s_barrier();
    __builtin_amdgcn_sched_barrier(0);

    int cur = 0;
    for (int t = 0; t < nt; ++t) {
        if (t + 1 < nt) stage(cur ^ 1, (t + 1) * 64);   // prefetch next tile
#pragma unroll
        for (int kk = 0; kk < 64; kk += 32) {
            bf16x8 af[4], bfr[4];
#pragma unroll
            for (int mi = 0; mi < 4; ++mi)
                af[mi] = *(const bf16x8*)&As[cur][(wr*64 + mi*16 + fr)*64 + kk + fq*8];
#pragma unroll
            for (int ni = 0; ni < 4; ++ni)
                bfr[ni] = *(const bf16x8*)&Bs[cur][(wc*64 + ni*16 + fr)*64 + kk + fq*8];
#pragma unroll
            for (int mi = 0; mi < 4; ++mi)
#pragma unroll
                for (int ni = 0; ni < 4; ++ni)
                    acc[mi][ni] = __builtin_amdgcn_mfma_f32_16x16x32_bf16(
                        af[mi], bfr[ni], acc[mi][ni], 0, 0, 0);
        }
        asm volatile("s_waitcnt vmcnt(0)" ::: "memory");
        __builtin_amdgcn_s_barrier();
        __builtin_amdgcn_sched_barrier(0);
        cur ^= 1;
    }
    // epilogue: C row = fq*4+v, col = fr
#pragma unroll
    for (int mi = 0; mi < 4; ++mi)
#pragma unroll
        for (int ni = 0; ni < 4; ++ni)
#pragma unroll
            for (int v = 0; v < 4; ++v) {
                int m = m0 + wr*64 + mi*16 + fq*4 + v;
                int n = n0 + wc*64 + ni*16 + fr;
                float val = acc[mi][ni][v];
                if (MODE == 1) {
                    float z = 1.f / (1.f + expf(-(val + bias[n])));
                    size_t idx = (size_t)m * 768 + n;
                    outb[idx] = f2b((1.f - z) * h0[idx] + z * htl[idx]);
                } else {
                    outf[(size_t)m * ldo + n] = val + bias[n];
                }
            }
}

// ---------------------------------------------------------------------------
// Prep kernels
// ---------------------------------------------------------------------------
__global__ __launch_bounds__(256) void cvt_bf16(const float* __restrict__ in,
                                                unsigned short* __restrict__ out, int n4)
{
    int i = blockIdx.x * 256 + threadIdx.x;
    if (i < n4) {
        float4 v = *(const float4*)&in[i * 4];
        out[i*4+0] = f2b(v.x); out[i*4+1] = f2b(v.y);
        out[i*4+2] = f2b(v.z); out[i*4+3] = f2b(v.w);
    }
}

__global__ __launch_bounds__(256) void transpose_w(const float* __restrict__ w,
                                                   unsigned short* __restrict__ wt,
                                                   int K, int N)
{
    __shared__ float tile[32][33];
    int kb = blockIdx.x * 32, nb = blockIdx.y * 32;
    int tx = threadIdx.x & 31, ty = threadIdx.x >> 5;
#pragma unroll
    for (int s = 0; s < 32; s += 8)
        tile[ty + s][tx] = w[(size_t)(kb + ty + s) * N + nb + tx];
    __syncthreads();
#pragma unroll
    for (int s = 0; s < 32; s += 8)
        wt[(size_t)(nb + ty + s) * K + kb + tx] = f2b(tile[tx][ty + s]);
}

__global__ void concat_bias(const float* __restrict__ bq, const float* __restrict__ bk,
                            const float* __restrict__ bv, float* __restrict__ o)
{
    int n = blockIdx.x * 256 + threadIdx.x;
    if (n < 2304) o[n] = (n < 768) ? bq[n] : (n < 1536) ? bk[n - 768] : bv[n - 1536];
}

__global__ __launch_bounds__(256) void build_gru_inputs(
    const float* __restrict__ h0, const float* __restrict__ hn,
    unsigned short* __restrict__ h0b, unsigned short* __restrict__ htlb,
    unsigned short* __restrict__ prodb, int n4)
{
    int i = blockIdx.x * 256 + threadIdx.x;
    if (i < n4) {
        float4 a = *(const float4*)&h0[i * 4];
        float4 b = *(const float4*)&hn[i * 4];
        h0b[i*4+0] = f2b(a.x); h0b[i*4+1] = f2b(a.y); h0b[i*4+2] = f2b(a.z); h0b[i*4+3] = f2b(a.w);
        htlb[i*4+0] = f2b(b.x); htlb[i*4+1] = f2b(b.y); htlb[i*4+2] = f2b(b.z); htlb[i*4+3] = f2b(b.w);
        prodb[i*4+0] = f2b(a.x*b.x); prodb[i*4+1] = f2b(a.y*b.y);
        prodb[i*4+2] = f2b(a.z*b.z); prodb[i*4+3] = f2b(a.w*b.w);
    }
}

// ---------------------------------------------------------------------------
// Low-rank projections -> bf16 Qr (scaled), bf16 Kr, fp32 Vr, bf16 exp(Vr)^T
// grid (T/8, 3), block 256 = 8 t x 32 r
// ---------------------------------------------------------------------------
__global__ __launch_bounds__(256) void lowrank_proj(
    const float* __restrict__ qkv,
    const float* __restrict__ pq, const float* __restrict__ pk, const float* __restrict__ pv,
    unsigned short* __restrict__ qrb, unsigned short* __restrict__ krb,
    float* __restrict__ vr, unsigned short* __restrict__ evtb)
{
    int tid = threadIdx.x;
    int r = tid & 31, tl = tid >> 5;
    int t = blockIdx.x * 8 + tl;
    int sel = blockIdx.y;
    const float* src = qkv + t*2304 + sel*768;
    const float* P = (sel == 0) ? pq : (sel == 1) ? pk : pv;
    float acc = 0.f;
    for (int k = 0; k < 768; k += 4) {
        float4 s4 = *(const float4*)&src[k];
        acc = fmaf(s4.x, P[(k+0)*32 + r], acc);
        acc = fmaf(s4.y, P[(k+1)*32 + r], acc);
        acc = fmaf(s4.z, P[(k+2)*32 + r], acc);
        acc = fmaf(s4.w, P[(k+3)*32 + r], acc);
    }
    if (sel == 0)      qrb[t*32 + r] = f2b(acc * INV_SQRT_R);
    else if (sel == 1) krb[t*32 + r] = f2b(acc);
    else { vr[t*32 + r] = acc; evtb[r*2048 + t] = f2b(expf(acc)); }
}

// ---------------------------------------------------------------------------
// Inclusive cumulative max over time per feature r. grid R, block 256
// ---------------------------------------------------------------------------
__global__ __launch_bounds__(256) void cummax_vr(const float* __restrict__ vr,
                                                 float* __restrict__ ms)
{
    __shared__ float part[256];
    int r = blockIdx.x, tid = threadIdx.x;
    int t0 = tid * 8;
    float v[8];
    float run = -INFINITY;
#pragma unroll
    for (int e = 0; e < 8; ++e) { run = fmaxf(run, vr[(t0+e)*32 + r]); v[e] = run; }
    part[tid] = run;
    __syncthreads();
    for (int off = 1; off < 256; off <<= 1) {
        float other = (tid >= off) ? part[tid - off] : -INFINITY;
        __syncthreads();
        part[tid] = fmaxf(part[tid], other);
        __syncthreads();
    }
    float excl = (tid > 0) ? part[tid - 1] : -INFINITY;
#pragma unroll
    for (int e = 0; e < 8; ++e) ms[(t0+e)*32 + r] = fmaxf(v[e], excl);
}

// ---------------------------------------------------------------------------
// Seed attention, MFMA flash-style. grid (16 i-tiles, 16 j-chunks), jc<=it.
// partial[it][jc][128][32] += sigmoid-weighted PV (fp32)
// ---------------------------------------------------------------------------
__global__ __launch_bounds__(256) void seed_mfma(
    const unsigned short* __restrict__ qrb, const unsigned short* __restrict__ krb,
    const unsigned short* __restrict__ evtb, float* __restrict__ partial)
{
    int it = blockIdx.x, jc = blockIdx.y;
    if (jc > it) return;
    const int i0 = it * 128, j0 = jc * 128;
    __shared__ unsigned short Qs[128*32];
    __shared__ unsigned short Ks[128*32];
    __shared__ unsigned short Es[32*128];    // swizzled
    __shared__ unsigned short Ps[128*128];   // swizzled
    const int tid = threadIdx.x, lane = tid & 63, wid = tid >> 6;
    const int fr = lane & 15, fq = lane >> 4;

    // stage Qr/Kr tiles (linear, global_load_lds)
#pragma unroll
    for (int s = 0; s < 2; ++s) {
        int cb = s * 256 + wid * 64;
        int c = cb + lane;
        int r = c >> 2, col = (c & 3) * 8;
        gload16(qrb + (size_t)(i0 + r) * 32 + col, &Qs[cb * 8]);
        gload16(krb + (size_t)(j0 + r) * 32 + col, &Ks[cb * 8]);
    }
    // stage evr^T tile (32 x 128), XOR-swizzled
#pragma unroll
    for (int s = 0; s < 2; ++s) {
        int c = s * 256 + tid;
        int rr = c >> 4, cc = c & 15;
        bf16x8 v = *(const bf16x8*)&evtb[(size_t)rr * 2048 + j0 + cc * 8];
        int byte = (rr * 256 + cc * 16) ^ ((rr & 7) << 4);
        *(bf16x8*)((char*)Es + byte) = v;
    }
    __syncthreads();

    // S = Qr Kr^T (K=32, one MFMA per 16x16 frag); wave (wr,wc) owns 64x64
    const int wr = wid >> 1, wc = wid & 1;
    bf16x8 af[4], bk[4];
#pragma unroll
    for (int mi = 0; mi < 4; ++mi)
        af[mi] = *(const bf16x8*)&Qs[(wr*64 + mi*16 + fr)*32 + fq*8];
#pragma unroll
    for (int ni = 0; ni < 4; ++ni)
        bk[ni] = *(const bf16x8*)&Ks[(wc*64 + ni*16 + fr)*32 + fq*8];
#pragma unroll
    for (int mi = 0; mi < 4; ++mi)
#pragma unroll
        for (int ni = 0; ni < 4; ++ni) {
            f32x4 s4 = __builtin_amdgcn_mfma_f32_16x16x32_bf16(
                af[mi], bk[ni], (f32x4){0.f,0.f,0.f,0.f}, 0, 0, 0);
#pragma unroll
            for (int v = 0; v < 4; ++v) {
                int row = wr*64 + mi*16 + fq*4 + v;   // local i
                int col = wc*64 + ni*16 + fr;         // local j
                float a = 0.f;
                if (j0 + col <= i0 + row) {
                    float s = s4[v];
                    a = 1.f / (1.f + expf(-(s*s + B_SCALAR)));
                }
                int byte = (row * 256 + col * 2) ^ ((row & 7) << 4);
                *(unsigned short*)((char*)Ps + byte) = f2b(a);
            }
        }
    __syncthreads();

    // Y = P @ evr : C[128][32]; wave owns rows [wid*32, wid*32+32)
    f32x4 yacc[2][2];
#pragma unroll
    for (int mi = 0; mi < 2; ++mi)
#pragma unroll
        for (int nf = 0; nf < 2; ++nf) yacc[mi][nf] = (f32x4){0.f,0.f,0.f,0.f};
#pragma unroll
    for (int ks = 0; ks < 4; ++ks) {
        bf16x8 pa[2], eb[2];
#pragma unroll
        for (int mi = 0; mi < 2; ++mi) {
            int row = wid*32 + mi*16 + fr;
            int byte = (row * 256 + ks * 64 + fq * 16) ^ ((row & 7) << 4);
            pa[mi] = *(const bf16x8*)((const char*)Ps + byte);
        }
#pragma unroll
        for (int nf = 0; nf < 2; ++nf) {
            int rrow = nf*16 + fr;
            int byte = (rrow * 256 + ks * 64 + fq * 16) ^ ((rrow & 7) << 4);
            eb[nf] = *(const bf16x8*)((const char*)Es + byte);
        }
#pragma unroll
        for (int mi = 0; mi < 2; ++mi)
#pragma unroll
            for (int nf = 0; nf < 2; ++nf)
                yacc[mi][nf] = __builtin_amdgcn_mfma_f32_16x16x32_bf16(
                    pa[mi], eb[nf], yacc[mi][nf], 0, 0, 0);
    }
    float* pout = partial + ((size_t)(it*16 + jc) * 128) * 32;
#pragma unroll
    for (int mi = 0; mi < 2; ++mi)
#pragma unroll
        for (int nf = 0; nf < 2; ++nf)
#pragma unroll
            for (int v = 0; v < 4; ++v) {
                int row = wid*32 + mi*16 + fq*4 + v;
                int col = nf*16 + fr;
                pout[row*32 + col] = yacc[mi][nf][v];
            }
}

// ---------------------------------------------------------------------------
// Reduce partials over j-chunks + LASER log epilogue -> lr[2048][32]
// ---------------------------------------------------------------------------
__global__ __launch_bounds__(256) void seed_finish(const float* __restrict__ partial,
                                                   const float* __restrict__ ms,
                                                   float* __restrict__ lr)
{
    int idx = blockIdx.x * 256 + threadIdx.x;     // 65536
    int i = idx >> 5, r = idx & 31;
    int it = i >> 7, row = i & 127;
    float y = 0.f;
    for (int jjc = 0; jjc <= it; ++jjc)
        y += partial[(((size_t)(it*16 + jjc) * 128) + row) * 32 + r];
    float m = ms[idx];
    lr[idx] = logf(fmaxf(y * expf(-m), 1e-30f)) + m;
}

// ---------------------------------------------------------------------------
// H0 = Lr @ up_w.  grid T, block 256, K=32
// ---------------------------------------------------------------------------
__global__ __launch_bounds__(256) void up_proj(const float* __restrict__ lr,
                                               const float* __restrict__ up,
                                               float* __restrict__ h0)
{
    __shared__ float ls[32];
    int t = blockIdx.x, tid = threadIdx.x;
    if (tid < 32) ls[tid] = lr[t*32 + tid];
    __syncthreads();
    for (int c = tid; c < 768; c += 256) {
        float acc = 0.f;
#pragma unroll
        for (int rr = 0; rr < 32; ++rr) acc = fmaf(ls[rr], up[rr*768 + c], acc);
        h0[t*768 + c] = acc;
    }
}

// ---------------------------------------------------------------------------
// Per-(t,h) inverse L2 norms. grid T, block 768
// ---------------------------------------------------------------------------
__global__ void head_norms(const float* __restrict__ qkv,
                           float* __restrict__ invq, float* __restrict__ invk)
{
    int t = blockIdx.x, tid = threadIdx.x;
    int h = tid >> 6, d = tid & 63;
    float q = qkv[t*2304 + h*64 + d];
    float k = qkv[t*2304 + 768 + h*64 + d];
    float sq = q*q, sk = k*k;
#pragma unroll
    for (int off = 32; off; off >>= 1) { sq += __shfl_xor(sq, off); sk += __shfl_xor(sk, off); }
    if (d == 0) {
        invq[t*12 + h] = 1.f / fmaxf(sqrtf(sq), 1e-12f);
        invk[t*12 + h] = 1.f / fmaxf(sqrtf(sk), 1e-12f);
    }
}

// ---------------------------------------------------------------------------
// Sliding past-window (129) max of V + Vexp = exp(V - m). grid (C/64, T/64)
// ---------------------------------------------------------------------------
__global__ __launch_bounds__(256) void slide_max(const float* __restrict__ qkv,
                                                 float* __restrict__ mnear,
                                                 float* __restrict__ vexp)
{
    __shared__ float vs[192][64];
    int c0 = blockIdx.x * 64, t0 = blockIdx.y * 64;
    int tid = threadIdx.x;
#pragma unroll
    for (int s = 0; s < 12; ++s) {
        int idx = tid + s * 256;
        int rr = idx >> 4, c4 = (idx & 15) * 4;
        int t = t0 - 128 + rr;
        float4 v4;
        if (t < 0) v4 = make_float4(-INFINITY, -INFINITY, -INFINITY, -INFINITY);
        else       v4 = *(const float4*)&qkv[t*2304 + 1536 + c0 + c4];
        *(float4*)&vs[rr][c4] = v4;
    }
    __syncthreads();
    int c = tid & 63, tg = tid >> 6;
    for (int u = 0; u < 16; ++u) {
        int tl = tg * 16 + u;
        float m = -INFINITY;
        for (int s = 0; s < 129; ++s) m = fmaxf(m, vs[tl + s][c]);
        float v = vs[tl + 128][c];
        int t = t0 + tl;
        mnear[t*768 + c0 + c] = m;
        vexp [t*768 + c0 + c] = expf(v - m);
    }
}

// ---------------------------------------------------------------------------
// Banded cos^2 attention weights. grid (H, T/16), block 256
// ---------------------------------------------------------------------------
__global__ __launch_bounds__(256) void near_cos(const float* __restrict__ qkv,
                                                const float* __restrict__ invq,
                                                const float* __restrict__ invk,
                                                float* __restrict__ aband)
{
    __shared__ float Qs[16][65];
    __shared__ float Ks[144][65];
    int hh = blockIdx.x, i0 = blockIdx.y * 16, tid = threadIdx.x;
    {
        int ii = tid >> 4, d4 = (tid & 15) * 4;
        float4 q4 = *(const float4*)&qkv[(i0+ii)*2304 + hh*64 + d4];
        float s = invq[(i0+ii)*12 + hh];
        Qs[ii][d4+0] = q4.x*s; Qs[ii][d4+1] = q4.y*s;
        Qs[ii][d4+2] = q4.z*s; Qs[ii][d4+3] = q4.w*s;
    }
#pragma unroll
    for (int v = 0; v < 9; ++v) {
        int idx = tid + v * 256;
        int rr = idx >> 4, d4 = (idx & 15) * 4;
        int j = i0 - 128 + rr;
        float4 k4 = make_float4(0.f, 0.f, 0.f, 0.f);
        float s = 0.f;
        if (j >= 0) { k4 = *(const float4*)&qkv[j*2304 + 768 + hh*64 + d4]; s = invk[j*12 + hh]; }
        Ks[rr][d4+0] = k4.x*s; Ks[rr][d4+1] = k4.y*s;
        Ks[rr][d4+2] = k4.z*s; Ks[rr][d4+3] = k4.w*s;
    }
    __syncthreads();
    int ii = tid & 15, jg = tid >> 4;
#pragma unroll
    for (int v = 0; v < 9; ++v) {
        int jj = jg + (v << 4);
        if (jj <= 128) {
            int rr = ii + jj;
            float s = 0.f;
            for (int d = 0; d < 64; ++d) s = fmaf(Qs[ii][d], Ks[rr][d], s);
            int j = i0 + ii - 128 + jj;
            float a = 0.f;
            if (j >= 0) a = 1.f / (1.f + expf(-(s*s*INV_TAU + B_SCALAR)));
            aband[(hh*2048 + i0 + ii)*132 + jj] = a;
        }
    }
}

// ---------------------------------------------------------------------------
// Banded PV + LASER epilogue. grid (H, T/16), block 256
// ---------------------------------------------------------------------------
__global__ __launch_bounds__(256) void near_pv(const float* __restrict__ aband,
                                               const float* __restrict__ vexp,
                                               const float* __restrict__ mnear,
                                               float* __restrict__ hn)
{
    __shared__ float Vs[144][64];
    __shared__ float As[16][132];
    int hh = blockIdx.x, i0 = blockIdx.y * 16, tid = threadIdx.x;
#pragma unroll
    for (int v = 0; v < 9; ++v) {
        int idx = tid + v * 256;
        int rr = idx >> 4, d4 = (idx & 15) * 4;
        int j = i0 - 128 + rr;
        float4 v4 = make_float4(0.f, 0.f, 0.f, 0.f);
        if (j >= 0) v4 = *(const float4*)&vexp[j*768 + hh*64 + d4];
        *(float4*)&Vs[rr][d4] = v4;
    }
    for (int idx = tid; idx < 16*129; idx += 256) {
        int ii = idx / 129, jj = idx - ii*129;
        As[ii][jj] = aband[(hh*2048 + i0 + ii)*132 + jj];
    }
    __syncthreads();
    int d = tid & 63, ig = tid >> 6;
    float acc[4] = {0.f, 0.f, 0.f, 0.f};
    for (int jj = 0; jj <= 128; ++jj) {
#pragma unroll
        for (int q = 0; q < 4; ++q) {
            int ii = ig*4 + q;
            acc[q] = fmaf(As[ii][jj], Vs[ii + jj][d], acc[q]);
        }
    }
#pragma unroll
    for (int q = 0; q < 4; ++q) {
        int ii = ig*4 + q;
        int idx = (i0 + ii)*768 + hh*64 + d;
        hn[idx] = logf(fmaxf(acc[q], 1e-30f)) + mnear[idx];
    }
}

// ---------------------------------------------------------------------------
// Head-wise sigmoid gate, in place. grid T*H/4, block 256
// ---------------------------------------------------------------------------
__global__ __launch_bounds__(256) void gate_kernel(const float* __restrict__ gu,
                                                   const float* __restrict__ gb,
                                                   float* __restrict__ hn)
{
    int w = blockIdx.x * 4 + (threadIdx.x >> 6);
    int lane = threadIdx.x & 63;
    int t = w / 12, h = w - t*12;
    int idx = t*768 + h*64 + lane;
    float v = hn[idx];
    float s = v * gu[h*64 + lane];
#pragma unroll
    for (int off = 32; off; off >>= 1) s += __shfl_xor(s, off);
    float g = 1.f / (1.f + expf(-(s + gb[h])));
    hn[idx] = v * g;
}

// ---------------------------------------------------------------------------
extern "C" void kernel_launch(void* const* d_in, const int* in_sizes, int n_in,
                              void* d_out, int out_size, void* d_ws, size_t ws_size,
                              hipStream_t stream)
{
    const float* x  = (const float*)d_in[0];
    const float* wq = (const float*)d_in[1];  const float* bq = (const float*)d_in[2];
    const float* wk = (const float*)d_in[3];  const float* bk = (const float*)d_in[4];
    const float* wv = (const float*)d_in[5];  const float* bv = (const float*)d_in[6];
    const float* wo = (const float*)d_in[7];  const float* bo = (const float*)d_in[8];
    const float* pq = (const float*)d_in[9];  const float* pk = (const float*)d_in[10];
    const float* pv = (const float*)d_in[11];
    const float* up = (const float*)d_in[12];
    const float* gu = (const float*)d_in[13]; const float* gb = (const float*)d_in[14];
    const float* wz = (const float*)d_in[15]; const float* bz = (const float*)d_in[16];
    float* out = (float*)d_out;

    float* w = (float*)d_ws;
    float* qkv  = w; w += 2048*2304;
    float* vr   = w; w += 2048*32;
    float* ms   = w; w += 2048*32;
    float* lr   = w; w += 2048*32;
    float* h0   = w; w += 2048*768;
    float* invq = w; w += 2048*12;
    float* invk = w; w += 2048*12;
    float* mnear= w; w += 2048*768;
    float* vexp = w; w += 2048*768;
    float* aband= w; w += 12*2048*132;
    float* hn   = w; w += 2048*768;      // becomes Htilde after gate
    float* partial = w; w += 16*16*128*32;
    float* bqkv = w; w += 2304;
    unsigned short* xb     = (unsigned short*)w; w += 2048*768/2;
    unsigned short* wqkvT  = (unsigned short*)w; w += 2304*768/2;
    unsigned short* wzT    = (unsigned short*)w; w += 768*3072/2;
    unsigned short* woT    = (unsigned short*)w; w += 768*768/2;
    unsigned short* h0b    = (unsigned short*)w; w += 2048*768/2;
    unsigned short* htlb   = (unsigned short*)w; w += 2048*768/2;
    unsigned short* prodb  = (unsigned short*)w; w += 2048*768/2;
    unsigned short* houtb  = (unsigned short*)w; w += 2048*768/2;
    unsigned short* qrb    = (unsigned short*)w; w += 2048*32/2;
    unsigned short* krb    = (unsigned short*)w; w += 2048*32/2;
    unsigned short* evtb   = (unsigned short*)w; w += 32*2048/2;

    // ---- prep
    cvt_bf16<<<1536, 256, 0, stream>>>(x, xb, 2048*768/4);
    transpose_w<<<dim3(24,24), 256, 0, stream>>>(wq, wqkvT,            768, 768);
    transpose_w<<<dim3(24,24), 256, 0, stream>>>(wk, wqkvT + 768*768,  768, 768);
    transpose_w<<<dim3(24,24), 256, 0, stream>>>(wv, wqkvT + 1536*768, 768, 768);
    transpose_w<<<dim3(96,24), 256, 0, stream>>>(wz, wzT, 3072, 768);
    transpose_w<<<dim3(24,24), 256, 0, stream>>>(wo, woT, 768, 768);
    concat_bias<<<9, 256, 0, stream>>>(bq, bk, bv, bqkv);

    // 0) QKV projections
    gemm_mfma<0><<<dim3(18,16), 256, 0, stream>>>(xb, nullptr, nullptr, nullptr,
        wqkvT, bqkv, nullptr, nullptr, qkv, nullptr, 768, 2304);

    // 1) low-rank path (MFMA seed attention)
    lowrank_proj<<<dim3(256,3), 256, 0, stream>>>(qkv, pq, pk, pv, qrb, krb, vr, evtb);
    cummax_vr<<<32, 256, 0, stream>>>(vr, ms);
    seed_mfma<<<dim3(16,16), 256, 0, stream>>>(qrb, krb, evtb, partial);
    seed_finish<<<256, 256, 0, stream>>>(partial, ms, lr);
    up_proj<<<2048, 256, 0, stream>>>(lr, up, h0);

    // 2) near-field path
    head_norms<<<2048, 768, 0, stream>>>(qkv, invq, invk);
    slide_max<<<dim3(12,32), 256, 0, stream>>>(qkv, mnear, vexp);
    near_cos<<<dim3(12,128), 256, 0, stream>>>(qkv, invq, invk, aband);
    near_pv<<<dim3(12,128), 256, 0, stream>>>(aband, vexp, mnear, hn);

    // 3) gate
    gate_kernel<<<2048*12/4, 256, 0, stream>>>(gu, gb, hn);

    // 4) GRU blend + output projection
    build_gru_inputs<<<1536, 256, 0, stream>>>(h0, hn, h0b, htlb, prodb, 2048*768/4);
    gemm_mfma<1><<<dim3(6,16), 256, 0, stream>>>(xb, h0b, htlb, prodb,
        wzT, bz, h0, hn, nullptr, houtb, 3072, 768);
    gemm_mfma<2><<<dim3(6,16), 256, 0, stream>>>(houtb, nullptr, nullptr, nullptr,
        woT, bo, nullptr, nullptr, out, nullptr, 768, 768);
}

// Round 4
// 256.775 us; speedup vs baseline: 3.8559x; 1.1805x over previous
//
#include <hip/hip_runtime.h>
#include <math.h>

// Problem constants (fixed: B=1, T=2048, C=768, H=12, D=64, R=32, K0=128)
static constexpr float B_SCALAR    = -7.6246189861593985f;   // -log(2048)
static constexpr float INV_TAU     = 2.8571428571428571f;    // 1/0.35
static constexpr float INV_SQRT_R  = 0.17677669529663687f;   // 1/sqrt(32)

typedef __attribute__((ext_vector_type(8))) short bf16x8;
typedef __attribute__((ext_vector_type(4))) float f32x4;

__device__ __forceinline__ unsigned short f2b(float f) {
    union { float f; unsigned int u; } v; v.f = f;
    unsigned int r = v.u + 0x7fffu + ((v.u >> 16) & 1u);
    return (unsigned short)(r >> 16);
}

typedef const __attribute__((address_space(1))) unsigned int* gp1_t;
typedef __attribute__((address_space(3))) unsigned int* lp3_t;
__device__ __forceinline__ void gload16(const unsigned short* g, unsigned short* l) {
    __builtin_amdgcn_global_load_lds((gp1_t)g, (lp3_t)l, 16, 0, 0);
}

// ---------------------------------------------------------------------------
// bf16 MFMA GEMM, 128x128 tile, BK=64, double-buffered LDS + 2-phase prefetch,
// LDS XOR-swizzle (source-permuted for global_load_lds, same involution on read).
// KZ>1: split-K, writes fp32 partial pbuf[kz][2048][768] (no bias/epilogue).
// MODE 0: QKV (KZ=1)   MODE 1: Wz piecewise A (KZ=4)   MODE 2: Wo (KZ=2)
// ---------------------------------------------------------------------------
template<int MODE, int KZ>
__global__ __launch_bounds__(256) void gemm_mfma(
    const unsigned short* __restrict__ A0, const unsigned short* __restrict__ A1,
    const unsigned short* __restrict__ A2, const unsigned short* __restrict__ A3,
    const unsigned short* __restrict__ Bt, const float* __restrict__ bias,
    float* __restrict__ outf, float* __restrict__ pbuf,
    int K, int ldo)
{
    __shared__ unsigned short As[2][128*64];
    __shared__ unsigned short Bs[2][128*64];
    const int tid = threadIdx.x;
    const int lane = tid & 63, wid = tid >> 6;
    const int wr = wid >> 1, wc = wid & 1;
    const int fr = lane & 15, fq = lane >> 4;
    const int n0 = blockIdx.x * 128, m0 = blockIdx.y * 128;
    const int kz = blockIdx.z;
    const int kslice = K / KZ;
    const int kbase = kz * kslice;
    const int nt = kslice / 64;

    f32x4 acc[4][4];
#pragma unroll
    for (int mi = 0; mi < 4; ++mi)
#pragma unroll
        for (int ni = 0; ni < 4; ++ni) acc[mi][ni] = (f32x4){0.f, 0.f, 0.f, 0.f};

    auto stage = [&](int buf, int k0) {
        const unsigned short* Ap;
        int k0l, ldA;
        if (MODE == 1) {
            int p = k0 / 768;
            Ap = (p == 0) ? A0 : (p == 1) ? A1 : (p == 2) ? A2 : A3;
            k0l = k0 - p * 768; ldA = 768;
        } else { Ap = A0; k0l = k0; ldA = K; }
#pragma unroll
        for (int i = 0; i < 4; ++i) {
            int cb = i * 256 + wid * 64;          // wave-uniform chunk base
            int c  = cb + lane;
            int r = c >> 3;
            int col = ((c & 7) ^ (r & 7)) * 8;    // source-permuted for XOR swizzle
            gload16(Ap + (size_t)(m0 + r) * ldA + k0l + col, &As[buf][cb * 8]);
            gload16(Bt + (size_t)(n0 + r) * K   + k0  + col, &Bs[buf][cb * 8]);
        }
    };
    auto frag = [&](const unsigned short* base, int row, int elem) -> bf16x8 {
        int byte = (row * 128 + elem * 2) ^ ((row & 7) << 4);
        return *(const bf16x8*)((const char*)base + byte);
    };

    stage(0, kbase);
    asm volatile("s_waitcnt vmcnt(0)" ::: "memory");
    __builtin_amdgcn_s_barrier();
    __builtin_amdgcn_sched_barrier(0);

    int cur = 0;
    for (int t = 0; t < nt; ++t) {
        if (t + 1 < nt) stage(cur ^ 1, kbase + (t + 1) * 64);
#pragma unroll
        for (int kk = 0; kk < 64; kk += 32) {
            bf16x8 af[4], bfr[4];
#pragma unroll
            for (int mi = 0; mi < 4; ++mi)
                af[mi] = frag(As[cur], wr*64 + mi*16 + fr, kk + fq*8);
#pragma unroll
            for (int ni = 0; ni < 4; ++ni)
                bfr[ni] = frag(Bs[cur], wc*64 + ni*16 + fr, kk + fq*8);
#pragma unroll
            for (int mi = 0; mi < 4; ++mi)
#pragma unroll
                for (int ni = 0; ni < 4; ++ni)
                    acc[mi][ni] = __builtin_amdgcn_mfma_f32_16x16x32_bf16(
                        af[mi], bfr[ni], acc[mi][ni], 0, 0, 0);
        }
        asm volatile("s_waitcnt vmcnt(0)" ::: "memory");
        __builtin_amdgcn_s_barrier();
        __builtin_amdgcn_sched_barrier(0);
        cur ^= 1;
    }
    // epilogue: C row = fq*4+v, col = fr
#pragma unroll
    for (int mi = 0; mi < 4; ++mi)
#pragma unroll
        for (int ni = 0; ni < 4; ++ni)
#pragma unroll
            for (int v = 0; v < 4; ++v) {
                int m = m0 + wr*64 + mi*16 + fq*4 + v;
                int n = n0 + wc*64 + ni*16 + fr;
                float val = acc[mi][ni][v];
                if (KZ > 1) {
                    pbuf[((size_t)kz * 2048 + m) * 768 + n] = val;
                } else {
                    outf[(size_t)m * ldo + n] = val + bias[n];
                }
            }
}

// ---------------------------------------------------------------------------
// Split-K combine kernels (BW-bound, float4)
// ---------------------------------------------------------------------------
__global__ __launch_bounds__(256) void wz_combine(
    const float* __restrict__ pbuf, const float* __restrict__ bz,
    const float* __restrict__ h0, const float* __restrict__ htl,
    unsigned short* __restrict__ outb)
{
    int i = blockIdx.x * 256 + threadIdx.x;          // n4 = 2048*768/4
    if (i >= 2048*768/4) return;
    float4 s = *(const float4*)&pbuf[i*4];
    float4 p1 = *(const float4*)&pbuf[1536*1024 + i*4];
    float4 p2 = *(const float4*)&pbuf[2*1536*1024 + i*4];
    float4 p3 = *(const float4*)&pbuf[3*1536*1024 + i*4];
    s.x += p1.x + p2.x + p3.x; s.y += p1.y + p2.y + p3.y;
    s.z += p1.z + p2.z + p3.z; s.w += p1.w + p2.w + p3.w;
    float4 b = *(const float4*)&bz[(i % 192) * 4];
    float4 a = *(const float4*)&h0[i*4];
    float4 t = *(const float4*)&htl[i*4];
    float z0 = 1.f/(1.f+expf(-(s.x+b.x))), z1 = 1.f/(1.f+expf(-(s.y+b.y)));
    float z2 = 1.f/(1.f+expf(-(s.z+b.z))), z3 = 1.f/(1.f+expf(-(s.w+b.w)));
    outb[i*4+0] = f2b((1.f-z0)*a.x + z0*t.x);
    outb[i*4+1] = f2b((1.f-z1)*a.y + z1*t.y);
    outb[i*4+2] = f2b((1.f-z2)*a.z + z2*t.z);
    outb[i*4+3] = f2b((1.f-z3)*a.w + z3*t.w);
}

__global__ __launch_bounds__(256) void wo_combine(
    const float* __restrict__ pbuf, const float* __restrict__ bo,
    float* __restrict__ out)
{
    int i = blockIdx.x * 256 + threadIdx.x;
    if (i >= 2048*768/4) return;
    float4 s = *(const float4*)&pbuf[i*4];
    float4 p1 = *(const float4*)&pbuf[1536*1024 + i*4];
    float4 b = *(const float4*)&bo[(i % 192) * 4];
    float4 o;
    o.x = s.x + p1.x + b.x; o.y = s.y + p1.y + b.y;
    o.z = s.z + p1.z + b.z; o.w = s.w + p1.w + b.w;
    *(float4*)&out[i*4] = o;
}

// ---------------------------------------------------------------------------
// Prep kernels
// ---------------------------------------------------------------------------
__global__ __launch_bounds__(256) void cvt_bf16(const float* __restrict__ in,
                                                unsigned short* __restrict__ out, int n4)
{
    int i = blockIdx.x * 256 + threadIdx.x;
    if (i < n4) {
        float4 v = *(const float4*)&in[i * 4];
        out[i*4+0] = f2b(v.x); out[i*4+1] = f2b(v.y);
        out[i*4+2] = f2b(v.z); out[i*4+3] = f2b(v.w);
    }
}

__global__ __launch_bounds__(256) void transpose_w(const float* __restrict__ w,
                                                   unsigned short* __restrict__ wt,
                                                   int K, int N)
{
    __shared__ float tile[32][33];
    int kb = blockIdx.x * 32, nb = blockIdx.y * 32;
    int tx = threadIdx.x & 31, ty = threadIdx.x >> 5;
#pragma unroll
    for (int s = 0; s < 32; s += 8)
        tile[ty + s][tx] = w[(size_t)(kb + ty + s) * N + nb + tx];
    __syncthreads();
#pragma unroll
    for (int s = 0; s < 32; s += 8)
        wt[(size_t)(nb + ty + s) * K + kb + tx] = f2b(tile[tx][ty + s]);
}

__global__ void concat_bias(const float* __restrict__ bq, const float* __restrict__ bk,
                            const float* __restrict__ bv, float* __restrict__ o)
{
    int n = blockIdx.x * 256 + threadIdx.x;
    if (n < 2304) o[n] = (n < 768) ? bq[n] : (n < 1536) ? bk[n - 768] : bv[n - 1536];
}

__global__ __launch_bounds__(256) void build_gru_inputs(
    const float* __restrict__ h0, const float* __restrict__ hn,
    unsigned short* __restrict__ h0b, unsigned short* __restrict__ htlb,
    unsigned short* __restrict__ prodb, int n4)
{
    int i = blockIdx.x * 256 + threadIdx.x;
    if (i < n4) {
        float4 a = *(const float4*)&h0[i * 4];
        float4 b = *(const float4*)&hn[i * 4];
        h0b[i*4+0] = f2b(a.x); h0b[i*4+1] = f2b(a.y); h0b[i*4+2] = f2b(a.z); h0b[i*4+3] = f2b(a.w);
        htlb[i*4+0] = f2b(b.x); htlb[i*4+1] = f2b(b.y); htlb[i*4+2] = f2b(b.z); htlb[i*4+3] = f2b(b.w);
        prodb[i*4+0] = f2b(a.x*b.x); prodb[i*4+1] = f2b(a.y*b.y);
        prodb[i*4+2] = f2b(a.z*b.z); prodb[i*4+3] = f2b(a.w*b.w);
    }
}

// ---------------------------------------------------------------------------
// Low-rank projections -> bf16 Qr (scaled), bf16 Kr, fp32 Vr, bf16 exp(Vr)^T
// ---------------------------------------------------------------------------
__global__ __launch_bounds__(256) void lowrank_proj(
    const float* __restrict__ qkv,
    const float* __restrict__ pq, const float* __restrict__ pk, const float* __restrict__ pv,
    unsigned short* __restrict__ qrb, unsigned short* __restrict__ krb,
    float* __restrict__ vr, unsigned short* __restrict__ evtb)
{
    int tid = threadIdx.x;
    int r = tid & 31, tl = tid >> 5;
    int t = blockIdx.x * 8 + tl;
    int sel = blockIdx.y;
    const float* src = qkv + t*2304 + sel*768;
    const float* P = (sel == 0) ? pq : (sel == 1) ? pk : pv;
    float acc = 0.f;
    for (int k = 0; k < 768; k += 4) {
        float4 s4 = *(const float4*)&src[k];
        acc = fmaf(s4.x, P[(k+0)*32 + r], acc);
        acc = fmaf(s4.y, P[(k+1)*32 + r], acc);
        acc = fmaf(s4.z, P[(k+2)*32 + r], acc);
        acc = fmaf(s4.w, P[(k+3)*32 + r], acc);
    }
    if (sel == 0)      qrb[t*32 + r] = f2b(acc * INV_SQRT_R);
    else if (sel == 1) krb[t*32 + r] = f2b(acc);
    else { vr[t*32 + r] = acc; evtb[r*2048 + t] = f2b(expf(acc)); }
}

// ---------------------------------------------------------------------------
// Inclusive cumulative max over time per feature r. grid R, block 256
// ---------------------------------------------------------------------------
__global__ __launch_bounds__(256) void cummax_vr(const float* __restrict__ vr,
                                                 float* __restrict__ ms)
{
    __shared__ float part[256];
    int r = blockIdx.x, tid = threadIdx.x;
    int t0 = tid * 8;
    float v[8];
    float run = -INFINITY;
#pragma unroll
    for (int e = 0; e < 8; ++e) { run = fmaxf(run, vr[(t0+e)*32 + r]); v[e] = run; }
    part[tid] = run;
    __syncthreads();
    for (int off = 1; off < 256; off <<= 1) {
        float other = (tid >= off) ? part[tid - off] : -INFINITY;
        __syncthreads();
        part[tid] = fmaxf(part[tid], other);
        __syncthreads();
    }
    float excl = (tid > 0) ? part[tid - 1] : -INFINITY;
#pragma unroll
    for (int e = 0; e < 8; ++e) ms[(t0+e)*32 + r] = fmaxf(v[e], excl);
}

// ---------------------------------------------------------------------------
// Seed attention, MFMA flash-style. grid (16 i-tiles, 16 j-chunks), jc<=it.
// ---------------------------------------------------------------------------
__global__ __launch_bounds__(256) void seed_mfma(
    const unsigned short* __restrict__ qrb, const unsigned short* __restrict__ krb,
    const unsigned short* __restrict__ evtb, float* __restrict__ partial)
{
    int it = blockIdx.x, jc = blockIdx.y;
    if (jc > it) return;
    const int i0 = it * 128, j0 = jc * 128;
    __shared__ unsigned short Qs[128*32];
    __shared__ unsigned short Ks[128*32];
    __shared__ unsigned short Es[32*128];    // swizzled
    __shared__ unsigned short Ps[128*128];   // swizzled
    const int tid = threadIdx.x, lane = tid & 63, wid = tid >> 6;
    const int fr = lane & 15, fq = lane >> 4;

#pragma unroll
    for (int s = 0; s < 2; ++s) {
        int cb = s * 256 + wid * 64;
        int c = cb + lane;
        int r = c >> 2, col = (c & 3) * 8;
        gload16(qrb + (size_t)(i0 + r) * 32 + col, &Qs[cb * 8]);
        gload16(krb + (size_t)(j0 + r) * 32 + col, &Ks[cb * 8]);
    }
#pragma unroll
    for (int s = 0; s < 2; ++s) {
        int c = s * 256 + tid;
        int rr = c >> 4, cc = c & 15;
        bf16x8 v = *(const bf16x8*)&evtb[(size_t)rr * 2048 + j0 + cc * 8];
        int byte = (rr * 256 + cc * 16) ^ ((rr & 7) << 4);
        *(bf16x8*)((char*)Es + byte) = v;
    }
    __syncthreads();

    const int wr = wid >> 1, wc = wid & 1;
    bf16x8 af[4], bk[4];
#pragma unroll
    for (int mi = 0; mi < 4; ++mi)
        af[mi] = *(const bf16x8*)&Qs[(wr*64 + mi*16 + fr)*32 + fq*8];
#pragma unroll
    for (int ni = 0; ni < 4; ++ni)
        bk[ni] = *(const bf16x8*)&Ks[(wc*64 + ni*16 + fr)*32 + fq*8];
#pragma unroll
    for (int mi = 0; mi < 4; ++mi)
#pragma unroll
        for (int ni = 0; ni < 4; ++ni) {
            f32x4 s4 = __builtin_amdgcn_mfma_f32_16x16x32_bf16(
                af[mi], bk[ni], (f32x4){0.f,0.f,0.f,0.f}, 0, 0, 0);
#pragma unroll
            for (int v = 0; v < 4; ++v) {
                int row = wr*64 + mi*16 + fq*4 + v;
                int col = wc*64 + ni*16 + fr;
                float a = 0.f;
                if (j0 + col <= i0 + row) {
                    float s = s4[v];
                    a = 1.f / (1.f + expf(-(s*s + B_SCALAR)));
                }
                int byte = (row * 256 + col * 2) ^ ((row & 7) << 4);
                *(unsigned short*)((char*)Ps + byte) = f2b(a);
            }
        }
    __syncthreads();

    f32x4 yacc[2][2];
#pragma unroll
    for (int mi = 0; mi < 2; ++mi)
#pragma unroll
        for (int nf = 0; nf < 2; ++nf) yacc[mi][nf] = (f32x4){0.f,0.f,0.f,0.f};
#pragma unroll
    for (int ks = 0; ks < 4; ++ks) {
        bf16x8 pa[2], eb[2];
#pragma unroll
        for (int mi = 0; mi < 2; ++mi) {
            int row = wid*32 + mi*16 + fr;
            int byte = (row * 256 + ks * 64 + fq * 16) ^ ((row & 7) << 4);
            pa[mi] = *(const bf16x8*)((const char*)Ps + byte);
        }
#pragma unroll
        for (int nf = 0; nf < 2; ++nf) {
            int rrow = nf*16 + fr;
            int byte = (rrow * 256 + ks * 64 + fq * 16) ^ ((rrow & 7) << 4);
            eb[nf] = *(const bf16x8*)((const char*)Es + byte);
        }
#pragma unroll
        for (int mi = 0; mi < 2; ++mi)
#pragma unroll
            for (int nf = 0; nf < 2; ++nf)
                yacc[mi][nf] = __builtin_amdgcn_mfma_f32_16x16x32_bf16(
                    pa[mi], eb[nf], yacc[mi][nf], 0, 0, 0);
    }
    float* pout = partial + ((size_t)(it*16 + jc) * 128) * 32;
#pragma unroll
    for (int mi = 0; mi < 2; ++mi)
#pragma unroll
        for (int nf = 0; nf < 2; ++nf)
#pragma unroll
            for (int v = 0; v < 4; ++v) {
                int row = wid*32 + mi*16 + fq*4 + v;
                int col = nf*16 + fr;
                pout[row*32 + col] = yacc[mi][nf][v];
            }
}

// ---------------------------------------------------------------------------
// Reduce partials over j-chunks + LASER log epilogue -> lr[2048][32]
// ---------------------------------------------------------------------------
__global__ __launch_bounds__(256) void seed_finish(const float* __restrict__ partial,
                                                   const float* __restrict__ ms,
                                                   float* __restrict__ lr)
{
    int idx = blockIdx.x * 256 + threadIdx.x;
    int i = idx >> 5, r = idx & 31;
    int it = i >> 7, row = i & 127;
    float y = 0.f;
    for (int jjc = 0; jjc <= it; ++jjc)
        y += partial[(((size_t)(it*16 + jjc) * 128) + row) * 32 + r];
    float m = ms[idx];
    lr[idx] = logf(fmaxf(y * expf(-m), 1e-30f)) + m;
}

// ---------------------------------------------------------------------------
// H0 = Lr @ up_w.  grid T, block 256, K=32
// ---------------------------------------------------------------------------
__global__ __launch_bounds__(256) void up_proj(const float* __restrict__ lr,
                                               const float* __restrict__ up,
                                               float* __restrict__ h0)
{
    __shared__ float ls[32];
    int t = blockIdx.x, tid = threadIdx.x;
    if (tid < 32) ls[tid] = lr[t*32 + tid];
    __syncthreads();
    for (int c = tid; c < 768; c += 256) {
        float acc = 0.f;
#pragma unroll
        for (int rr = 0; rr < 32; ++rr) acc = fmaf(ls[rr], up[rr*768 + c], acc);
        h0[t*768 + c] = acc;
    }
}

// ---------------------------------------------------------------------------
// Per-(t,h) inverse L2 norms. grid T, block 768
// ---------------------------------------------------------------------------
__global__ void head_norms(const float* __restrict__ qkv,
                           float* __restrict__ invq, float* __restrict__ invk)
{
    int t = blockIdx.x, tid = threadIdx.x;
    int h = tid >> 6, d = tid & 63;
    float q = qkv[t*2304 + h*64 + d];
    float k = qkv[t*2304 + 768 + h*64 + d];
    float sq = q*q, sk = k*k;
#pragma unroll
    for (int off = 32; off; off >>= 1) { sq += __shfl_xor(sq, off); sk += __shfl_xor(sk, off); }
    if (d == 0) {
        invq[t*12 + h] = 1.f / fmaxf(sqrtf(sq), 1e-12f);
        invk[t*12 + h] = 1.f / fmaxf(sqrtf(sk), 1e-12f);
    }
}

// ---------------------------------------------------------------------------
// Sliding past-window (129) max of V + Vexp = exp(V - m). grid (C/64, T/64)
// ---------------------------------------------------------------------------
__global__ __launch_bounds__(256) void slide_max(const float* __restrict__ qkv,
                                                 float* __restrict__ mnear,
                                                 float* __restrict__ vexp)
{
    __shared__ float vs[192][64];
    int c0 = blockIdx.x * 64, t0 = blockIdx.y * 64;
    int tid = threadIdx.x;
#pragma unroll
    for (int s = 0; s < 12; ++s) {
        int idx = tid + s * 256;
        int rr = idx >> 4, c4 = (idx & 15) * 4;
        int t = t0 - 128 + rr;
        float4 v4;
        if (t < 0) v4 = make_float4(-INFINITY, -INFINITY, -INFINITY, -INFINITY);
        else       v4 = *(const float4*)&qkv[t*2304 + 1536 + c0 + c4];
        *(float4*)&vs[rr][c4] = v4;
    }
    __syncthreads();
    int c = tid & 63, tg = tid >> 6;
    for (int u = 0; u < 16; ++u) {
        int tl = tg * 16 + u;
        float m = -INFINITY;
        for (int s = 0; s < 129; ++s) m = fmaxf(m, vs[tl + s][c]);
        float v = vs[tl + 128][c];
        int t = t0 + tl;
        mnear[t*768 + c0 + c] = m;
        vexp [t*768 + c0 + c] = expf(v - m);
    }
}

// ---------------------------------------------------------------------------
// Banded cos^2 attention weights. grid (H, T/16), block 256
// ---------------------------------------------------------------------------
__global__ __launch_bounds__(256) void near_cos(const float* __restrict__ qkv,
                                                const float* __restrict__ invq,
                                                const float* __restrict__ invk,
                                                float* __restrict__ aband)
{
    __shared__ float Qs[16][65];
    __shared__ float Ks[144][65];
    int hh = blockIdx.x, i0 = blockIdx.y * 16, tid = threadIdx.x;
    {
        int ii = tid >> 4, d4 = (tid & 15) * 4;
        float4 q4 = *(const float4*)&qkv[(i0+ii)*2304 + hh*64 + d4];
        float s = invq[(i0+ii)*12 + hh];
        Qs[ii][d4+0] = q4.x*s; Qs[ii][d4+1] = q4.y*s;
        Qs[ii][d4+2] = q4.z*s; Qs[ii][d4+3] = q4.w*s;
    }
#pragma unroll
    for (int v = 0; v < 9; ++v) {
        int idx = tid + v * 256;
        int rr = idx >> 4, d4 = (idx & 15) * 4;
        int j = i0 - 128 + rr;
        float4 k4 = make_float4(0.f, 0.f, 0.f, 0.f);
        float s = 0.f;
        if (j >= 0) { k4 = *(const float4*)&qkv[j*2304 + 768 + hh*64 + d4]; s = invk[j*12 + hh]; }
        Ks[rr][d4+0] = k4.x*s; Ks[rr][d4+1] = k4.y*s;
        Ks[rr][d4+2] = k4.z*s; Ks[rr][d4+3] = k4.w*s;
    }
    __syncthreads();
    int ii = tid & 15, jg = tid >> 4;
#pragma unroll
    for (int v = 0; v < 9; ++v) {
        int jj = jg + (v << 4);
        if (jj <= 128) {
            int rr = ii + jj;
            float s = 0.f;
            for (int d = 0; d < 64; ++d) s = fmaf(Qs[ii][d], Ks[rr][d], s);
            int j = i0 + ii - 128 + jj;
            float a = 0.f;
            if (j >= 0) a = 1.f / (1.f + expf(-(s*s*INV_TAU + B_SCALAR)));
            aband[(hh*2048 + i0 + ii)*132 + jj] = a;
        }
    }
}

// ---------------------------------------------------------------------------
// Banded PV + LASER epilogue. grid (H, T/16), block 256
// ---------------------------------------------------------------------------
__global__ __launch_bounds__(256) void near_pv(const float* __restrict__ aband,
                                               const float* __restrict__ vexp,
                                               const float* __restrict__ mnear,
                                               float* __restrict__ hn)
{
    __shared__ float Vs[144][64];
    __shared__ float As[16][132];
    int hh = blockIdx.x, i0 = blockIdx.y * 16, tid = threadIdx.x;
#pragma unroll
    for (int v = 0; v < 9; ++v) {
        int idx = tid + v * 256;
        int rr = idx >> 4, d4 = (idx & 15) * 4;
        int j = i0 - 128 + rr;
        float4 v4 = make_float4(0.f, 0.f, 0.f, 0.f);
        if (j >= 0) v4 = *(const float4*)&vexp[j*768 + hh*64 + d4];
        *(float4*)&Vs[rr][d4] = v4;
    }
    for (int idx = tid; idx < 16*129; idx += 256) {
        int ii = idx / 129, jj = idx - ii*129;
        As[ii][jj] = aband[(hh*2048 + i0 + ii)*132 + jj];
    }
    __syncthreads();
    int d = tid & 63, ig = tid >> 6;
    float acc[4] = {0.f, 0.f, 0.f, 0.f};
    for (int jj = 0; jj <= 128; ++jj) {
#pragma unroll
        for (int q = 0; q < 4; ++q) {
            int ii = ig*4 + q;
            acc[q] = fmaf(As[ii][jj], Vs[ii + jj][d], acc[q]);
        }
    }
#pragma unroll
    for (int q = 0; q < 4; ++q) {
        int ii = ig*4 + q;
        int idx = (i0 + ii)*768 + hh*64 + d;
        hn[idx] = logf(fmaxf(acc[q], 1e-30f)) + mnear[idx];
    }
}

// ---------------------------------------------------------------------------
// Head-wise sigmoid gate, in place. grid T*H/4, block 256
// ---------------------------------------------------------------------------
__global__ __launch_bounds__(256) void gate_kernel(const float* __restrict__ gu,
                                                   const float* __restrict__ gb,
                                                   float* __restrict__ hn)
{
    int w = blockIdx.x * 4 + (threadIdx.x >> 6);
    int lane = threadIdx.x & 63;
    int t = w / 12, h = w - t*12;
    int idx = t*768 + h*64 + lane;
    float v = hn[idx];
    float s = v * gu[h*64 + lane];
#pragma unroll
    for (int off = 32; off; off >>= 1) s += __shfl_xor(s, off);
    float g = 1.f / (1.f + expf(-(s + gb[h])));
    hn[idx] = v * g;
}

// ---------------------------------------------------------------------------
extern "C" void kernel_launch(void* const* d_in, const int* in_sizes, int n_in,
                              void* d_out, int out_size, void* d_ws, size_t ws_size,
                              hipStream_t stream)
{
    const float* x  = (const float*)d_in[0];
    const float* wq = (const float*)d_in[1];  const float* bq = (const float*)d_in[2];
    const float* wk = (const float*)d_in[3];  const float* bk = (const float*)d_in[4];
    const float* wv = (const float*)d_in[5];  const float* bv = (const float*)d_in[6];
    const float* wo = (const float*)d_in[7];  const float* bo = (const float*)d_in[8];
    const float* pq = (const float*)d_in[9];  const float* pk = (const float*)d_in[10];
    const float* pv = (const float*)d_in[11];
    const float* up = (const float*)d_in[12];
    const float* gu = (const float*)d_in[13]; const float* gb = (const float*)d_in[14];
    const float* wz = (const float*)d_in[15]; const float* bz = (const float*)d_in[16];
    float* out = (float*)d_out;

    float* w = (float*)d_ws;
    float* qkv  = w; w += 2048*2304;
    float* vr   = w; w += 2048*32;
    float* ms   = w; w += 2048*32;
    float* lr   = w; w += 2048*32;
    float* h0   = w; w += 2048*768;
    float* invq = w; w += 2048*12;
    float* invk = w; w += 2048*12;
    float* mnear= w; w += 2048*768;
    float* vexp = w; w += 2048*768;
    float* aband= w; w += 12*2048*132;
    float* hn   = w; w += 2048*768;      // becomes Htilde after gate
    float* partial = w; w += 16*16*128*32;
    float* pgemm = w; w += 4*2048*768;   // split-K partials (Wz: 4, Wo: 2)
    float* bqkv = w; w += 2304;
    unsigned short* xb     = (unsigned short*)w; w += 2048*768/2;
    unsigned short* wqkvT  = (unsigned short*)w; w += 2304*768/2;
    unsigned short* wzT    = (unsigned short*)w; w += 768*3072/2;
    unsigned short* woT    = (unsigned short*)w; w += 768*768/2;
    unsigned short* h0b    = (unsigned short*)w; w += 2048*768/2;
    unsigned short* htlb   = (unsigned short*)w; w += 2048*768/2;
    unsigned short* prodb  = (unsigned short*)w; w += 2048*768/2;
    unsigned short* houtb  = (unsigned short*)w; w += 2048*768/2;
    unsigned short* qrb    = (unsigned short*)w; w += 2048*32/2;
    unsigned short* krb    = (unsigned short*)w; w += 2048*32/2;
    unsigned short* evtb   = (unsigned short*)w; w += 32*2048/2;

    // ---- prep
    cvt_bf16<<<1536, 256, 0, stream>>>(x, xb, 2048*768/4);
    transpose_w<<<dim3(24,24), 256, 0, stream>>>(wq, wqkvT,            768, 768);
    transpose_w<<<dim3(24,24), 256, 0, stream>>>(wk, wqkvT + 768*768,  768, 768);
    transpose_w<<<dim3(24,24), 256, 0, stream>>>(wv, wqkvT + 1536*768, 768, 768);
    transpose_w<<<dim3(96,24), 256, 0, stream>>>(wz, wzT, 3072, 768);
    transpose_w<<<dim3(24,24), 256, 0, stream>>>(wo, woT, 768, 768);
    concat_bias<<<9, 256, 0, stream>>>(bq, bk, bv, bqkv);

    // 0) QKV projections (unsplit: 288 blocks)
    gemm_mfma<0,1><<<dim3(18,16,1), 256, 0, stream>>>(xb, nullptr, nullptr, nullptr,
        wqkvT, bqkv, qkv, nullptr, 768, 2304);

    // 1) low-rank path (MFMA seed attention)
    lowrank_proj<<<dim3(256,3), 256, 0, stream>>>(qkv, pq, pk, pv, qrb, krb, vr, evtb);
    cummax_vr<<<32, 256, 0, stream>>>(vr, ms);
    seed_mfma<<<dim3(16,16), 256, 0, stream>>>(qrb, krb, evtb, partial);
    seed_finish<<<256, 256, 0, stream>>>(partial, ms, lr);
    up_proj<<<2048, 256, 0, stream>>>(lr, up, h0);

    // 2) near-field path
    head_norms<<<2048, 768, 0, stream>>>(qkv, invq, invk);
    slide_max<<<dim3(12,32), 256, 0, stream>>>(qkv, mnear, vexp);
    near_cos<<<dim3(12,128), 256, 0, stream>>>(qkv, invq, invk, aband);
    near_pv<<<dim3(12,128), 256, 0, stream>>>(aband, vexp, mnear, hn);

    // 3) gate
    gate_kernel<<<2048*12/4, 256, 0, stream>>>(gu, gb, hn);

    // 4) GRU blend (split-K=4) + combine + output projection (split-K=2) + combine
    build_gru_inputs<<<1536, 256, 0, stream>>>(h0, hn, h0b, htlb, prodb, 2048*768/4);
    gemm_mfma<1,4><<<dim3(6,16,4), 256, 0, stream>>>(xb, h0b, htlb, prodb,
        wzT, nullptr, nullptr, pgemm, 3072, 768);
    wz_combine<<<1536, 256, 0, stream>>>(pgemm, bz, h0, hn, houtb);
    gemm_mfma<2,2><<<dim3(6,16,2), 256, 0, stream>>>(houtb, nullptr, nullptr, nullptr,
        woT, nullptr, nullptr, pgemm, 768, 768);
    wo_combine<<<1536, 256, 0, stream>>>(pgemm, bo, out);
}

// Round 7
// 224.118 us; speedup vs baseline: 4.4178x; 1.1457x over previous
//
#include <hip/hip_runtime.h>
#include <math.h>

// Problem constants (fixed: B=1, T=2048, C=768, H=12, D=64, R=32, K0=128)
static constexpr float B_SCALAR    = -7.6246189861593985f;   // -log(2048)
static constexpr float INV_TAU     = 2.8571428571428571f;    // 1/0.35
static constexpr float INV_SQRT_R  = 0.17677669529663687f;   // 1/sqrt(32)

typedef __attribute__((ext_vector_type(8))) short bf16x8;
typedef __attribute__((ext_vector_type(4))) float f32x4;

__device__ __forceinline__ unsigned short f2b(float f) {
    union { float f; unsigned int u; } v; v.f = f;
    unsigned int r = v.u + 0x7fffu + ((v.u >> 16) & 1u);
    return (unsigned short)(r >> 16);
}

typedef const __attribute__((address_space(1))) unsigned int* gp1_t;
typedef __attribute__((address_space(3))) unsigned int* lp3_t;
__device__ __forceinline__ void gload16(const unsigned short* g, unsigned short* l) {
    __builtin_amdgcn_global_load_lds((gp1_t)g, (lp3_t)l, 16, 0, 0);
}

// XOR-swizzled bf16x8 read from a row-major LDS tile with 128B rows
__device__ __forceinline__ bf16x8 frag128(const unsigned short* base, int row, int elem) {
    int byte = (row * 128 + elem * 2) ^ ((row & 7) << 4);
    return *(const bf16x8*)((const char*)base + byte);
}

// ---------------------------------------------------------------------------
// bf16 MFMA GEMM, 128x128 tile, BK=64, double-buffered 2-phase prefetch,
// XOR-swizzled LDS (source-permuted global_load_lds + same involution on read).
// MODE 0: QKV (KZ=1, fp32 out + bf16 copy)  MODE 1: Wz piecewise A (split-K)
// MODE 2: Wo (split-K)
// ---------------------------------------------------------------------------
template<int MODE, int KZ>
__global__ __launch_bounds__(256) void gemm_mfma(
    const unsigned short* __restrict__ A0, const unsigned short* __restrict__ A1,
    const unsigned short* __restrict__ A2, const unsigned short* __restrict__ A3,
    const unsigned short* __restrict__ Bt, const float* __restrict__ bias,
    float* __restrict__ outf, unsigned short* __restrict__ outb,
    float* __restrict__ pbuf, int K, int ldo)
{
    __shared__ unsigned short As[2][128*64];
    __shared__ unsigned short Bs[2][128*64];
    const int tid = threadIdx.x;
    const int lane = tid & 63, wid = tid >> 6;
    const int wr = wid >> 1, wc = wid & 1;
    const int fr = lane & 15, fq = lane >> 4;
    const int n0 = blockIdx.x * 128, m0 = blockIdx.y * 128;
    const int kz = blockIdx.z;
    const int kslice = K / KZ;
    const int kbase = kz * kslice;
    const int nt = kslice / 64;

    f32x4 acc[4][4];
#pragma unroll
    for (int mi = 0; mi < 4; ++mi)
#pragma unroll
        for (int ni = 0; ni < 4; ++ni) acc[mi][ni] = (f32x4){0.f, 0.f, 0.f, 0.f};

    auto stage = [&](int buf, int k0) {
        const unsigned short* Ap;
        int k0l, ldA;
        if (MODE == 1) {
            int p = k0 / 768;
            Ap = (p == 0) ? A0 : (p == 1) ? A1 : (p == 2) ? A2 : A3;
            k0l = k0 - p * 768; ldA = 768;
        } else { Ap = A0; k0l = k0; ldA = K; }
#pragma unroll
        for (int i = 0; i < 4; ++i) {
            int cb = i * 256 + wid * 64;
            int c  = cb + lane;
            int r = c >> 3;
            int col = ((c & 7) ^ (r & 7)) * 8;
            gload16(Ap + (size_t)(m0 + r) * ldA + k0l + col, &As[buf][cb * 8]);
            gload16(Bt + (size_t)(n0 + r) * K   + k0  + col, &Bs[buf][cb * 8]);
        }
    };

    stage(0, kbase);
    asm volatile("s_waitcnt vmcnt(0)" ::: "memory");
    __builtin_amdgcn_s_barrier();
    __builtin_amdgcn_sched_barrier(0);

    int cur = 0;
    for (int t = 0; t < nt; ++t) {
        if (t + 1 < nt) stage(cur ^ 1, kbase + (t + 1) * 64);
#pragma unroll
        for (int kk = 0; kk < 64; kk += 32) {
            bf16x8 af[4], bfr[4];
#pragma unroll
            for (int mi = 0; mi < 4; ++mi)
                af[mi] = frag128(As[cur], wr*64 + mi*16 + fr, kk + fq*8);
#pragma unroll
            for (int ni = 0; ni < 4; ++ni)
                bfr[ni] = frag128(Bs[cur], wc*64 + ni*16 + fr, kk + fq*8);
#pragma unroll
            for (int mi = 0; mi < 4; ++mi)
#pragma unroll
                for (int ni = 0; ni < 4; ++ni)
                    acc[mi][ni] = __builtin_amdgcn_mfma_f32_16x16x32_bf16(
                        af[mi], bfr[ni], acc[mi][ni], 0, 0, 0);
        }
        asm volatile("s_waitcnt vmcnt(0)" ::: "memory");
        __builtin_amdgcn_s_barrier();
        __builtin_amdgcn_sched_barrier(0);
        cur ^= 1;
    }
#pragma unroll
    for (int mi = 0; mi < 4; ++mi)
#pragma unroll
        for (int ni = 0; ni < 4; ++ni)
#pragma unroll
            for (int v = 0; v < 4; ++v) {
                int m = m0 + wr*64 + mi*16 + fq*4 + v;
                int n = n0 + wc*64 + ni*16 + fr;
                float val = acc[mi][ni][v];
                if (KZ > 1) {
                    pbuf[((size_t)kz * 2048 + m) * 768 + n] = val;
                } else {
                    float vv = val + bias[n];
                    outf[(size_t)m * ldo + n] = vv;
                    if (MODE == 0) outb[(size_t)m * ldo + n] = f2b(vv);
                }
            }
}

// ---------------------------------------------------------------------------
// Split-K combines
// ---------------------------------------------------------------------------
__global__ __launch_bounds__(256) void wz_combine(
    const float* __restrict__ pbuf, const float* __restrict__ bz,
    const float* __restrict__ h0, const float* __restrict__ htl,
    unsigned short* __restrict__ outb)
{
    int i = blockIdx.x * 256 + threadIdx.x;
    if (i >= 2048*768/4) return;
    float4 s = *(const float4*)&pbuf[i*4];
    float4 p1 = *(const float4*)&pbuf[1536*1024 + i*4];
    float4 p2 = *(const float4*)&pbuf[2*1536*1024 + i*4];
    float4 p3 = *(const float4*)&pbuf[3*1536*1024 + i*4];
    s.x += p1.x + p2.x + p3.x; s.y += p1.y + p2.y + p3.y;
    s.z += p1.z + p2.z + p3.z; s.w += p1.w + p2.w + p3.w;
    float4 b = *(const float4*)&bz[(i % 192) * 4];
    float4 a = *(const float4*)&h0[i*4];
    float4 t = *(const float4*)&htl[i*4];
    float z0 = 1.f/(1.f+expf(-(s.x+b.x))), z1 = 1.f/(1.f+expf(-(s.y+b.y)));
    float z2 = 1.f/(1.f+expf(-(s.z+b.z))), z3 = 1.f/(1.f+expf(-(s.w+b.w)));
    outb[i*4+0] = f2b((1.f-z0)*a.x + z0*t.x);
    outb[i*4+1] = f2b((1.f-z1)*a.y + z1*t.y);
    outb[i*4+2] = f2b((1.f-z2)*a.z + z2*t.z);
    outb[i*4+3] = f2b((1.f-z3)*a.w + z3*t.w);
}

__global__ __launch_bounds__(256) void wo_combine(
    const float* __restrict__ pbuf, const float* __restrict__ bo,
    float* __restrict__ out)
{
    int i = blockIdx.x * 256 + threadIdx.x;
    if (i >= 2048*768/4) return;
    float4 s = *(const float4*)&pbuf[i*4];
    float4 p1 = *(const float4*)&pbuf[1536*1024 + i*4];
    float4 b = *(const float4*)&bo[(i % 192) * 4];
    float4 o;
    o.x = s.x + p1.x + b.x; o.y = s.y + p1.y + b.y;
    o.z = s.z + p1.z + b.z; o.w = s.w + p1.w + b.w;
    *(float4*)&out[i*4] = o;
}

// ---------------------------------------------------------------------------
// Prep kernels
// ---------------------------------------------------------------------------
__global__ __launch_bounds__(256) void cvt_bf16(const float* __restrict__ in,
                                                unsigned short* __restrict__ out, int n4)
{
    int i = blockIdx.x * 256 + threadIdx.x;
    if (i < n4) {
        float4 v = *(const float4*)&in[i * 4];
        out[i*4+0] = f2b(v.x); out[i*4+1] = f2b(v.y);
        out[i*4+2] = f2b(v.z); out[i*4+3] = f2b(v.w);
    }
}

__global__ __launch_bounds__(256) void transpose_w(const float* __restrict__ w,
                                                   unsigned short* __restrict__ wt,
                                                   int K, int N)
{
    __shared__ float tile[32][33];
    int kb = blockIdx.x * 32, nb = blockIdx.y * 32;
    int tx = threadIdx.x & 31, ty = threadIdx.x >> 5;
#pragma unroll
    for (int s = 0; s < 32; s += 8)
        tile[ty + s][tx] = w[(size_t)(kb + ty + s) * N + nb + tx];
    __syncthreads();
#pragma unroll
    for (int s = 0; s < 32; s += 8)
        wt[(size_t)(nb + ty + s) * K + kb + tx] = f2b(tile[tx][ty + s]);
}

__global__ void concat_bias(const float* __restrict__ bq, const float* __restrict__ bk,
                            const float* __restrict__ bv, float* __restrict__ o)
{
    int n = blockIdx.x * 256 + threadIdx.x;
    if (n < 2304) o[n] = (n < 768) ? bq[n] : (n < 1536) ? bk[n - 768] : bv[n - 1536];
}

__global__ __launch_bounds__(256) void build_gru_inputs(
    const float* __restrict__ h0, const float* __restrict__ hn,
    unsigned short* __restrict__ h0b, unsigned short* __restrict__ htlb,
    unsigned short* __restrict__ prodb, int n4)
{
    int i = blockIdx.x * 256 + threadIdx.x;
    if (i < n4) {
        float4 a = *(const float4*)&h0[i * 4];
        float4 b = *(const float4*)&hn[i * 4];
        h0b[i*4+0] = f2b(a.x); h0b[i*4+1] = f2b(a.y); h0b[i*4+2] = f2b(a.z); h0b[i*4+3] = f2b(a.w);
        htlb[i*4+0] = f2b(b.x); htlb[i*4+1] = f2b(b.y); htlb[i*4+2] = f2b(b.z); htlb[i*4+3] = f2b(b.w);
        prodb[i*4+0] = f2b(a.x*b.x); prodb[i*4+1] = f2b(a.y*b.y);
        prodb[i*4+2] = f2b(a.z*b.z); prodb[i*4+3] = f2b(a.w*b.w);
    }
}

// ---------------------------------------------------------------------------
// Low-rank projections via MFMA, split-K=4.
// grid (16 m-tiles, 3 sels, 4 kz). A = qkvb slice, B = pT[sel][32][768].
// ---------------------------------------------------------------------------
__global__ __launch_bounds__(256) void lowrank_mfma(
    const unsigned short* __restrict__ qkvb, const unsigned short* __restrict__ pT,
    float* __restrict__ pbuf)
{
    __shared__ unsigned short As[2][128*64];
    __shared__ unsigned short Bs[2][32*64];
    const int tid = threadIdx.x, lane = tid & 63, wid = tid >> 6;
    const int fr = lane & 15, fq = lane >> 4;
    const int m0 = blockIdx.x * 128;
    const int sel = blockIdx.y, kz = blockIdx.z;
    const int kbase = kz * 192;

    f32x4 acc[2][2];
#pragma unroll
    for (int mi = 0; mi < 2; ++mi)
#pragma unroll
        for (int ni = 0; ni < 2; ++ni) acc[mi][ni] = (f32x4){0.f,0.f,0.f,0.f};

    auto stage = [&](int buf, int k0) {
        // A tile: 128 rows x 64 cols = 1024 chunks  (BUG FIX: was i<2 = half)
#pragma unroll
        for (int i = 0; i < 4; ++i) {
            int cb = i * 256 + wid * 64, c = cb + lane;
            int r = c >> 3, col = ((c & 7) ^ (r & 7)) * 8;
            gload16(qkvb + (size_t)(m0 + r) * 2304 + sel*768 + k0 + col, &As[buf][cb * 8]);
        }
        // B tile: 32 rows x 64 cols = 256 chunks
        {
            int cb = wid * 64, c = cb + lane;
            int r = c >> 3, col = ((c & 7) ^ (r & 7)) * 8;
            gload16(pT + (size_t)sel * 32*768 + (size_t)r * 768 + k0 + col, &Bs[buf][cb * 8]);
        }
    };

    stage(0, kbase);
    asm volatile("s_waitcnt vmcnt(0)" ::: "memory");
    __builtin_amdgcn_s_barrier();
    __builtin_amdgcn_sched_barrier(0);

    int cur = 0;
    for (int t = 0; t < 3; ++t) {
        if (t + 1 < 3) stage(cur ^ 1, kbase + (t + 1) * 64);
#pragma unroll
        for (int kk = 0; kk < 64; kk += 32) {
            bf16x8 a[2], b[2];
#pragma unroll
            for (int mi = 0; mi < 2; ++mi)
                a[mi] = frag128(As[cur], wid*32 + mi*16 + fr, kk + fq*8);
#pragma unroll
            for (int ni = 0; ni < 2; ++ni)
                b[ni] = frag128(Bs[cur], ni*16 + fr, kk + fq*8);
#pragma unroll
            for (int mi = 0; mi < 2; ++mi)
#pragma unroll
                for (int ni = 0; ni < 2; ++ni)
                    acc[mi][ni] = __builtin_amdgcn_mfma_f32_16x16x32_bf16(
                        a[mi], b[ni], acc[mi][ni], 0, 0, 0);
        }
        asm volatile("s_waitcnt vmcnt(0)" ::: "memory");
        __builtin_amdgcn_s_barrier();
        __builtin_amdgcn_sched_barrier(0);
        cur ^= 1;
    }
#pragma unroll
    for (int mi = 0; mi < 2; ++mi)
#pragma unroll
        for (int ni = 0; ni < 2; ++ni)
#pragma unroll
            for (int v = 0; v < 4; ++v) {
                int m = m0 + wid*32 + mi*16 + fq*4 + v;
                int n = ni*16 + fr;
                pbuf[((size_t)(kz*3 + sel) * 2048 + m) * 32 + n] = acc[mi][ni][v];
            }
}

__global__ __launch_bounds__(256) void lowrank_finish(
    const float* __restrict__ pbuf,
    unsigned short* __restrict__ qrb, unsigned short* __restrict__ krb,
    float* __restrict__ vr, unsigned short* __restrict__ evtb)
{
    int idx = blockIdx.x * 256 + threadIdx.x;        // 3*65536
    int sel = idx >> 16, rem = idx & 65535;
    float s = pbuf[(size_t)(0*3 + sel)*65536 + rem]
            + pbuf[(size_t)(1*3 + sel)*65536 + rem]
            + pbuf[(size_t)(2*3 + sel)*65536 + rem]
            + pbuf[(size_t)(3*3 + sel)*65536 + rem];
    if (sel == 0)      qrb[rem] = f2b(s * INV_SQRT_R);
    else if (sel == 1) krb[rem] = f2b(s);
    else {
        int t = rem >> 5, r = rem & 31;
        vr[rem] = s;
        evtb[(size_t)r * 2048 + t] = f2b(expf(s));
    }
}

// ---------------------------------------------------------------------------
// Inclusive cumulative max over time per feature r. grid R, block 256
// ---------------------------------------------------------------------------
__global__ __launch_bounds__(256) void cummax_vr(const float* __restrict__ vr,
                                                 float* __restrict__ ms)
{
    __shared__ float part[256];
    int r = blockIdx.x, tid = threadIdx.x;
    int t0 = tid * 8;
    float v[8];
    float run = -INFINITY;
#pragma unroll
    for (int e = 0; e < 8; ++e) { run = fmaxf(run, vr[(t0+e)*32 + r]); v[e] = run; }
    part[tid] = run;
    __syncthreads();
    for (int off = 1; off < 256; off <<= 1) {
        float other = (tid >= off) ? part[tid - off] : -INFINITY;
        __syncthreads();
        part[tid] = fmaxf(part[tid], other);
        __syncthreads();
    }
    float excl = (tid > 0) ? part[tid - 1] : -INFINITY;
#pragma unroll
    for (int e = 0; e < 8; ++e) ms[(t0+e)*32 + r] = fmaxf(v[e], excl);
}

// ---------------------------------------------------------------------------
// Seed attention, MFMA flash-style. grid (16 i-tiles, 16 j-chunks), jc<=it.
// ---------------------------------------------------------------------------
__global__ __launch_bounds__(256) void seed_mfma(
    const unsigned short* __restrict__ qrb, const unsigned short* __restrict__ krb,
    const unsigned short* __restrict__ evtb, float* __restrict__ partial)
{
    int it = blockIdx.x, jc = blockIdx.y;
    if (jc > it) return;
    const int i0 = it * 128, j0 = jc * 128;
    __shared__ unsigned short Qs[128*32];
    __shared__ unsigned short Ks[128*32];
    __shared__ unsigned short Es[32*128];
    __shared__ unsigned short Ps[128*128];
    const int tid = threadIdx.x, lane = tid & 63, wid = tid >> 6;
    const int fr = lane & 15, fq = lane >> 4;

#pragma unroll
    for (int s = 0; s < 2; ++s) {
        int cb = s * 256 + wid * 64;
        int c = cb + lane;
        int r = c >> 2, col = (c & 3) * 8;
        gload16(qrb + (size_t)(i0 + r) * 32 + col, &Qs[cb * 8]);
        gload16(krb + (size_t)(j0 + r) * 32 + col, &Ks[cb * 8]);
    }
#pragma unroll
    for (int s = 0; s < 2; ++s) {
        int c = s * 256 + tid;
        int rr = c >> 4, cc = c & 15;
        bf16x8 v = *(const bf16x8*)&evtb[(size_t)rr * 2048 + j0 + cc * 8];
        int byte = (rr * 256 + cc * 16) ^ ((rr & 7) << 4);
        *(bf16x8*)((char*)Es + byte) = v;
    }
    __syncthreads();

    const int wr = wid >> 1, wc = wid & 1;
    bf16x8 af[4], bk[4];
#pragma unroll
    for (int mi = 0; mi < 4; ++mi)
        af[mi] = *(const bf16x8*)&Qs[(wr*64 + mi*16 + fr)*32 + fq*8];
#pragma unroll
    for (int ni = 0; ni < 4; ++ni)
        bk[ni] = *(const bf16x8*)&Ks[(wc*64 + ni*16 + fr)*32 + fq*8];
#pragma unroll
    for (int mi = 0; mi < 4; ++mi)
#pragma unroll
        for (int ni = 0; ni < 4; ++ni) {
            f32x4 s4 = __builtin_amdgcn_mfma_f32_16x16x32_bf16(
                af[mi], bk[ni], (f32x4){0.f,0.f,0.f,0.f}, 0, 0, 0);
#pragma unroll
            for (int v = 0; v < 4; ++v) {
                int row = wr*64 + mi*16 + fq*4 + v;
                int col = wc*64 + ni*16 + fr;
                float a = 0.f;
                if (j0 + col <= i0 + row) {
                    float s = s4[v];
                    a = 1.f / (1.f + expf(-(s*s + B_SCALAR)));
                }
                int byte = (row * 256 + col * 2) ^ ((row & 7) << 4);
                *(unsigned short*)((char*)Ps + byte) = f2b(a);
            }
        }
    __syncthreads();

    f32x4 yacc[2][2];
#pragma unroll
    for (int mi = 0; mi < 2; ++mi)
#pragma unroll
        for (int nf = 0; nf < 2; ++nf) yacc[mi][nf] = (f32x4){0.f,0.f,0.f,0.f};
#pragma unroll
    for (int ks = 0; ks < 4; ++ks) {
        bf16x8 pa[2], eb[2];
#pragma unroll
        for (int mi = 0; mi < 2; ++mi) {
            int row = wid*32 + mi*16 + fr;
            int byte = (row * 256 + ks * 64 + fq * 16) ^ ((row & 7) << 4);
            pa[mi] = *(const bf16x8*)((const char*)Ps + byte);
        }
#pragma unroll
        for (int nf = 0; nf < 2; ++nf) {
            int rrow = nf*16 + fr;
            int byte = (rrow * 256 + ks * 64 + fq * 16) ^ ((rrow & 7) << 4);
            eb[nf] = *(const bf16x8*)((const char*)Es + byte);
        }
#pragma unroll
        for (int mi = 0; mi < 2; ++mi)
#pragma unroll
            for (int nf = 0; nf < 2; ++nf)
                yacc[mi][nf] = __builtin_amdgcn_mfma_f32_16x16x32_bf16(
                    pa[mi], eb[nf], yacc[mi][nf], 0, 0, 0);
    }
    float* pout = partial + ((size_t)(it*16 + jc) * 128) * 32;
#pragma unroll
    for (int mi = 0; mi < 2; ++mi)
#pragma unroll
        for (int nf = 0; nf < 2; ++nf)
#pragma unroll
            for (int v = 0; v < 4; ++v) {
                int row = wid*32 + mi*16 + fq*4 + v;
                int col = nf*16 + fr;
                pout[row*32 + col] = yacc[mi][nf][v];
            }
}

__global__ __launch_bounds__(256) void seed_finish(const float* __restrict__ partial,
                                                   const float* __restrict__ ms,
                                                   float* __restrict__ lr)
{
    int idx = blockIdx.x * 256 + threadIdx.x;
    int i = idx >> 5, r = idx & 31;
    int it = i >> 7, row = i & 127;
    float y = 0.f;
    for (int jjc = 0; jjc <= it; ++jjc)
        y += partial[(((size_t)(it*16 + jjc) * 128) + row) * 32 + r];
    float m = ms[idx];
    lr[idx] = logf(fmaxf(y * expf(-m), 1e-30f)) + m;
}

// ---------------------------------------------------------------------------
// H0 = Lr @ up_w.  grid T, block 256, K=32
// ---------------------------------------------------------------------------
__global__ __launch_bounds__(256) void up_proj(const float* __restrict__ lr,
                                               const float* __restrict__ up,
                                               float* __restrict__ h0)
{
    __shared__ float ls[32];
    int t = blockIdx.x, tid = threadIdx.x;
    if (tid < 32) ls[tid] = lr[t*32 + tid];
    __syncthreads();
    for (int c = tid; c < 768; c += 256) {
        float acc = 0.f;
#pragma unroll
        for (int rr = 0; rr < 32; ++rr) acc = fmaf(ls[rr], up[rr*768 + c], acc);
        h0[t*768 + c] = acc;
    }
}

// ---------------------------------------------------------------------------
// Per-(t,h) L2-normalized Q,K -> bf16. grid T, block 768
// ---------------------------------------------------------------------------
__global__ void head_norms_write(const float* __restrict__ qkv,
                                 unsigned short* __restrict__ qhatb,
                                 unsigned short* __restrict__ khatb)
{
    int t = blockIdx.x, tid = threadIdx.x;
    int h = tid >> 6, d = tid & 63;
    float q = qkv[t*2304 + h*64 + d];
    float k = qkv[t*2304 + 768 + h*64 + d];
    float sq = q*q, sk = k*k;
#pragma unroll
    for (int off = 32; off; off >>= 1) { sq += __shfl_xor(sq, off); sk += __shfl_xor(sk, off); }
    float iq = 1.f / fmaxf(sqrtf(sq), 1e-12f);
    float ik = 1.f / fmaxf(sqrtf(sk), 1e-12f);
    qhatb[(size_t)t*768 + h*64 + d] = f2b(q * iq);
    khatb[(size_t)t*768 + h*64 + d] = f2b(k * ik);
}

// ---------------------------------------------------------------------------
// Sliding past-window (129) max of V + Vexp = exp(V - m), both fp32 [t][c].
// grid (C/64, T/64)
// ---------------------------------------------------------------------------
__global__ __launch_bounds__(256) void slide_max(const float* __restrict__ qkv,
                                                 float* __restrict__ mnear,
                                                 float* __restrict__ vexp)
{
    __shared__ float vs[192][64];
    int c0 = blockIdx.x * 64, t0 = blockIdx.y * 64;
    int tid = threadIdx.x;
#pragma unroll
    for (int s = 0; s < 12; ++s) {
        int idx = tid + s * 256;
        int rr = idx >> 4, c4 = (idx & 15) * 4;
        int t = t0 - 128 + rr;
        float4 v4;
        if (t < 0) v4 = make_float4(-INFINITY, -INFINITY, -INFINITY, -INFINITY);
        else       v4 = *(const float4*)&qkv[t*2304 + 1536 + c0 + c4];
        *(float4*)&vs[rr][c4] = v4;
    }
    __syncthreads();
    int c = tid & 63, tg = tid >> 6;
    for (int u = 0; u < 16; ++u) {
        int tl = tg * 16 + u;
        float m = -INFINITY;
        for (int s = 0; s < 129; ++s) m = fmaxf(m, vs[tl + s][c]);
        float v = vs[tl + 128][c];
        int t = t0 + tl;
        mnear[(size_t)t*768 + c0 + c] = m;
        vexp [(size_t)t*768 + c0 + c] = expf(v - m);
    }
}

// ---------------------------------------------------------------------------
// Fused near-field v2 (precision-hardened):
//  QK^T via bf16 MFMA -> masked sigmoid -> P kept FP32 in LDS ->
//  PV in FP32 VALU (V streamed fp32 from global, wave-broadcast P reads) ->
//  log+m -> head gate -> hn.
// grid (64 i-tiles of 32, 12 heads), block 256 (4 waves). LDS ~45 KB.
// ---------------------------------------------------------------------------
__global__ __launch_bounds__(256) void near_fused2(
    const unsigned short* __restrict__ qhatb, const unsigned short* __restrict__ khatb,
    const float* __restrict__ vexp, const float* __restrict__ mnear,
    const float* __restrict__ gu, const float* __restrict__ gb,
    float* __restrict__ hn)
{
    __shared__ unsigned short Qs[32*64];    // 4 KB
    __shared__ unsigned short Ks[160*64];   // 20 KB
    __shared__ float Pf[32][161];           // ~20.6 KB, fp32 P
    const int it = blockIdx.x, hh = blockIdx.y;
    const int i0 = it * 32;
    const int tid = threadIdx.x, lane = tid & 63, wid = tid >> 6;
    const int fr = lane & 15, fq = lane >> 4;

    // ---- stage Qhat [32][64]
    {
        int cb = wid * 64, c = cb + lane;
        int r = c >> 3, col = ((c & 7) ^ (r & 7)) * 8;
        gload16(qhatb + (size_t)(i0 + r) * 768 + hh*64 + col, &Qs[cb * 8]);
    }
    // ---- stage Khat [160][64], rows j = i0-128+r (clamped; masked later)
#pragma unroll
    for (int i = 0; i < 5; ++i) {
        int cb = i * 256 + wid * 64, c = cb + lane;
        int r = c >> 3, col = ((c & 7) ^ (r & 7)) * 8;
        int j = i0 - 128 + r; if (j < 0) j = 0;
        gload16(khatb + (size_t)j * 768 + hh*64 + col, &Ks[cb * 8]);
    }
    __syncthreads();

    // ---- S = Qhat Khat^T: M=32, N=160, K=64. Wave (wm,wn): wm=wid&1 m-frag,
    //      wn=wid>>1 owns 5 n-frags.
    const int wm = wid & 1, wn = wid >> 1;
    f32x4 sacc[5];
#pragma unroll
    for (int u = 0; u < 5; ++u) sacc[u] = (f32x4){0.f,0.f,0.f,0.f};
#pragma unroll
    for (int kt = 0; kt < 2; ++kt) {
        int kk = kt * 32;
        bf16x8 qa = frag128(Qs, wm*16 + fr, kk + fq*8);
#pragma unroll
        for (int u = 0; u < 5; ++u) {
            bf16x8 kb = frag128(Ks, (wn*5 + u)*16 + fr, kk + fq*8);
            sacc[u] = __builtin_amdgcn_mfma_f32_16x16x32_bf16(qa, kb, sacc[u], 0, 0, 0);
        }
    }
    // ---- masked sigmoid -> P fp32
#pragma unroll
    for (int u = 0; u < 5; ++u)
#pragma unroll
        for (int v = 0; v < 4; ++v) {
            int il = wm*16 + fq*4 + v;
            int jl = (wn*5 + u)*16 + fr;
            float s = sacc[u][v];
            float a = 0.f;
            if (jl >= il && jl <= il + 128 && (i0 - 128 + jl) >= 0)
                a = 1.f / (1.f + expf(-(s*s*INV_TAU + B_SCALAR)));
            Pf[il][jl] = a;
        }
    __syncthreads();

    // ---- Y = P @ Vexp, fp32 VALU. Wave wid owns rows [8wid, 8wid+8), lane = d.
    const int d = lane;
    const int r0 = wid * 8;
    float acc[8] = {0.f,0.f,0.f,0.f,0.f,0.f,0.f,0.f};
    int jl0 = (i0 >= 128) ? 0 : (128 - i0);
    for (int jl = jl0; jl < 160; ++jl) {
        float vv = vexp[(size_t)(i0 - 128 + jl) * 768 + hh*64 + d];
#pragma unroll
        for (int q = 0; q < 8; ++q)
            acc[q] = fmaf(Pf[r0 + q][jl], vv, acc[q]);
    }

    // ---- epilogue: log + m, head gate (full-wave reduce over d), write
    float guv = gu[hh*64 + d];
    float gbh = gb[hh];
#pragma unroll
    for (int q = 0; q < 8; ++q) {
        int row = i0 + r0 + q;
        float h = logf(fmaxf(acc[q], 1e-30f)) + mnear[(size_t)row*768 + hh*64 + d];
        float s = h * guv;
#pragma unroll
        for (int off = 32; off; off >>= 1) s += __shfl_xor(s, off);
        float g = 1.f / (1.f + expf(-(s + gbh)));
        hn[(size_t)row*768 + hh*64 + d] = h * g;
    }
}

// ---------------------------------------------------------------------------
extern "C" void kernel_launch(void* const* d_in, const int* in_sizes, int n_in,
                              void* d_out, int out_size, void* d_ws, size_t ws_size,
                              hipStream_t stream)
{
    const float* x  = (const float*)d_in[0];
    const float* wq = (const float*)d_in[1];  const float* bq = (const float*)d_in[2];
    const float* wk = (const float*)d_in[3];  const float* bk = (const float*)d_in[4];
    const float* wv = (const float*)d_in[5];  const float* bv = (const float*)d_in[6];
    const float* wo = (const float*)d_in[7];  const float* bo = (const float*)d_in[8];
    const float* pq = (const float*)d_in[9];  const float* pk = (const float*)d_in[10];
    const float* pv = (const float*)d_in[11];
    const float* up = (const float*)d_in[12];
    const float* gu = (const float*)d_in[13]; const float* gb = (const float*)d_in[14];
    const float* wz = (const float*)d_in[15]; const float* bz = (const float*)d_in[16];
    float* out = (float*)d_out;

    float* w = (float*)d_ws;
    float* qkv  = w; w += 2048*2304;
    float* vr   = w; w += 2048*32;
    float* ms   = w; w += 2048*32;
    float* lr   = w; w += 2048*32;
    float* h0   = w; w += 2048*768;
    float* mnear= w; w += 2048*768;
    float* vexp = w; w += 2048*768;
    float* hn   = w; w += 2048*768;          // Htilde after near_fused2
    float* partial = w; w += 16*16*128*32;   // seed partials
    float* pgemm = w; w += 4*2048*768;       // split-K partials (Wz 4 / Wo 2)
    float* plr   = w; w += 4*3*2048*32;      // lowrank split-K partials
    float* bqkv = w; w += 2304;
    unsigned short* xb     = (unsigned short*)w; w += 2048*768/2;
    unsigned short* qkvb   = (unsigned short*)w; w += 2048*2304/2;
    unsigned short* wqkvT  = (unsigned short*)w; w += 2304*768/2;
    unsigned short* wzT    = (unsigned short*)w; w += 768*3072/2;
    unsigned short* woT    = (unsigned short*)w; w += 768*768/2;
    unsigned short* pT     = (unsigned short*)w; w += 3*32*768/2;
    unsigned short* h0b    = (unsigned short*)w; w += 2048*768/2;
    unsigned short* htlb   = (unsigned short*)w; w += 2048*768/2;
    unsigned short* prodb  = (unsigned short*)w; w += 2048*768/2;
    unsigned short* houtb  = (unsigned short*)w; w += 2048*768/2;
    unsigned short* qrb    = (unsigned short*)w; w += 2048*32/2;
    unsigned short* krb    = (unsigned short*)w; w += 2048*32/2;
    unsigned short* evtb   = (unsigned short*)w; w += 32*2048/2;
    unsigned short* qhatb  = (unsigned short*)w; w += 2048*768/2;
    unsigned short* khatb  = (unsigned short*)w; w += 2048*768/2;

    // ---- prep
    cvt_bf16<<<1536, 256, 0, stream>>>(x, xb, 2048*768/4);
    transpose_w<<<dim3(24,24), 256, 0, stream>>>(wq, wqkvT,            768, 768);
    transpose_w<<<dim3(24,24), 256, 0, stream>>>(wk, wqkvT + 768*768,  768, 768);
    transpose_w<<<dim3(24,24), 256, 0, stream>>>(wv, wqkvT + 1536*768, 768, 768);
    transpose_w<<<dim3(96,24), 256, 0, stream>>>(wz, wzT, 3072, 768);
    transpose_w<<<dim3(24,24), 256, 0, stream>>>(wo, woT, 768, 768);
    transpose_w<<<dim3(24,1),  256, 0, stream>>>(pq, pT,            768, 32);
    transpose_w<<<dim3(24,1),  256, 0, stream>>>(pk, pT + 32*768,   768, 32);
    transpose_w<<<dim3(24,1),  256, 0, stream>>>(pv, pT + 2*32*768, 768, 32);
    concat_bias<<<9, 256, 0, stream>>>(bq, bk, bv, bqkv);

    // 0) QKV projections (fp32 + bf16 copy)
    gemm_mfma<0,1><<<dim3(18,16,1), 256, 0, stream>>>(xb, nullptr, nullptr, nullptr,
        wqkvT, bqkv, qkv, qkvb, nullptr, 768, 2304);

    // 1) low-rank path
    lowrank_mfma<<<dim3(16,3,4), 256, 0, stream>>>(qkvb, pT, plr);
    lowrank_finish<<<768, 256, 0, stream>>>(plr, qrb, krb, vr, evtb);
    cummax_vr<<<32, 256, 0, stream>>>(vr, ms);
    seed_mfma<<<dim3(16,16), 256, 0, stream>>>(qrb, krb, evtb, partial);
    seed_finish<<<256, 256, 0, stream>>>(partial, ms, lr);
    up_proj<<<2048, 256, 0, stream>>>(lr, up, h0);

    // 2) near-field path (fused, precision-hardened)
    head_norms_write<<<2048, 768, 0, stream>>>(qkv, qhatb, khatb);
    slide_max<<<dim3(12,32), 256, 0, stream>>>(qkv, mnear, vexp);
    near_fused2<<<dim3(64,12), 256, 0, stream>>>(qhatb, khatb, vexp, mnear, gu, gb, hn);

    // 3) GRU blend (split-K=4) + output projection (split-K=2)
    build_gru_inputs<<<1536, 256, 0, stream>>>(h0, hn, h0b, htlb, prodb, 2048*768/4);
    gemm_mfma<1,4><<<dim3(6,16,4), 256, 0, stream>>>(xb, h0b, htlb, prodb,
        wzT, nullptr, nullptr, nullptr, pgemm, 3072, 768);
    wz_combine<<<1536, 256, 0, stream>>>(pgemm, bz, h0, hn, houtb);
    gemm_mfma<2,2><<<dim3(6,16,2), 256, 0, stream>>>(houtb, nullptr, nullptr, nullptr,
        woT, nullptr, nullptr, nullptr, pgemm, 768, 768);
    wo_combine<<<1536, 256, 0, stream>>>(pgemm, bo, out);
}

// Round 8
// 180.913 us; speedup vs baseline: 5.4728x; 1.2388x over previous
//
#include <hip/hip_runtime.h>
#include <math.h>

// Problem constants (fixed: B=1, T=2048, C=768, H=12, D=64, R=32, K0=128)
static constexpr float B_SCALAR    = -7.6246189861593985f;   // -log(2048)
static constexpr float INV_TAU     = 2.8571428571428571f;    // 1/0.35
static constexpr float INV_SQRT_R  = 0.17677669529663687f;   // 1/sqrt(32)

typedef __attribute__((ext_vector_type(8))) short bf16x8;
typedef __attribute__((ext_vector_type(4))) float f32x4;

__device__ __forceinline__ unsigned short f2b(float f) {
    union { float f; unsigned int u; } v; v.f = f;
    unsigned int r = v.u + 0x7fffu + ((v.u >> 16) & 1u);
    return (unsigned short)(r >> 16);
}

typedef const __attribute__((address_space(1))) unsigned int* gp1_t;
typedef __attribute__((address_space(3))) unsigned int* lp3_t;
__device__ __forceinline__ void gload16(const unsigned short* g, unsigned short* l) {
    __builtin_amdgcn_global_load_lds((gp1_t)g, (lp3_t)l, 16, 0, 0);
}

// XOR-swizzled bf16x8 read from a row-major LDS tile with 128B rows
__device__ __forceinline__ bf16x8 frag128(const unsigned short* base, int row, int elem) {
    int byte = (row * 128 + elem * 2) ^ ((row & 7) << 4);
    return *(const bf16x8*)((const char*)base + byte);
}
// same for 384B rows (192 bf16 per row)
__device__ __forceinline__ bf16x8 frag384(const unsigned short* base, int row, int elem) {
    int byte = (row * 384 + elem * 2) ^ ((row & 7) << 4);
    return *(const bf16x8*)((const char*)base + byte);
}

// ---------------------------------------------------------------------------
// bf16 MFMA GEMM, 128x128 tile, BK=64, double-buffered 2-phase prefetch,
// XOR-swizzled LDS (source-permuted global_load_lds + same involution on read).
// MODE 0: QKV (KZ=1, fp32 out + bf16 copy)  MODE 1: Wz piecewise A (split-K)
// MODE 2: Wo (split-K)
// ---------------------------------------------------------------------------
template<int MODE, int KZ>
__global__ __launch_bounds__(256) void gemm_mfma(
    const unsigned short* __restrict__ A0, const unsigned short* __restrict__ A1,
    const unsigned short* __restrict__ A2, const unsigned short* __restrict__ A3,
    const unsigned short* __restrict__ Bt, const float* __restrict__ bias,
    float* __restrict__ outf, unsigned short* __restrict__ outb,
    float* __restrict__ pbuf, int K, int ldo)
{
    __shared__ unsigned short As[2][128*64];
    __shared__ unsigned short Bs[2][128*64];
    const int tid = threadIdx.x;
    const int lane = tid & 63, wid = tid >> 6;
    const int wr = wid >> 1, wc = wid & 1;
    const int fr = lane & 15, fq = lane >> 4;
    const int n0 = blockIdx.x * 128, m0 = blockIdx.y * 128;
    const int kz = blockIdx.z;
    const int kslice = K / KZ;
    const int kbase = kz * kslice;
    const int nt = kslice / 64;

    f32x4 acc[4][4];
#pragma unroll
    for (int mi = 0; mi < 4; ++mi)
#pragma unroll
        for (int ni = 0; ni < 4; ++ni) acc[mi][ni] = (f32x4){0.f, 0.f, 0.f, 0.f};

    auto stage = [&](int buf, int k0) {
        const unsigned short* Ap;
        int k0l, ldA;
        if (MODE == 1) {
            int p = k0 / 768;
            Ap = (p == 0) ? A0 : (p == 1) ? A1 : (p == 2) ? A2 : A3;
            k0l = k0 - p * 768; ldA = 768;
        } else { Ap = A0; k0l = k0; ldA = K; }
#pragma unroll
        for (int i = 0; i < 4; ++i) {
            int cb = i * 256 + wid * 64;
            int c  = cb + lane;
            int r = c >> 3;
            int col = ((c & 7) ^ (r & 7)) * 8;
            gload16(Ap + (size_t)(m0 + r) * ldA + k0l + col, &As[buf][cb * 8]);
            gload16(Bt + (size_t)(n0 + r) * K   + k0  + col, &Bs[buf][cb * 8]);
        }
    };

    stage(0, kbase);
    asm volatile("s_waitcnt vmcnt(0)" ::: "memory");
    __builtin_amdgcn_s_barrier();
    __builtin_amdgcn_sched_barrier(0);

    int cur = 0;
    for (int t = 0; t < nt; ++t) {
        if (t + 1 < nt) stage(cur ^ 1, kbase + (t + 1) * 64);
#pragma unroll
        for (int kk = 0; kk < 64; kk += 32) {
            bf16x8 af[4], bfr[4];
#pragma unroll
            for (int mi = 0; mi < 4; ++mi)
                af[mi] = frag128(As[cur], wr*64 + mi*16 + fr, kk + fq*8);
#pragma unroll
            for (int ni = 0; ni < 4; ++ni)
                bfr[ni] = frag128(Bs[cur], wc*64 + ni*16 + fr, kk + fq*8);
#pragma unroll
            for (int mi = 0; mi < 4; ++mi)
#pragma unroll
                for (int ni = 0; ni < 4; ++ni)
                    acc[mi][ni] = __builtin_amdgcn_mfma_f32_16x16x32_bf16(
                        af[mi], bfr[ni], acc[mi][ni], 0, 0, 0);
        }
        asm volatile("s_waitcnt vmcnt(0)" ::: "memory");
        __builtin_amdgcn_s_barrier();
        __builtin_amdgcn_sched_barrier(0);
        cur ^= 1;
    }
#pragma unroll
    for (int mi = 0; mi < 4; ++mi)
#pragma unroll
        for (int ni = 0; ni < 4; ++ni)
#pragma unroll
            for (int v = 0; v < 4; ++v) {
                int m = m0 + wr*64 + mi*16 + fq*4 + v;
                int n = n0 + wc*64 + ni*16 + fr;
                float val = acc[mi][ni][v];
                if (KZ > 1) {
                    pbuf[((size_t)kz * 2048 + m) * 768 + n] = val;
                } else {
                    float vv = val + bias[n];
                    outf[(size_t)m * ldo + n] = vv;
                    if (MODE == 0) outb[(size_t)m * ldo + n] = f2b(vv);
                }
            }
}

// ---------------------------------------------------------------------------
// Split-K combines
// ---------------------------------------------------------------------------
__global__ __launch_bounds__(256) void wz_combine(
    const float* __restrict__ pbuf, const float* __restrict__ bz,
    const float* __restrict__ h0, const float* __restrict__ htl,
    unsigned short* __restrict__ outb)
{
    int i = blockIdx.x * 256 + threadIdx.x;
    if (i >= 2048*768/4) return;
    float4 s = *(const float4*)&pbuf[i*4];
    float4 p1 = *(const float4*)&pbuf[1536*1024 + i*4];
    float4 p2 = *(const float4*)&pbuf[2*1536*1024 + i*4];
    float4 p3 = *(const float4*)&pbuf[3*1536*1024 + i*4];
    s.x += p1.x + p2.x + p3.x; s.y += p1.y + p2.y + p3.y;
    s.z += p1.z + p2.z + p3.z; s.w += p1.w + p2.w + p3.w;
    float4 b = *(const float4*)&bz[(i % 192) * 4];
    float4 a = *(const float4*)&h0[i*4];
    float4 t = *(const float4*)&htl[i*4];
    float z0 = 1.f/(1.f+expf(-(s.x+b.x))), z1 = 1.f/(1.f+expf(-(s.y+b.y)));
    float z2 = 1.f/(1.f+expf(-(s.z+b.z))), z3 = 1.f/(1.f+expf(-(s.w+b.w)));
    outb[i*4+0] = f2b((1.f-z0)*a.x + z0*t.x);
    outb[i*4+1] = f2b((1.f-z1)*a.y + z1*t.y);
    outb[i*4+2] = f2b((1.f-z2)*a.z + z2*t.z);
    outb[i*4+3] = f2b((1.f-z3)*a.w + z3*t.w);
}

__global__ __launch_bounds__(256) void wo_combine(
    const float* __restrict__ pbuf, const float* __restrict__ bo,
    float* __restrict__ out)
{
    int i = blockIdx.x * 256 + threadIdx.x;
    if (i >= 2048*768/4) return;
    float4 s = *(const float4*)&pbuf[i*4];
    float4 p1 = *(const float4*)&pbuf[1536*1024 + i*4];
    float4 b = *(const float4*)&bo[(i % 192) * 4];
    float4 o;
    o.x = s.x + p1.x + b.x; o.y = s.y + p1.y + b.y;
    o.z = s.z + p1.z + b.z; o.w = s.w + p1.w + b.w;
    *(float4*)&out[i*4] = o;
}

// ---------------------------------------------------------------------------
// Prep kernels
// ---------------------------------------------------------------------------
__global__ __launch_bounds__(256) void cvt_bf16(const float* __restrict__ in,
                                                unsigned short* __restrict__ out, int n4)
{
    int i = blockIdx.x * 256 + threadIdx.x;
    if (i < n4) {
        float4 v = *(const float4*)&in[i * 4];
        out[i*4+0] = f2b(v.x); out[i*4+1] = f2b(v.y);
        out[i*4+2] = f2b(v.z); out[i*4+3] = f2b(v.w);
    }
}

__global__ __launch_bounds__(256) void transpose_w(const float* __restrict__ w,
                                                   unsigned short* __restrict__ wt,
                                                   int K, int N)
{
    __shared__ float tile[32][33];
    int kb = blockIdx.x * 32, nb = blockIdx.y * 32;
    int tx = threadIdx.x & 31, ty = threadIdx.x >> 5;
#pragma unroll
    for (int s = 0; s < 32; s += 8)
        tile[ty + s][tx] = w[(size_t)(kb + ty + s) * N + nb + tx];
    __syncthreads();
#pragma unroll
    for (int s = 0; s < 32; s += 8)
        wt[(size_t)(nb + ty + s) * K + kb + tx] = f2b(tile[tx][ty + s]);
}

__global__ void concat_bias(const float* __restrict__ bq, const float* __restrict__ bk,
                            const float* __restrict__ bv, float* __restrict__ o)
{
    int n = blockIdx.x * 256 + threadIdx.x;
    if (n < 2304) o[n] = (n < 768) ? bq[n] : (n < 1536) ? bk[n - 768] : bv[n - 1536];
}

__global__ __launch_bounds__(256) void build_gru_inputs(
    const float* __restrict__ h0, const float* __restrict__ hn,
    unsigned short* __restrict__ h0b, unsigned short* __restrict__ htlb,
    unsigned short* __restrict__ prodb, int n4)
{
    int i = blockIdx.x * 256 + threadIdx.x;
    if (i < n4) {
        float4 a = *(const float4*)&h0[i * 4];
        float4 b = *(const float4*)&hn[i * 4];
        h0b[i*4+0] = f2b(a.x); h0b[i*4+1] = f2b(a.y); h0b[i*4+2] = f2b(a.z); h0b[i*4+3] = f2b(a.w);
        htlb[i*4+0] = f2b(b.x); htlb[i*4+1] = f2b(b.y); htlb[i*4+2] = f2b(b.z); htlb[i*4+3] = f2b(b.w);
        prodb[i*4+0] = f2b(a.x*b.x); prodb[i*4+1] = f2b(a.y*b.y);
        prodb[i*4+2] = f2b(a.z*b.z); prodb[i*4+3] = f2b(a.w*b.w);
    }
}

// ---------------------------------------------------------------------------
// Low-rank projections via MFMA, split-K=4.
// grid (16 m-tiles, 3 sels, 4 kz). A = qkvb slice, B = pT[sel][32][768].
// ---------------------------------------------------------------------------
__global__ __launch_bounds__(256) void lowrank_mfma(
    const unsigned short* __restrict__ qkvb, const unsigned short* __restrict__ pT,
    float* __restrict__ pbuf)
{
    __shared__ unsigned short As[2][128*64];
    __shared__ unsigned short Bs[2][32*64];
    const int tid = threadIdx.x, lane = tid & 63, wid = tid >> 6;
    const int fr = lane & 15, fq = lane >> 4;
    const int m0 = blockIdx.x * 128;
    const int sel = blockIdx.y, kz = blockIdx.z;
    const int kbase = kz * 192;

    f32x4 acc[2][2];
#pragma unroll
    for (int mi = 0; mi < 2; ++mi)
#pragma unroll
        for (int ni = 0; ni < 2; ++ni) acc[mi][ni] = (f32x4){0.f,0.f,0.f,0.f};

    auto stage = [&](int buf, int k0) {
        // A tile: 128 rows x 64 cols = 1024 chunks (4 x 256)
#pragma unroll
        for (int i = 0; i < 4; ++i) {
            int cb = i * 256 + wid * 64, c = cb + lane;
            int r = c >> 3, col = ((c & 7) ^ (r & 7)) * 8;
            gload16(qkvb + (size_t)(m0 + r) * 2304 + sel*768 + k0 + col, &As[buf][cb * 8]);
        }
        // B tile: 32 rows x 64 cols = 256 chunks
        {
            int cb = wid * 64, c = cb + lane;
            int r = c >> 3, col = ((c & 7) ^ (r & 7)) * 8;
            gload16(pT + (size_t)sel * 32*768 + (size_t)r * 768 + k0 + col, &Bs[buf][cb * 8]);
        }
    };

    stage(0, kbase);
    asm volatile("s_waitcnt vmcnt(0)" ::: "memory");
    __builtin_amdgcn_s_barrier();
    __builtin_amdgcn_sched_barrier(0);

    int cur = 0;
    for (int t = 0; t < 3; ++t) {
        if (t + 1 < 3) stage(cur ^ 1, kbase + (t + 1) * 64);
#pragma unroll
        for (int kk = 0; kk < 64; kk += 32) {
            bf16x8 a[2], b[2];
#pragma unroll
            for (int mi = 0; mi < 2; ++mi)
                a[mi] = frag128(As[cur], wid*32 + mi*16 + fr, kk + fq*8);
#pragma unroll
            for (int ni = 0; ni < 2; ++ni)
                b[ni] = frag128(Bs[cur], ni*16 + fr, kk + fq*8);
#pragma unroll
            for (int mi = 0; mi < 2; ++mi)
#pragma unroll
                for (int ni = 0; ni < 2; ++ni)
                    acc[mi][ni] = __builtin_amdgcn_mfma_f32_16x16x32_bf16(
                        a[mi], b[ni], acc[mi][ni], 0, 0, 0);
        }
        asm volatile("s_waitcnt vmcnt(0)" ::: "memory");
        __builtin_amdgcn_s_barrier();
        __builtin_amdgcn_sched_barrier(0);
        cur ^= 1;
    }
#pragma unroll
    for (int mi = 0; mi < 2; ++mi)
#pragma unroll
        for (int ni = 0; ni < 2; ++ni)
#pragma unroll
            for (int v = 0; v < 4; ++v) {
                int m = m0 + wid*32 + mi*16 + fq*4 + v;
                int n = ni*16 + fr;
                pbuf[((size_t)(kz*3 + sel) * 2048 + m) * 32 + n] = acc[mi][ni][v];
            }
}

__global__ __launch_bounds__(256) void lowrank_finish(
    const float* __restrict__ pbuf,
    unsigned short* __restrict__ qrb, unsigned short* __restrict__ krb,
    float* __restrict__ vr, unsigned short* __restrict__ evtb)
{
    int idx = blockIdx.x * 256 + threadIdx.x;        // 3*65536
    int sel = idx >> 16, rem = idx & 65535;
    float s = pbuf[(size_t)(0*3 + sel)*65536 + rem]
            + pbuf[(size_t)(1*3 + sel)*65536 + rem]
            + pbuf[(size_t)(2*3 + sel)*65536 + rem]
            + pbuf[(size_t)(3*3 + sel)*65536 + rem];
    if (sel == 0)      qrb[rem] = f2b(s * INV_SQRT_R);
    else if (sel == 1) krb[rem] = f2b(s);
    else {
        int t = rem >> 5, r = rem & 31;
        vr[rem] = s;
        evtb[(size_t)r * 2048 + t] = f2b(expf(s));
    }
}

// ---------------------------------------------------------------------------
// Inclusive cumulative max over time per feature r. grid R, block 256
// ---------------------------------------------------------------------------
__global__ __launch_bounds__(256) void cummax_vr(const float* __restrict__ vr,
                                                 float* __restrict__ ms)
{
    __shared__ float part[256];
    int r = blockIdx.x, tid = threadIdx.x;
    int t0 = tid * 8;
    float v[8];
    float run = -INFINITY;
#pragma unroll
    for (int e = 0; e < 8; ++e) { run = fmaxf(run, vr[(t0+e)*32 + r]); v[e] = run; }
    part[tid] = run;
    __syncthreads();
    for (int off = 1; off < 256; off <<= 1) {
        float other = (tid >= off) ? part[tid - off] : -INFINITY;
        __syncthreads();
        part[tid] = fmaxf(part[tid], other);
        __syncthreads();
    }
    float excl = (tid > 0) ? part[tid - 1] : -INFINITY;
#pragma unroll
    for (int e = 0; e < 8; ++e) ms[(t0+e)*32 + r] = fmaxf(v[e], excl);
}

// ---------------------------------------------------------------------------
// Seed attention, MFMA flash-style. grid (16 i-tiles, 16 j-chunks), jc<=it.
// ---------------------------------------------------------------------------
__global__ __launch_bounds__(256) void seed_mfma(
    const unsigned short* __restrict__ qrb, const unsigned short* __restrict__ krb,
    const unsigned short* __restrict__ evtb, float* __restrict__ partial)
{
    int it = blockIdx.x, jc = blockIdx.y;
    if (jc > it) return;
    const int i0 = it * 128, j0 = jc * 128;
    __shared__ unsigned short Qs[128*32];
    __shared__ unsigned short Ks[128*32];
    __shared__ unsigned short Es[32*128];
    __shared__ unsigned short Ps[128*128];
    const int tid = threadIdx.x, lane = tid & 63, wid = tid >> 6;
    const int fr = lane & 15, fq = lane >> 4;

#pragma unroll
    for (int s = 0; s < 2; ++s) {
        int cb = s * 256 + wid * 64;
        int c = cb + lane;
        int r = c >> 2, col = (c & 3) * 8;
        gload16(qrb + (size_t)(i0 + r) * 32 + col, &Qs[cb * 8]);
        gload16(krb + (size_t)(j0 + r) * 32 + col, &Ks[cb * 8]);
    }
#pragma unroll
    for (int s = 0; s < 2; ++s) {
        int c = s * 256 + tid;
        int rr = c >> 4, cc = c & 15;
        bf16x8 v = *(const bf16x8*)&evtb[(size_t)rr * 2048 + j0 + cc * 8];
        int byte = (rr * 256 + cc * 16) ^ ((rr & 7) << 4);
        *(bf16x8*)((char*)Es + byte) = v;
    }
    __syncthreads();

    const int wr = wid >> 1, wc = wid & 1;
    bf16x8 af[4], bk[4];
#pragma unroll
    for (int mi = 0; mi < 4; ++mi)
        af[mi] = *(const bf16x8*)&Qs[(wr*64 + mi*16 + fr)*32 + fq*8];
#pragma unroll
    for (int ni = 0; ni < 4; ++ni)
        bk[ni] = *(const bf16x8*)&Ks[(wc*64 + ni*16 + fr)*32 + fq*8];
#pragma unroll
    for (int mi = 0; mi < 4; ++mi)
#pragma unroll
        for (int ni = 0; ni < 4; ++ni) {
            f32x4 s4 = __builtin_amdgcn_mfma_f32_16x16x32_bf16(
                af[mi], bk[ni], (f32x4){0.f,0.f,0.f,0.f}, 0, 0, 0);
#pragma unroll
            for (int v = 0; v < 4; ++v) {
                int row = wr*64 + mi*16 + fq*4 + v;
                int col = wc*64 + ni*16 + fr;
                float a = 0.f;
                if (j0 + col <= i0 + row) {
                    float s = s4[v];
                    a = 1.f / (1.f + expf(-(s*s + B_SCALAR)));
                }
                int byte = (row * 256 + col * 2) ^ ((row & 7) << 4);
                *(unsigned short*)((char*)Ps + byte) = f2b(a);
            }
        }
    __syncthreads();

    f32x4 yacc[2][2];
#pragma unroll
    for (int mi = 0; mi < 2; ++mi)
#pragma unroll
        for (int nf = 0; nf < 2; ++nf) yacc[mi][nf] = (f32x4){0.f,0.f,0.f,0.f};
#pragma unroll
    for (int ks = 0; ks < 4; ++ks) {
        bf16x8 pa[2], eb[2];
#pragma unroll
        for (int mi = 0; mi < 2; ++mi) {
            int row = wid*32 + mi*16 + fr;
            int byte = (row * 256 + ks * 64 + fq * 16) ^ ((row & 7) << 4);
            pa[mi] = *(const bf16x8*)((const char*)Ps + byte);
        }
#pragma unroll
        for (int nf = 0; nf < 2; ++nf) {
            int rrow = nf*16 + fr;
            int byte = (rrow * 256 + ks * 64 + fq * 16) ^ ((rrow & 7) << 4);
            eb[nf] = *(const bf16x8*)((const char*)Es + byte);
        }
#pragma unroll
        for (int mi = 0; mi < 2; ++mi)
#pragma unroll
            for (int nf = 0; nf < 2; ++nf)
                yacc[mi][nf] = __builtin_amdgcn_mfma_f32_16x16x32_bf16(
                    pa[mi], eb[nf], yacc[mi][nf], 0, 0, 0);
    }
    float* pout = partial + ((size_t)(it*16 + jc) * 128) * 32;
#pragma unroll
    for (int mi = 0; mi < 2; ++mi)
#pragma unroll
        for (int nf = 0; nf < 2; ++nf)
#pragma unroll
            for (int v = 0; v < 4; ++v) {
                int row = wid*32 + mi*16 + fq*4 + v;
                int col = nf*16 + fr;
                pout[row*32 + col] = yacc[mi][nf][v];
            }
}

__global__ __launch_bounds__(256) void seed_finish(const float* __restrict__ partial,
                                                   const float* __restrict__ ms,
                                                   float* __restrict__ lr)
{
    int idx = blockIdx.x * 256 + threadIdx.x;
    int i = idx >> 5, r = idx & 31;
    int it = i >> 7, row = i & 127;
    float y = 0.f;
    for (int jjc = 0; jjc <= it; ++jjc)
        y += partial[(((size_t)(it*16 + jjc) * 128) + row) * 32 + r];
    float m = ms[idx];
    lr[idx] = logf(fmaxf(y * expf(-m), 1e-30f)) + m;
}

// ---------------------------------------------------------------------------
// H0 = Lr @ up_w.  grid T, block 256, K=32
// ---------------------------------------------------------------------------
__global__ __launch_bounds__(256) void up_proj(const float* __restrict__ lr,
                                               const float* __restrict__ up,
                                               float* __restrict__ h0)
{
    __shared__ float ls[32];
    int t = blockIdx.x, tid = threadIdx.x;
    if (tid < 32) ls[tid] = lr[t*32 + tid];
    __syncthreads();
    for (int c = tid; c < 768; c += 256) {
        float acc = 0.f;
#pragma unroll
        for (int rr = 0; rr < 32; ++rr) acc = fmaf(ls[rr], up[rr*768 + c], acc);
        h0[t*768 + c] = acc;
    }
}

// ---------------------------------------------------------------------------
// Per-(t,h) L2-normalized Q,K -> bf16. grid T, block 768
// ---------------------------------------------------------------------------
__global__ void head_norms_write(const float* __restrict__ qkv,
                                 unsigned short* __restrict__ qhatb,
                                 unsigned short* __restrict__ khatb)
{
    int t = blockIdx.x, tid = threadIdx.x;
    int h = tid >> 6, d = tid & 63;
    float q = qkv[t*2304 + h*64 + d];
    float k = qkv[t*2304 + 768 + h*64 + d];
    float sq = q*q, sk = k*k;
#pragma unroll
    for (int off = 32; off; off >>= 1) { sq += __shfl_xor(sq, off); sk += __shfl_xor(sk, off); }
    float iq = 1.f / fmaxf(sqrtf(sq), 1e-12f);
    float ik = 1.f / fmaxf(sqrtf(sk), 1e-12f);
    qhatb[(size_t)t*768 + h*64 + d] = f2b(q * iq);
    khatb[(size_t)t*768 + h*64 + d] = f2b(k * ik);
}

// ---------------------------------------------------------------------------
// Sliding past-window (129) max of V -> mnear fp32; exp(V-m) -> vexptb bf16
// TRANSPOSED [c][t]. grid (C/64, T/64)
// ---------------------------------------------------------------------------
__global__ __launch_bounds__(256) void slide_max(const float* __restrict__ qkv,
                                                 float* __restrict__ mnear,
                                                 unsigned short* __restrict__ vexptb)
{
    __shared__ float vs[192][64];
    int c0 = blockIdx.x * 64, t0 = blockIdx.y * 64;
    int tid = threadIdx.x;
#pragma unroll
    for (int s = 0; s < 12; ++s) {
        int idx = tid + s * 256;
        int rr = idx >> 4, c4 = (idx & 15) * 4;
        int t = t0 - 128 + rr;
        float4 v4;
        if (t < 0) v4 = make_float4(-INFINITY, -INFINITY, -INFINITY, -INFINITY);
        else       v4 = *(const float4*)&qkv[t*2304 + 1536 + c0 + c4];
        *(float4*)&vs[rr][c4] = v4;
    }
    __syncthreads();
    int c = tid & 63, tg = tid >> 6;
    for (int u = 0; u < 16; ++u) {
        int tl = tg * 16 + u;
        float m = -INFINITY;
        for (int s = 0; s < 129; ++s) m = fmaxf(m, vs[tl + s][c]);
        float v = vs[tl + 128][c];
        int t = t0 + tl;
        mnear[(size_t)t*768 + c0 + c] = m;
        vexptb[(size_t)(c0 + c) * 2048 + t] = f2b(expf(v - m));
    }
}

// ---------------------------------------------------------------------------
// Fused near-field (full MFMA): QK^T -> masked sigmoid -> P bf16 (XOR-swz LDS,
// reusing K buffer) -> PV MFMA vs transposed bf16 exp(V-m) -> log+m -> gate.
// grid (32 i-tiles of 64, 12 heads), block 256 (4 waves). LDS 56 KB.
// ---------------------------------------------------------------------------
__global__ __launch_bounds__(256) void near_fused(
    const unsigned short* __restrict__ qhatb, const unsigned short* __restrict__ khatb,
    const unsigned short* __restrict__ vexptb, const float* __restrict__ mnear,
    const float* __restrict__ gu, const float* __restrict__ gb,
    float* __restrict__ hn)
{
    __shared__ unsigned short Qs[64*64];     // 8 KB
    __shared__ unsigned short KPs[192*64];   // 24 KB: Khat, then P[64][192]
    __shared__ unsigned short Vst[64*192];   // 24 KB: Vexp^T [d][jl]
    const int it = blockIdx.x, hh = blockIdx.y;
    const int i0 = it * 64;
    const int tid = threadIdx.x, lane = tid & 63, wid = tid >> 6;
    const int fr = lane & 15, fq = lane >> 4;

    // ---- stage Qhat [64][64]: 512 chunks
#pragma unroll
    for (int i = 0; i < 2; ++i) {
        int cb = i * 256 + wid * 64, c = cb + lane;
        int r = c >> 3, col = ((c & 7) ^ (r & 7)) * 8;
        gload16(qhatb + (size_t)(i0 + r) * 768 + hh*64 + col, &Qs[cb * 8]);
    }
    // ---- stage Khat [192][64]: 1536 chunks, rows j = i0-128+r clamped
#pragma unroll
    for (int i = 0; i < 6; ++i) {
        int cb = i * 256 + wid * 64, c = cb + lane;
        int r = c >> 3, col = ((c & 7) ^ (r & 7)) * 8;
        int j = i0 - 128 + r; if (j < 0) j = 0;
        gload16(khatb + (size_t)j * 768 + hh*64 + col, &KPs[cb * 8]);
    }
    // ---- stage Vexp^T [64][192]: 1536 chunks, source chunk-permuted (rule #21)
#pragma unroll
    for (int i = 0; i < 6; ++i) {
        int cb = i * 256 + wid * 64, c = cb + lane;
        int d = c / 24, cc = c - d * 24;
        int ccp = (cc & 24) | ((cc & 7) ^ (d & 7));
        int t = i0 - 128 + ccp * 8; if (t < 0) t = 0;
        gload16(vexptb + (size_t)(hh*64 + d) * 2048 + t, &Vst[cb * 8]);
    }
    __syncthreads();

    // ---- S = Qhat Khat^T: M=64, N=192 (wave strip of 48), K=64
    f32x4 sacc[4][3];
#pragma unroll
    for (int mi = 0; mi < 4; ++mi)
#pragma unroll
        for (int ni = 0; ni < 3; ++ni) sacc[mi][ni] = (f32x4){0.f,0.f,0.f,0.f};
#pragma unroll
    for (int kt = 0; kt < 2; ++kt) {
        int kk = kt * 32;
        bf16x8 qa[4], kb[3];
#pragma unroll
        for (int mi = 0; mi < 4; ++mi)
            qa[mi] = frag128(Qs, mi*16 + fr, kk + fq*8);
#pragma unroll
        for (int ni = 0; ni < 3; ++ni)
            kb[ni] = frag128(KPs, wid*48 + ni*16 + fr, kk + fq*8);
#pragma unroll
        for (int mi = 0; mi < 4; ++mi)
#pragma unroll
            for (int ni = 0; ni < 3; ++ni)
                sacc[mi][ni] = __builtin_amdgcn_mfma_f32_16x16x32_bf16(
                    qa[mi], kb[ni], sacc[mi][ni], 0, 0, 0);
    }
    __syncthreads();   // all Khat reads done before P overwrites the buffer

    // ---- masked sigmoid -> P[64][192] bf16 (overwrite KPs)
#pragma unroll
    for (int mi = 0; mi < 4; ++mi)
#pragma unroll
        for (int ni = 0; ni < 3; ++ni)
#pragma unroll
            for (int v = 0; v < 4; ++v) {
                int il = mi*16 + fq*4 + v;
                int jl = wid*48 + ni*16 + fr;
                float s = sacc[mi][ni][v];
                float a = 0.f;
                if (jl >= il && jl <= il + 128 && (i0 - 128 + jl) >= 0)
                    a = 1.f / (1.f + expf(-(s*s*INV_TAU + B_SCALAR)));
                int byte = (il * 384 + jl * 2) ^ ((il & 7) << 4);
                *(unsigned short*)((char*)KPs + byte) = f2b(a);
            }
    __syncthreads();

    // ---- Y = P @ Vexp: M=64 (wave strip of 16), N=64, K=192
    f32x4 yacc[4];
#pragma unroll
    for (int nf = 0; nf < 4; ++nf) yacc[nf] = (f32x4){0.f,0.f,0.f,0.f};
#pragma unroll
    for (int ks = 0; ks < 6; ++ks) {
        int kk = ks * 32;
        bf16x8 pa = frag384(KPs, wid*16 + fr, kk + fq*8);
        bf16x8 vb[4];
#pragma unroll
        for (int nf = 0; nf < 4; ++nf)
            vb[nf] = frag384(Vst, nf*16 + fr, kk + fq*8);
#pragma unroll
        for (int nf = 0; nf < 4; ++nf)
            yacc[nf] = __builtin_amdgcn_mfma_f32_16x16x32_bf16(pa, vb[nf], yacc[nf], 0, 0, 0);
    }

    // ---- epilogue: log + m, head gate, write
    float hv[4][4];
    float sp[4] = {0.f, 0.f, 0.f, 0.f};
#pragma unroll
    for (int nf = 0; nf < 4; ++nf) {
        int d = nf*16 + fr;
        float guv = gu[hh*64 + d];
#pragma unroll
        for (int v = 0; v < 4; ++v) {
            int row = wid*16 + fq*4 + v;
            float y = yacc[nf][v];
            float h = logf(fmaxf(y, 1e-30f)) + mnear[(size_t)(i0 + row)*768 + hh*64 + d];
            hv[nf][v] = h;
            sp[v] = fmaf(h, guv, sp[v]);
        }
    }
#pragma unroll
    for (int off = 1; off < 16; off <<= 1) {
#pragma unroll
        for (int v = 0; v < 4; ++v) sp[v] += __shfl_xor(sp[v], off);
    }
    float gbh = gb[hh];
#pragma unroll
    for (int v = 0; v < 4; ++v) sp[v] = 1.f / (1.f + expf(-(sp[v] + gbh)));
#pragma unroll
    for (int nf = 0; nf < 4; ++nf)
#pragma unroll
        for (int v = 0; v < 4; ++v) {
            int row = wid*16 + fq*4 + v;
            int d = nf*16 + fr;
            hn[(size_t)(i0 + row)*768 + hh*64 + d] = hv[nf][v] * sp[v];
        }
}

// ---------------------------------------------------------------------------
extern "C" void kernel_launch(void* const* d_in, const int* in_sizes, int n_in,
                              void* d_out, int out_size, void* d_ws, size_t ws_size,
                              hipStream_t stream)
{
    const float* x  = (const float*)d_in[0];
    const float* wq = (const float*)d_in[1];  const float* bq = (const float*)d_in[2];
    const float* wk = (const float*)d_in[3];  const float* bk = (const float*)d_in[4];
    const float* wv = (const float*)d_in[5];  const float* bv = (const float*)d_in[6];
    const float* wo = (const float*)d_in[7];  const float* bo = (const float*)d_in[8];
    const float* pq = (const float*)d_in[9];  const float* pk = (const float*)d_in[10];
    const float* pv = (const float*)d_in[11];
    const float* up = (const float*)d_in[12];
    const float* gu = (const float*)d_in[13]; const float* gb = (const float*)d_in[14];
    const float* wz = (const float*)d_in[15]; const float* bz = (const float*)d_in[16];
    float* out = (float*)d_out;

    float* w = (float*)d_ws;
    float* qkv  = w; w += 2048*2304;
    float* vr   = w; w += 2048*32;
    float* ms   = w; w += 2048*32;
    float* lr   = w; w += 2048*32;
    float* h0   = w; w += 2048*768;
    float* mnear= w; w += 2048*768;
    float* hn   = w; w += 2048*768;          // Htilde after near_fused
    float* partial = w; w += 16*16*128*32;   // seed partials
    float* pgemm = w; w += 4*2048*768;       // split-K partials (Wz 4 / Wo 2)
    float* plr   = w; w += 4*3*2048*32;      // lowrank split-K partials
    float* bqkv = w; w += 2304;
    unsigned short* xb     = (unsigned short*)w; w += 2048*768/2;
    unsigned short* qkvb   = (unsigned short*)w; w += 2048*2304/2;
    unsigned short* wqkvT  = (unsigned short*)w; w += 2304*768/2;
    unsigned short* wzT    = (unsigned short*)w; w += 768*3072/2;
    unsigned short* woT    = (unsigned short*)w; w += 768*768/2;
    unsigned short* pT     = (unsigned short*)w; w += 3*32*768/2;
    unsigned short* h0b    = (unsigned short*)w; w += 2048*768/2;
    unsigned short* htlb   = (unsigned short*)w; w += 2048*768/2;
    unsigned short* prodb  = (unsigned short*)w; w += 2048*768/2;
    unsigned short* houtb  = (unsigned short*)w; w += 2048*768/2;
    unsigned short* qrb    = (unsigned short*)w; w += 2048*32/2;
    unsigned short* krb    = (unsigned short*)w; w += 2048*32/2;
    unsigned short* evtb   = (unsigned short*)w; w += 32*2048/2;
    unsigned short* qhatb  = (unsigned short*)w; w += 2048*768/2;
    unsigned short* khatb  = (unsigned short*)w; w += 2048*768/2;
    unsigned short* vexptb = (unsigned short*)w; w += 768*2048/2;

    // ---- prep
    cvt_bf16<<<1536, 256, 0, stream>>>(x, xb, 2048*768/4);
    transpose_w<<<dim3(24,24), 256, 0, stream>>>(wq, wqkvT,            768, 768);
    transpose_w<<<dim3(24,24), 256, 0, stream>>>(wk, wqkvT + 768*768,  768, 768);
    transpose_w<<<dim3(24,24), 256, 0, stream>>>(wv, wqkvT + 1536*768, 768, 768);
    transpose_w<<<dim3(96,24), 256, 0, stream>>>(wz, wzT, 3072, 768);
    transpose_w<<<dim3(24,24), 256, 0, stream>>>(wo, woT, 768, 768);
    transpose_w<<<dim3(24,1),  256, 0, stream>>>(pq, pT,            768, 32);
    transpose_w<<<dim3(24,1),  256, 0, stream>>>(pk, pT + 32*768,   768, 32);
    transpose_w<<<dim3(24,1),  256, 0, stream>>>(pv, pT + 2*32*768, 768, 32);
    concat_bias<<<9, 256, 0, stream>>>(bq, bk, bv, bqkv);

    // 0) QKV projections (fp32 + bf16 copy)
    gemm_mfma<0,1><<<dim3(18,16,1), 256, 0, stream>>>(xb, nullptr, nullptr, nullptr,
        wqkvT, bqkv, qkv, qkvb, nullptr, 768, 2304);

    // 1) low-rank path
    lowrank_mfma<<<dim3(16,3,4), 256, 0, stream>>>(qkvb, pT, plr);
    lowrank_finish<<<768, 256, 0, stream>>>(plr, qrb, krb, vr, evtb);
    cummax_vr<<<32, 256, 0, stream>>>(vr, ms);
    seed_mfma<<<dim3(16,16), 256, 0, stream>>>(qrb, krb, evtb, partial);
    seed_finish<<<256, 256, 0, stream>>>(partial, ms, lr);
    up_proj<<<2048, 256, 0, stream>>>(lr, up, h0);

    // 2) near-field path (full MFMA)
    head_norms_write<<<2048, 768, 0, stream>>>(qkv, qhatb, khatb);
    slide_max<<<dim3(12,32), 256, 0, stream>>>(qkv, mnear, vexptb);
    near_fused<<<dim3(32,12), 256, 0, stream>>>(qhatb, khatb, vexptb, mnear, gu, gb, hn);

    // 3) GRU blend (split-K=4) + output projection (split-K=2)
    build_gru_inputs<<<1536, 256, 0, stream>>>(h0, hn, h0b, htlb, prodb, 2048*768/4);
    gemm_mfma<1,4><<<dim3(6,16,4), 256, 0, stream>>>(xb, h0b, htlb, prodb,
        wzT, nullptr, nullptr, nullptr, pgemm, 3072, 768);
    wz_combine<<<1536, 256, 0, stream>>>(pgemm, bz, h0, hn, houtb);
    gemm_mfma<2,2><<<dim3(6,16,2), 256, 0, stream>>>(houtb, nullptr, nullptr, nullptr,
        woT, nullptr, nullptr, nullptr, pgemm, 768, 768);
    wo_combine<<<1536, 256, 0, stream>>>(pgemm, bo, out);
}

// Round 9
// 148.216 us; speedup vs baseline: 6.6802x; 1.2206x over previous
//
#include <hip/hip_runtime.h>
#include <math.h>

// Problem constants (fixed: B=1, T=2048, C=768, H=12, D=64, R=32, K0=128)
static constexpr float B_SCALAR    = -7.6246189861593985f;   // -log(2048)
static constexpr float INV_TAU     = 2.8571428571428571f;    // 1/0.35
static constexpr float INV_SQRT_R  = 0.17677669529663687f;   // 1/sqrt(32)

typedef __attribute__((ext_vector_type(8))) short bf16x8;
typedef __attribute__((ext_vector_type(4))) float f32x4;

__device__ __forceinline__ unsigned short f2b(float f) {
    union { float f; unsigned int u; } v; v.f = f;
    unsigned int r = v.u + 0x7fffu + ((v.u >> 16) & 1u);
    return (unsigned short)(r >> 16);
}

typedef const __attribute__((address_space(1))) unsigned int* gp1_t;
typedef __attribute__((address_space(3))) unsigned int* lp3_t;
__device__ __forceinline__ void gload16(const unsigned short* g, unsigned short* l) {
    __builtin_amdgcn_global_load_lds((gp1_t)g, (lp3_t)l, 16, 0, 0);
}

// XOR-swizzled bf16x8 read from a row-major LDS tile with 128B rows
__device__ __forceinline__ bf16x8 frag128(const unsigned short* base, int row, int elem) {
    int byte = (row * 128 + elem * 2) ^ ((row & 7) << 4);
    return *(const bf16x8*)((const char*)base + byte);
}
// same for 384B rows (192 bf16 per row)
__device__ __forceinline__ bf16x8 frag384(const unsigned short* base, int row, int elem) {
    int byte = (row * 384 + elem * 2) ^ ((row & 7) << 4);
    return *(const bf16x8*)((const char*)base + byte);
}

// ---------------------------------------------------------------------------
// bf16 MFMA GEMM, 128x128 tile, BK=64, double-buffered 2-phase prefetch,
// XOR-swizzled LDS. MODE 0: QKV (KZ=1, fp32 out + bf16 copy)
// MODE 1: Wz piecewise A (split-K)  MODE 2: Wo (split-K)
// ---------------------------------------------------------------------------
template<int MODE, int KZ>
__global__ __launch_bounds__(256) void gemm_mfma(
    const unsigned short* __restrict__ A0, const unsigned short* __restrict__ A1,
    const unsigned short* __restrict__ A2, const unsigned short* __restrict__ A3,
    const unsigned short* __restrict__ Bt, const float* __restrict__ bias,
    float* __restrict__ outf, unsigned short* __restrict__ outb,
    float* __restrict__ pbuf, int K, int ldo)
{
    __shared__ unsigned short As[2][128*64];
    __shared__ unsigned short Bs[2][128*64];
    const int tid = threadIdx.x;
    const int lane = tid & 63, wid = tid >> 6;
    const int wr = wid >> 1, wc = wid & 1;
    const int fr = lane & 15, fq = lane >> 4;
    const int n0 = blockIdx.x * 128, m0 = blockIdx.y * 128;
    const int kz = blockIdx.z;
    const int kslice = K / KZ;
    const int kbase = kz * kslice;
    const int nt = kslice / 64;

    f32x4 acc[4][4];
#pragma unroll
    for (int mi = 0; mi < 4; ++mi)
#pragma unroll
        for (int ni = 0; ni < 4; ++ni) acc[mi][ni] = (f32x4){0.f, 0.f, 0.f, 0.f};

    auto stage = [&](int buf, int k0) {
        const unsigned short* Ap;
        int k0l, ldA;
        if (MODE == 1) {
            int p = k0 / 768;
            Ap = (p == 0) ? A0 : (p == 1) ? A1 : (p == 2) ? A2 : A3;
            k0l = k0 - p * 768; ldA = 768;
        } else { Ap = A0; k0l = k0; ldA = K; }
#pragma unroll
        for (int i = 0; i < 4; ++i) {
            int cb = i * 256 + wid * 64;
            int c  = cb + lane;
            int r = c >> 3;
            int col = ((c & 7) ^ (r & 7)) * 8;
            gload16(Ap + (size_t)(m0 + r) * ldA + k0l + col, &As[buf][cb * 8]);
            gload16(Bt + (size_t)(n0 + r) * K   + k0  + col, &Bs[buf][cb * 8]);
        }
    };

    stage(0, kbase);
    asm volatile("s_waitcnt vmcnt(0)" ::: "memory");
    __builtin_amdgcn_s_barrier();
    __builtin_amdgcn_sched_barrier(0);

    int cur = 0;
    for (int t = 0; t < nt; ++t) {
        if (t + 1 < nt) stage(cur ^ 1, kbase + (t + 1) * 64);
#pragma unroll
        for (int kk = 0; kk < 64; kk += 32) {
            bf16x8 af[4], bfr[4];
#pragma unroll
            for (int mi = 0; mi < 4; ++mi)
                af[mi] = frag128(As[cur], wr*64 + mi*16 + fr, kk + fq*8);
#pragma unroll
            for (int ni = 0; ni < 4; ++ni)
                bfr[ni] = frag128(Bs[cur], wc*64 + ni*16 + fr, kk + fq*8);
#pragma unroll
            for (int mi = 0; mi < 4; ++mi)
#pragma unroll
                for (int ni = 0; ni < 4; ++ni)
                    acc[mi][ni] = __builtin_amdgcn_mfma_f32_16x16x32_bf16(
                        af[mi], bfr[ni], acc[mi][ni], 0, 0, 0);
        }
        asm volatile("s_waitcnt vmcnt(0)" ::: "memory");
        __builtin_amdgcn_s_barrier();
        __builtin_amdgcn_sched_barrier(0);
        cur ^= 1;
    }
#pragma unroll
    for (int mi = 0; mi < 4; ++mi)
#pragma unroll
        for (int ni = 0; ni < 4; ++ni)
#pragma unroll
            for (int v = 0; v < 4; ++v) {
                int m = m0 + wr*64 + mi*16 + fq*4 + v;
                int n = n0 + wc*64 + ni*16 + fr;
                float val = acc[mi][ni][v];
                if (KZ > 1) {
                    pbuf[((size_t)kz * 2048 + m) * 768 + n] = val;
                } else {
                    float vv = val + bias[n];
                    outf[(size_t)m * ldo + n] = vv;
                    if (MODE == 0) outb[(size_t)m * ldo + n] = f2b(vv);
                }
            }
}

// ---------------------------------------------------------------------------
// Split-K combines
// ---------------------------------------------------------------------------
__global__ __launch_bounds__(256) void wz_combine(
    const float* __restrict__ pbuf, const float* __restrict__ bz,
    const float* __restrict__ h0, const float* __restrict__ htl,
    unsigned short* __restrict__ outb)
{
    int i = blockIdx.x * 256 + threadIdx.x;
    if (i >= 2048*768/4) return;
    float4 s = *(const float4*)&pbuf[i*4];
    float4 p1 = *(const float4*)&pbuf[1536*1024 + i*4];
    float4 p2 = *(const float4*)&pbuf[2*1536*1024 + i*4];
    float4 p3 = *(const float4*)&pbuf[3*1536*1024 + i*4];
    s.x += p1.x + p2.x + p3.x; s.y += p1.y + p2.y + p3.y;
    s.z += p1.z + p2.z + p3.z; s.w += p1.w + p2.w + p3.w;
    float4 b = *(const float4*)&bz[(i % 192) * 4];
    float4 a = *(const float4*)&h0[i*4];
    float4 t = *(const float4*)&htl[i*4];
    float z0 = 1.f/(1.f+expf(-(s.x+b.x))), z1 = 1.f/(1.f+expf(-(s.y+b.y)));
    float z2 = 1.f/(1.f+expf(-(s.z+b.z))), z3 = 1.f/(1.f+expf(-(s.w+b.w)));
    outb[i*4+0] = f2b((1.f-z0)*a.x + z0*t.x);
    outb[i*4+1] = f2b((1.f-z1)*a.y + z1*t.y);
    outb[i*4+2] = f2b((1.f-z2)*a.z + z2*t.z);
    outb[i*4+3] = f2b((1.f-z3)*a.w + z3*t.w);
}

__global__ __launch_bounds__(256) void wo_combine(
    const float* __restrict__ pbuf, const float* __restrict__ bo,
    float* __restrict__ out)
{
    int i = blockIdx.x * 256 + threadIdx.x;
    if (i >= 2048*768/4) return;
    float4 s = *(const float4*)&pbuf[i*4];
    float4 p1 = *(const float4*)&pbuf[1536*1024 + i*4];
    float4 b = *(const float4*)&bo[(i % 192) * 4];
    float4 o;
    o.x = s.x + p1.x + b.x; o.y = s.y + p1.y + b.y;
    o.z = s.z + p1.z + b.z; o.w = s.w + p1.w + b.w;
    *(float4*)&out[i*4] = o;
}

// ---------------------------------------------------------------------------
// Mega-prep: x->bf16 cast, all weight transposes (fp32->bf16), bias concat.
// One dispatch, 6225 blocks, blockIdx -> task map.
// ---------------------------------------------------------------------------
__global__ __launch_bounds__(256) void prep_all(
    const float* __restrict__ x, unsigned short* __restrict__ xb,
    const float* __restrict__ wq, const float* __restrict__ wk,
    const float* __restrict__ wv, unsigned short* __restrict__ wqkvT,
    const float* __restrict__ wz, unsigned short* __restrict__ wzT,
    const float* __restrict__ wo, unsigned short* __restrict__ woT,
    const float* __restrict__ pq, const float* __restrict__ pk,
    const float* __restrict__ pv, unsigned short* __restrict__ pT,
    const float* __restrict__ bq, const float* __restrict__ bk,
    const float* __restrict__ bv, float* __restrict__ bqkv)
{
    __shared__ float tile[32][33];
    int b = blockIdx.x;
    if (b < 1536) {                       // task: cvt x -> xb
        int i = b * 256 + threadIdx.x;
        float4 v = *(const float4*)&x[i * 4];
        xb[i*4+0] = f2b(v.x); xb[i*4+1] = f2b(v.y);
        xb[i*4+2] = f2b(v.z); xb[i*4+3] = f2b(v.w);
        return;
    }
    b -= 1536;
    const float* src; unsigned short* dst; int K, N, tb;
    if (b < 1728) {                       // wq/wk/wv transpose (576 each)
        int sel = b / 576;
        src = (sel == 0) ? wq : (sel == 1) ? wk : wv;
        dst = wqkvT + (size_t)sel * 768 * 768;
        K = 768; N = 768; tb = b - sel * 576;
    } else if (b < 4032) {                // wz (2304)
        src = wz; dst = wzT; K = 3072; N = 768; tb = b - 1728;
    } else if (b < 4608) {                // wo (576)
        src = wo; dst = woT; K = 768; N = 768; tb = b - 4032;
    } else if (b < 4680) {                // pq/pk/pv (24 each)
        int sel = (b - 4608) / 24;
        src = (sel == 0) ? pq : (sel == 1) ? pk : pv;
        dst = pT + (size_t)sel * 32 * 768;
        K = 768; N = 32; tb = (b - 4608) % 24;
    } else {                              // concat_bias (9)
        int n = (b - 4680) * 256 + threadIdx.x;
        if (n < 2304)
            bqkv[n] = (n < 768) ? bq[n] : (n < 1536) ? bk[n - 768] : bv[n - 1536];
        return;
    }
    int kt = K / 32;
    int kb = (tb % kt) * 32, nb = (tb / kt) * 32;
    int tx = threadIdx.x & 31, ty = threadIdx.x >> 5;
#pragma unroll
    for (int s = 0; s < 32; s += 8)
        tile[ty + s][tx] = src[(size_t)(kb + ty + s) * N + nb + tx];
    __syncthreads();
#pragma unroll
    for (int s = 0; s < 32; s += 8)
        dst[(size_t)(nb + ty + s) * K + kb + tx] = f2b(tile[tx][ty + s]);
}

// ---------------------------------------------------------------------------
// Low-rank projections via MFMA, split-K=4.
// grid (16 m-tiles, 3 sels, 4 kz). A = qkvb slice, B = pT[sel][32][768].
// ---------------------------------------------------------------------------
__global__ __launch_bounds__(256) void lowrank_mfma(
    const unsigned short* __restrict__ qkvb, const unsigned short* __restrict__ pT,
    float* __restrict__ pbuf)
{
    __shared__ unsigned short As[2][128*64];
    __shared__ unsigned short Bs[2][32*64];
    const int tid = threadIdx.x, lane = tid & 63, wid = tid >> 6;
    const int fr = lane & 15, fq = lane >> 4;
    const int m0 = blockIdx.x * 128;
    const int sel = blockIdx.y, kz = blockIdx.z;
    const int kbase = kz * 192;

    f32x4 acc[2][2];
#pragma unroll
    for (int mi = 0; mi < 2; ++mi)
#pragma unroll
        for (int ni = 0; ni < 2; ++ni) acc[mi][ni] = (f32x4){0.f,0.f,0.f,0.f};

    auto stage = [&](int buf, int k0) {
#pragma unroll
        for (int i = 0; i < 4; ++i) {     // A: 128x64 = 1024 chunks
            int cb = i * 256 + wid * 64, c = cb + lane;
            int r = c >> 3, col = ((c & 7) ^ (r & 7)) * 8;
            gload16(qkvb + (size_t)(m0 + r) * 2304 + sel*768 + k0 + col, &As[buf][cb * 8]);
        }
        {                                 // B: 32x64 = 256 chunks
            int cb = wid * 64, c = cb + lane;
            int r = c >> 3, col = ((c & 7) ^ (r & 7)) * 8;
            gload16(pT + (size_t)sel * 32*768 + (size_t)r * 768 + k0 + col, &Bs[buf][cb * 8]);
        }
    };

    stage(0, kbase);
    asm volatile("s_waitcnt vmcnt(0)" ::: "memory");
    __builtin_amdgcn_s_barrier();
    __builtin_amdgcn_sched_barrier(0);

    int cur = 0;
    for (int t = 0; t < 3; ++t) {
        if (t + 1 < 3) stage(cur ^ 1, kbase + (t + 1) * 64);
#pragma unroll
        for (int kk = 0; kk < 64; kk += 32) {
            bf16x8 a[2], b[2];
#pragma unroll
            for (int mi = 0; mi < 2; ++mi)
                a[mi] = frag128(As[cur], wid*32 + mi*16 + fr, kk + fq*8);
#pragma unroll
            for (int ni = 0; ni < 2; ++ni)
                b[ni] = frag128(Bs[cur], ni*16 + fr, kk + fq*8);
#pragma unroll
            for (int mi = 0; mi < 2; ++mi)
#pragma unroll
                for (int ni = 0; ni < 2; ++ni)
                    acc[mi][ni] = __builtin_amdgcn_mfma_f32_16x16x32_bf16(
                        a[mi], b[ni], acc[mi][ni], 0, 0, 0);
        }
        asm volatile("s_waitcnt vmcnt(0)" ::: "memory");
        __builtin_amdgcn_s_barrier();
        __builtin_amdgcn_sched_barrier(0);
        cur ^= 1;
    }
#pragma unroll
    for (int mi = 0; mi < 2; ++mi)
#pragma unroll
        for (int ni = 0; ni < 2; ++ni)
#pragma unroll
            for (int v = 0; v < 4; ++v) {
                int m = m0 + wid*32 + mi*16 + fq*4 + v;
                int n = ni*16 + fr;
                pbuf[((size_t)(kz*3 + sel) * 2048 + m) * 32 + n] = acc[mi][ni][v];
            }
}

__global__ __launch_bounds__(256) void lowrank_finish(
    const float* __restrict__ pbuf,
    unsigned short* __restrict__ qrb, unsigned short* __restrict__ krb,
    float* __restrict__ vr, unsigned short* __restrict__ evtb)
{
    int idx = blockIdx.x * 256 + threadIdx.x;        // 3*65536
    int sel = idx >> 16, rem = idx & 65535;
    float s = pbuf[(size_t)(0*3 + sel)*65536 + rem]
            + pbuf[(size_t)(1*3 + sel)*65536 + rem]
            + pbuf[(size_t)(2*3 + sel)*65536 + rem]
            + pbuf[(size_t)(3*3 + sel)*65536 + rem];
    if (sel == 0)      qrb[rem] = f2b(s * INV_SQRT_R);
    else if (sel == 1) krb[rem] = f2b(s);
    else {
        int t = rem >> 5, r = rem & 31;
        vr[rem] = s;
        evtb[(size_t)r * 2048 + t] = f2b(expf(s));
    }
}

// ---------------------------------------------------------------------------
// Inclusive cumulative max over time per feature r. grid R, block 256
// ---------------------------------------------------------------------------
__global__ __launch_bounds__(256) void cummax_vr(const float* __restrict__ vr,
                                                 float* __restrict__ ms)
{
    __shared__ float part[256];
    int r = blockIdx.x, tid = threadIdx.x;
    int t0 = tid * 8;
    float v[8];
    float run = -INFINITY;
#pragma unroll
    for (int e = 0; e < 8; ++e) { run = fmaxf(run, vr[(t0+e)*32 + r]); v[e] = run; }
    part[tid] = run;
    __syncthreads();
    for (int off = 1; off < 256; off <<= 1) {
        float other = (tid >= off) ? part[tid - off] : -INFINITY;
        __syncthreads();
        part[tid] = fmaxf(part[tid], other);
        __syncthreads();
    }
    float excl = (tid > 0) ? part[tid - 1] : -INFINITY;
#pragma unroll
    for (int e = 0; e < 8; ++e) ms[(t0+e)*32 + r] = fmaxf(v[e], excl);
}

// ---------------------------------------------------------------------------
// Seed attention, MFMA flash-style. grid (16 i-tiles, 16 j-chunks), jc<=it.
// ---------------------------------------------------------------------------
__global__ __launch_bounds__(256) void seed_mfma(
    const unsigned short* __restrict__ qrb, const unsigned short* __restrict__ krb,
    const unsigned short* __restrict__ evtb, float* __restrict__ partial)
{
    int it = blockIdx.x, jc = blockIdx.y;
    if (jc > it) return;
    const int i0 = it * 128, j0 = jc * 128;
    __shared__ unsigned short Qs[128*32];
    __shared__ unsigned short Ks[128*32];
    __shared__ unsigned short Es[32*128];
    __shared__ unsigned short Ps[128*128];
    const int tid = threadIdx.x, lane = tid & 63, wid = tid >> 6;
    const int fr = lane & 15, fq = lane >> 4;

#pragma unroll
    for (int s = 0; s < 2; ++s) {
        int cb = s * 256 + wid * 64;
        int c = cb + lane;
        int r = c >> 2, col = (c & 3) * 8;
        gload16(qrb + (size_t)(i0 + r) * 32 + col, &Qs[cb * 8]);
        gload16(krb + (size_t)(j0 + r) * 32 + col, &Ks[cb * 8]);
    }
#pragma unroll
    for (int s = 0; s < 2; ++s) {
        int c = s * 256 + tid;
        int rr = c >> 4, cc = c & 15;
        bf16x8 v = *(const bf16x8*)&evtb[(size_t)rr * 2048 + j0 + cc * 8];
        int byte = (rr * 256 + cc * 16) ^ ((rr & 7) << 4);
        *(bf16x8*)((char*)Es + byte) = v;
    }
    __syncthreads();

    const int wr = wid >> 1, wc = wid & 1;
    bf16x8 af[4], bk[4];
#pragma unroll
    for (int mi = 0; mi < 4; ++mi)
        af[mi] = *(const bf16x8*)&Qs[(wr*64 + mi*16 + fr)*32 + fq*8];
#pragma unroll
    for (int ni = 0; ni < 4; ++ni)
        bk[ni] = *(const bf16x8*)&Ks[(wc*64 + ni*16 + fr)*32 + fq*8];
#pragma unroll
    for (int mi = 0; mi < 4; ++mi)
#pragma unroll
        for (int ni = 0; ni < 4; ++ni) {
            f32x4 s4 = __builtin_amdgcn_mfma_f32_16x16x32_bf16(
                af[mi], bk[ni], (f32x4){0.f,0.f,0.f,0.f}, 0, 0, 0);
#pragma unroll
            for (int v = 0; v < 4; ++v) {
                int row = wr*64 + mi*16 + fq*4 + v;
                int col = wc*64 + ni*16 + fr;
                float a = 0.f;
                if (j0 + col <= i0 + row) {
                    float s = s4[v];
                    a = 1.f / (1.f + expf(-(s*s + B_SCALAR)));
                }
                int byte = (row * 256 + col * 2) ^ ((row & 7) << 4);
                *(unsigned short*)((char*)Ps + byte) = f2b(a);
            }
        }
    __syncthreads();

    f32x4 yacc[2][2];
#pragma unroll
    for (int mi = 0; mi < 2; ++mi)
#pragma unroll
        for (int nf = 0; nf < 2; ++nf) yacc[mi][nf] = (f32x4){0.f,0.f,0.f,0.f};
#pragma unroll
    for (int ks = 0; ks < 4; ++ks) {
        bf16x8 pa[2], eb[2];
#pragma unroll
        for (int mi = 0; mi < 2; ++mi) {
            int row = wid*32 + mi*16 + fr;
            int byte = (row * 256 + ks * 64 + fq * 16) ^ ((row & 7) << 4);
            pa[mi] = *(const bf16x8*)((const char*)Ps + byte);
        }
#pragma unroll
        for (int nf = 0; nf < 2; ++nf) {
            int rrow = nf*16 + fr;
            int byte = (rrow * 256 + ks * 64 + fq * 16) ^ ((rrow & 7) << 4);
            eb[nf] = *(const bf16x8*)((const char*)Es + byte);
        }
#pragma unroll
        for (int mi = 0; mi < 2; ++mi)
#pragma unroll
            for (int nf = 0; nf < 2; ++nf)
                yacc[mi][nf] = __builtin_amdgcn_mfma_f32_16x16x32_bf16(
                    pa[mi], eb[nf], yacc[mi][nf], 0, 0, 0);
    }
    float* pout = partial + ((size_t)(it*16 + jc) * 128) * 32;
#pragma unroll
    for (int mi = 0; mi < 2; ++mi)
#pragma unroll
        for (int nf = 0; nf < 2; ++nf)
#pragma unroll
            for (int v = 0; v < 4; ++v) {
                int row = wid*32 + mi*16 + fq*4 + v;
                int col = nf*16 + fr;
                pout[row*32 + col] = yacc[mi][nf][v];
            }
}

// ---------------------------------------------------------------------------
// Fused: reduce seed partials + LASER log + H0 = Lr @ up_w (+ bf16 copy).
// grid T, block 256.
// ---------------------------------------------------------------------------
__global__ __launch_bounds__(256) void seed_up(
    const float* __restrict__ partial, const float* __restrict__ ms,
    const float* __restrict__ up, float* __restrict__ h0,
    unsigned short* __restrict__ h0b)
{
    __shared__ float ls[32];
    int t = blockIdx.x, tid = threadIdx.x;
    if (tid < 32) {
        int r = tid;
        int it = t >> 7, row = t & 127;
        float y = 0.f;
        for (int jjc = 0; jjc <= it; ++jjc)
            y += partial[(((size_t)(it*16 + jjc) * 128) + row) * 32 + r];
        float m = ms[t*32 + r];
        ls[r] = logf(fmaxf(y * expf(-m), 1e-30f)) + m;
    }
    __syncthreads();
    for (int c = tid; c < 768; c += 256) {
        float acc = 0.f;
#pragma unroll
        for (int rr = 0; rr < 32; ++rr) acc = fmaf(ls[rr], up[rr*768 + c], acc);
        h0[(size_t)t*768 + c] = acc;
        h0b[(size_t)t*768 + c] = f2b(acc);
    }
}

// ---------------------------------------------------------------------------
// Per-(t,h) L2-normalized Q,K -> bf16. grid T, block 768
// ---------------------------------------------------------------------------
__global__ void head_norms_write(const float* __restrict__ qkv,
                                 unsigned short* __restrict__ qhatb,
                                 unsigned short* __restrict__ khatb)
{
    int t = blockIdx.x, tid = threadIdx.x;
    int h = tid >> 6, d = tid & 63;
    float q = qkv[t*2304 + h*64 + d];
    float k = qkv[t*2304 + 768 + h*64 + d];
    float sq = q*q, sk = k*k;
#pragma unroll
    for (int off = 32; off; off >>= 1) { sq += __shfl_xor(sq, off); sk += __shfl_xor(sk, off); }
    float iq = 1.f / fmaxf(sqrtf(sq), 1e-12f);
    float ik = 1.f / fmaxf(sqrtf(sk), 1e-12f);
    qhatb[(size_t)t*768 + h*64 + d] = f2b(q * iq);
    khatb[(size_t)t*768 + h*64 + d] = f2b(k * ik);
}

// ---------------------------------------------------------------------------
// Sliding past-window (129) max of V -> mnear fp32; exp(V-m) -> vexptb bf16
// TRANSPOSED [c][t]. grid (C/64, T/64). Exact window decomposition:
// 16 overlapping windows/thread share a 114-row core + suffix/prefix scans.
// ---------------------------------------------------------------------------
__global__ __launch_bounds__(256) void slide_max(const float* __restrict__ qkv,
                                                 float* __restrict__ mnear,
                                                 unsigned short* __restrict__ vexptb)
{
    __shared__ float vs[192][64];
    int c0 = blockIdx.x * 64, t0 = blockIdx.y * 64;
    int tid = threadIdx.x;
#pragma unroll
    for (int s = 0; s < 12; ++s) {
        int idx = tid + s * 256;
        int rr = idx >> 4, c4 = (idx & 15) * 4;
        int t = t0 - 128 + rr;
        float4 v4;
        if (t < 0) v4 = make_float4(-INFINITY, -INFINITY, -INFINITY, -INFINITY);
        else       v4 = *(const float4*)&qkv[t*2304 + 1536 + c0 + c4];
        *(float4*)&vs[rr][c4] = v4;
    }
    __syncthreads();
    int c = tid & 63, tg = tid >> 6;
    const int TG = tg * 16;
    // core = max over rows [TG+15, TG+128] (common to all 16 windows)
    float core = -INFINITY;
    for (int s = TG + 15; s <= TG + 128; ++s) core = fmaxf(core, vs[s][c]);
    // head(u) = max rows [TG+u, TG+14]; tail(u) = max rows [TG+129, TG+128+u]
    float head[16], tail[16];
    head[15] = -INFINITY;
    float hs = -INFINITY;
#pragma unroll
    for (int u = 14; u >= 0; --u) { hs = fmaxf(hs, vs[TG + u][c]); head[u] = hs; }
    tail[0] = -INFINITY;
    float ts = -INFINITY;
#pragma unroll
    for (int u = 1; u <= 15; ++u) { ts = fmaxf(ts, vs[TG + 128 + u][c]); tail[u] = ts; }
#pragma unroll
    for (int u = 0; u < 16; ++u) {
        int tl = TG + u;
        float m = fmaxf(fmaxf(core, head[u]), tail[u]);
        float v = vs[tl + 128][c];
        int t = t0 + tl;
        mnear[(size_t)t*768 + c0 + c] = m;
        vexptb[(size_t)(c0 + c) * 2048 + t] = f2b(expf(v - m));
    }
}

// ---------------------------------------------------------------------------
// Fused near-field (full MFMA): QK^T -> masked sigmoid -> P bf16 (XOR-swz LDS,
// reusing K buffer) -> PV MFMA vs transposed bf16 exp(V-m) -> log+m -> gate.
// Epilogue also emits Htilde bf16 + (H0*Htilde) bf16 for the Wz GEMM.
// grid (32 i-tiles of 64, 12 heads), block 256 (4 waves). LDS 56 KB.
// ---------------------------------------------------------------------------
__global__ __launch_bounds__(256) void near_fused(
    const unsigned short* __restrict__ qhatb, const unsigned short* __restrict__ khatb,
    const unsigned short* __restrict__ vexptb, const float* __restrict__ mnear,
    const float* __restrict__ gu, const float* __restrict__ gb,
    const float* __restrict__ h0, float* __restrict__ hn,
    unsigned short* __restrict__ htlb, unsigned short* __restrict__ prodb)
{
    __shared__ unsigned short Qs[64*64];     // 8 KB
    __shared__ unsigned short KPs[192*64];   // 24 KB: Khat, then P[64][192]
    __shared__ unsigned short Vst[64*192];   // 24 KB: Vexp^T [d][jl]
    const int it = blockIdx.x, hh = blockIdx.y;
    const int i0 = it * 64;
    const int tid = threadIdx.x, lane = tid & 63, wid = tid >> 6;
    const int fr = lane & 15, fq = lane >> 4;

#pragma unroll
    for (int i = 0; i < 2; ++i) {            // Qhat [64][64]: 512 chunks
        int cb = i * 256 + wid * 64, c = cb + lane;
        int r = c >> 3, col = ((c & 7) ^ (r & 7)) * 8;
        gload16(qhatb + (size_t)(i0 + r) * 768 + hh*64 + col, &Qs[cb * 8]);
    }
#pragma unroll
    for (int i = 0; i < 6; ++i) {            // Khat [192][64]: 1536 chunks
        int cb = i * 256 + wid * 64, c = cb + lane;
        int r = c >> 3, col = ((c & 7) ^ (r & 7)) * 8;
        int j = i0 - 128 + r; if (j < 0) j = 0;
        gload16(khatb + (size_t)j * 768 + hh*64 + col, &KPs[cb * 8]);
    }
#pragma unroll
    for (int i = 0; i < 6; ++i) {            // Vexp^T [64][192]: 1536 chunks
        int cb = i * 256 + wid * 64, c = cb + lane;
        int d = c / 24, cc = c - d * 24;
        int ccp = (cc & 24) | ((cc & 7) ^ (d & 7));
        int t = i0 - 128 + ccp * 8; if (t < 0) t = 0;
        gload16(vexptb + (size_t)(hh*64 + d) * 2048 + t, &Vst[cb * 8]);
    }
    __syncthreads();

    // S = Qhat Khat^T: M=64, N=192 (wave strip of 48), K=64
    f32x4 sacc[4][3];
#pragma unroll
    for (int mi = 0; mi < 4; ++mi)
#pragma unroll
        for (int ni = 0; ni < 3; ++ni) sacc[mi][ni] = (f32x4){0.f,0.f,0.f,0.f};
#pragma unroll
    for (int kt = 0; kt < 2; ++kt) {
        int kk = kt * 32;
        bf16x8 qa[4], kb[3];
#pragma unroll
        for (int mi = 0; mi < 4; ++mi)
            qa[mi] = frag128(Qs, mi*16 + fr, kk + fq*8);
#pragma unroll
        for (int ni = 0; ni < 3; ++ni)
            kb[ni] = frag128(KPs, wid*48 + ni*16 + fr, kk + fq*8);
#pragma unroll
        for (int mi = 0; mi < 4; ++mi)
#pragma unroll
            for (int ni = 0; ni < 3; ++ni)
                sacc[mi][ni] = __builtin_amdgcn_mfma_f32_16x16x32_bf16(
                    qa[mi], kb[ni], sacc[mi][ni], 0, 0, 0);
    }
    __syncthreads();   // Khat reads done before P overwrites

    // masked sigmoid -> P[64][192] bf16 (overwrite KPs)
#pragma unroll
    for (int mi = 0; mi < 4; ++mi)
#pragma unroll
        for (int ni = 0; ni < 3; ++ni)
#pragma unroll
            for (int v = 0; v < 4; ++v) {
                int il = mi*16 + fq*4 + v;
                int jl = wid*48 + ni*16 + fr;
                float s = sacc[mi][ni][v];
                float a = 0.f;
                if (jl >= il && jl <= il + 128 && (i0 - 128 + jl) >= 0)
                    a = 1.f / (1.f + expf(-(s*s*INV_TAU + B_SCALAR)));
                int byte = (il * 384 + jl * 2) ^ ((il & 7) << 4);
                *(unsigned short*)((char*)KPs + byte) = f2b(a);
            }
    __syncthreads();

    // Y = P @ Vexp: M=64 (wave strip of 16), N=64, K=192
    f32x4 yacc[4];
#pragma unroll
    for (int nf = 0; nf < 4; ++nf) yacc[nf] = (f32x4){0.f,0.f,0.f,0.f};
#pragma unroll
    for (int ks = 0; ks < 6; ++ks) {
        int kk = ks * 32;
        bf16x8 pa = frag384(KPs, wid*16 + fr, kk + fq*8);
        bf16x8 vb[4];
#pragma unroll
        for (int nf = 0; nf < 4; ++nf)
            vb[nf] = frag384(Vst, nf*16 + fr, kk + fq*8);
#pragma unroll
        for (int nf = 0; nf < 4; ++nf)
            yacc[nf] = __builtin_amdgcn_mfma_f32_16x16x32_bf16(pa, vb[nf], yacc[nf], 0, 0, 0);
    }

    // epilogue: log + m, head gate, write hn fp32 + htlb/prodb bf16
    float hv[4][4];
    float sp[4] = {0.f, 0.f, 0.f, 0.f};
#pragma unroll
    for (int nf = 0; nf < 4; ++nf) {
        int d = nf*16 + fr;
        float guv = gu[hh*64 + d];
#pragma unroll
        for (int v = 0; v < 4; ++v) {
            int row = wid*16 + fq*4 + v;
            float y = yacc[nf][v];
            float h = logf(fmaxf(y, 1e-30f)) + mnear[(size_t)(i0 + row)*768 + hh*64 + d];
            hv[nf][v] = h;
            sp[v] = fmaf(h, guv, sp[v]);
        }
    }
#pragma unroll
    for (int off = 1; off < 16; off <<= 1) {
#pragma unroll
        for (int v = 0; v < 4; ++v) sp[v] += __shfl_xor(sp[v], off);
    }
    float gbh = gb[hh];
#pragma unroll
    for (int v = 0; v < 4; ++v) sp[v] = 1.f / (1.f + expf(-(sp[v] + gbh)));
#pragma unroll
    for (int nf = 0; nf < 4; ++nf)
#pragma unroll
        for (int v = 0; v < 4; ++v) {
            int row = wid*16 + fq*4 + v;
            int d = nf*16 + fr;
            size_t idx = (size_t)(i0 + row)*768 + hh*64 + d;
            float htl = hv[nf][v] * sp[v];
            hn[idx] = htl;
            htlb[idx] = f2b(htl);
            prodb[idx] = f2b(h0[idx] * htl);
        }
}

// ---------------------------------------------------------------------------
extern "C" void kernel_launch(void* const* d_in, const int* in_sizes, int n_in,
                              void* d_out, int out_size, void* d_ws, size_t ws_size,
                              hipStream_t stream)
{
    const float* x  = (const float*)d_in[0];
    const float* wq = (const float*)d_in[1];  const float* bq = (const float*)d_in[2];
    const float* wk = (const float*)d_in[3];  const float* bk = (const float*)d_in[4];
    const float* wv = (const float*)d_in[5];  const float* bv = (const float*)d_in[6];
    const float* wo = (const float*)d_in[7];  const float* bo = (const float*)d_in[8];
    const float* pq = (const float*)d_in[9];  const float* pk = (const float*)d_in[10];
    const float* pv = (const float*)d_in[11];
    const float* up = (const float*)d_in[12];
    const float* gu = (const float*)d_in[13]; const float* gb = (const float*)d_in[14];
    const float* wz = (const float*)d_in[15]; const float* bz = (const float*)d_in[16];
    float* out = (float*)d_out;

    float* w = (float*)d_ws;
    float* qkv  = w; w += 2048*2304;
    float* vr   = w; w += 2048*32;
    float* ms   = w; w += 2048*32;
    float* h0   = w; w += 2048*768;
    float* mnear= w; w += 2048*768;
    float* hn   = w; w += 2048*768;          // Htilde after near_fused
    float* partial = w; w += 16*16*128*32;   // seed partials
    float* pgemm = w; w += 4*2048*768;       // split-K partials (Wz 4 / Wo 2)
    float* plr   = w; w += 4*3*2048*32;      // lowrank split-K partials
    float* bqkv = w; w += 2304;
    unsigned short* xb     = (unsigned short*)w; w += 2048*768/2;
    unsigned short* qkvb   = (unsigned short*)w; w += 2048*2304/2;
    unsigned short* wqkvT  = (unsigned short*)w; w += 2304*768/2;
    unsigned short* wzT    = (unsigned short*)w; w += 768*3072/2;
    unsigned short* woT    = (unsigned short*)w; w += 768*768/2;
    unsigned short* pT     = (unsigned short*)w; w += 3*32*768/2;
    unsigned short* h0b    = (unsigned short*)w; w += 2048*768/2;
    unsigned short* htlb   = (unsigned short*)w; w += 2048*768/2;
    unsigned short* prodb  = (unsigned short*)w; w += 2048*768/2;
    unsigned short* houtb  = (unsigned short*)w; w += 2048*768/2;
    unsigned short* qrb    = (unsigned short*)w; w += 2048*32/2;
    unsigned short* krb    = (unsigned short*)w; w += 2048*32/2;
    unsigned short* evtb   = (unsigned short*)w; w += 32*2048/2;
    unsigned short* qhatb  = (unsigned short*)w; w += 2048*768/2;
    unsigned short* khatb  = (unsigned short*)w; w += 2048*768/2;
    unsigned short* vexptb = (unsigned short*)w; w += 768*2048/2;

    // ---- prep (single mega-dispatch: cvt + 8 transposes + bias concat)
    prep_all<<<6225, 256, 0, stream>>>(x, xb, wq, wk, wv, wqkvT, wz, wzT,
                                       wo, woT, pq, pk, pv, pT, bq, bk, bv, bqkv);

    // 0) QKV projections (fp32 + bf16 copy)
    gemm_mfma<0,1><<<dim3(18,16,1), 256, 0, stream>>>(xb, nullptr, nullptr, nullptr,
        wqkvT, bqkv, qkv, qkvb, nullptr, 768, 2304);

    // 1) low-rank path
    lowrank_mfma<<<dim3(16,3,4), 256, 0, stream>>>(qkvb, pT, plr);
    lowrank_finish<<<768, 256, 0, stream>>>(plr, qrb, krb, vr, evtb);
    cummax_vr<<<32, 256, 0, stream>>>(vr, ms);
    seed_mfma<<<dim3(16,16), 256, 0, stream>>>(qrb, krb, evtb, partial);
    seed_up<<<2048, 256, 0, stream>>>(partial, ms, up, h0, h0b);

    // 2) near-field path (full MFMA, fused gate + GRU-input emission)
    head_norms_write<<<2048, 768, 0, stream>>>(qkv, qhatb, khatb);
    slide_max<<<dim3(12,32), 256, 0, stream>>>(qkv, mnear, vexptb);
    near_fused<<<dim3(32,12), 256, 0, stream>>>(qhatb, khatb, vexptb, mnear,
                                                gu, gb, h0, hn, htlb, prodb);

    // 3) GRU blend (split-K=4) + output projection (split-K=2)
    gemm_mfma<1,4><<<dim3(6,16,4), 256, 0, stream>>>(xb, h0b, htlb, prodb,
        wzT, nullptr, nullptr, nullptr, pgemm, 3072, 768);
    wz_combine<<<1536, 256, 0, stream>>>(pgemm, bz, h0, hn, houtb);
    gemm_mfma<2,2><<<dim3(6,16,2), 256, 0, stream>>>(houtb, nullptr, nullptr, nullptr,
        woT, nullptr, nullptr, nullptr, pgemm, 768, 768);
    wo_combine<<<1536, 256, 0, stream>>>(pgemm, bo, out);
}